// Round 1
// baseline (5096.084 us; speedup 1.0000x reference)
//
#include <hip/hip_runtime.h>
#include <math.h>

#define DIMV 384
#define NHEADV 8
#define HDV 48
#define CORR_DIMV 882
#define NFRAMESV 24
#define PPIV 96
#define NPATCHV (NFRAMESV * PPIV)        // 2304
#define ETOK (NPATCHV * NFRAMESV)        // 55296
#define MTOK 96
#define NGRP (ETOK / MTOK)               // 576

// ---------------------------------------------------------------------------
// Tiled f32 GEMM: C[M x N] = epi(A[M x K] @ W[K x N] + bias)
// EPI: 0 = store, 1 = relu-store, 2 = accumulate into C (C += r + bias)
// GATHER: A row r is A[gidx[r]]; gidx[r] < 0 -> zero row (mask semantics)
// RELU_A: apply relu to A elements on load
// ---------------------------------------------------------------------------
template<int EPI, bool GATHER, bool RELU_A>
__global__ __launch_bounds__(256)
void gemm_f32(const float* __restrict__ A, const float* __restrict__ W,
              const float* __restrict__ bias, float* __restrict__ C,
              const int* __restrict__ gidx, int K, int N)
{
    const int row0 = blockIdx.y * 64;
    const int col0 = blockIdx.x * 64;
    __shared__ float As[16][68];
    __shared__ float Ws[16][68];
    const int tid = threadIdx.x;
    const int tx = tid & 15, ty = tid >> 4;
    float acc[4][4] = {};

    for (int k0 = 0; k0 < K; k0 += 16) {
        #pragma unroll
        for (int i = 0; i < 4; ++i) {
            int idx = tid + i * 256;
            int r = idx >> 4, c = idx & 15;
            int ar = row0 + r;
            long srow = ar;
            if (GATHER) srow = gidx[ar];
            float v = 0.f;
            if ((!GATHER || srow >= 0) && (k0 + c) < K)
                v = A[srow * (long)K + k0 + c];
            if (RELU_A) v = fmaxf(v, 0.f);
            As[c][r] = v;
        }
        #pragma unroll
        for (int i = 0; i < 4; ++i) {
            int idx = tid + i * 256;
            int r = idx >> 6, c = idx & 63;
            float v = 0.f;
            if (k0 + r < K) v = W[(long)(k0 + r) * N + col0 + c];
            Ws[r][c] = v;
        }
        __syncthreads();
        #pragma unroll
        for (int k = 0; k < 16; ++k) {
            float a[4], b[4];
            #pragma unroll
            for (int i = 0; i < 4; ++i) a[i] = As[k][ty * 4 + i];
            #pragma unroll
            for (int j = 0; j < 4; ++j) b[j] = Ws[k][tx * 4 + j];
            #pragma unroll
            for (int i = 0; i < 4; ++i)
                #pragma unroll
                for (int j = 0; j < 4; ++j)
                    acc[i][j] = fmaf(a[i], b[j], acc[i][j]);
        }
        __syncthreads();
    }

    #pragma unroll
    for (int i = 0; i < 4; ++i) {
        long r = row0 + ty * 4 + i;
        #pragma unroll
        for (int j = 0; j < 4; ++j) {
            int cidx = col0 + tx * 4 + j;
            float v = acc[i][j];
            if (bias) v += bias[cidx];
            long off = r * N + cidx;
            if (EPI == 1) v = fmaxf(v, 0.f);
            if (EPI == 2) v += C[off];
            C[off] = v;
        }
    }
}

// ---------------------------------------------------------------------------
// LayerNorm over DIM=384, one wave per row (4 rows/block).
// dst[row] = LN(s0[srow] (+ s1[srow]) (+ s2[srow])) * g + b
// srow = gather ? gather[row] : row
// ---------------------------------------------------------------------------
__global__ __launch_bounds__(256)
void ln_kernel(float* __restrict__ dst, const float* __restrict__ s0,
               const float* __restrict__ s1, const float* __restrict__ s2,
               const int* __restrict__ gather,
               const float* __restrict__ g, const float* __restrict__ b)
{
    const int wave = threadIdx.x >> 6;
    const int lane = threadIdx.x & 63;
    const long row = (long)blockIdx.x * 4 + wave;
    const long srow = gather ? (long)gather[row] : row;

    float x[6];
    float sum = 0.f;
    #pragma unroll
    for (int i = 0; i < 6; ++i) {
        int c = lane + i * 64;
        float v = s0[srow * DIMV + c];
        if (s1) v += s1[srow * DIMV + c];
        if (s2) v += s2[srow * DIMV + c];
        x[i] = v; sum += v;
    }
    #pragma unroll
    for (int o = 32; o > 0; o >>= 1) sum += __shfl_xor(sum, o);
    float mu = sum * (1.f / DIMV);
    float vs = 0.f;
    #pragma unroll
    for (int i = 0; i < 6; ++i) { float d = x[i] - mu; vs += d * d; }
    #pragma unroll
    for (int o = 32; o > 0; o >>= 1) vs += __shfl_xor(vs, o);
    float rstd = rsqrtf(vs * (1.f / DIMV) + 1e-3f);
    #pragma unroll
    for (int i = 0; i < 6; ++i) {
        int c = lane + i * 64;
        dst[row * DIMV + c] = (x[i] - mu) * rstd * g[c] + b[c];
    }
}

// ---------------------------------------------------------------------------
// Segment softmax-aggregation. Segments are contiguous 24-row blocks
// (kk = repeat(arange(NPATCH), NFRAMES)). One block per patch, one thread
// per column. y[p, col] = sum_r f[p*24+r, col] * softmax_r(g[p*24+r, col])
// ---------------------------------------------------------------------------
__global__ __launch_bounds__(384)
void softagg_kernel(const float* __restrict__ gbuf, const float* __restrict__ fbuf,
                    float* __restrict__ y)
{
    const int p = blockIdx.x;
    const int col = threadIdx.x;
    const long base = (long)p * NFRAMESV * DIMV + col;
    float gv[NFRAMESV];
    float gmax = -INFINITY;
    #pragma unroll
    for (int r = 0; r < NFRAMESV; ++r) {
        gv[r] = gbuf[base + (long)r * DIMV];
        gmax = fmaxf(gmax, gv[r]);
    }
    float den = 0.f;
    #pragma unroll
    for (int r = 0; r < NFRAMESV; ++r) { gv[r] = expf(gv[r] - gmax); den += gv[r]; }
    float acc = 0.f;
    #pragma unroll
    for (int r = 0; r < NFRAMESV; ++r) acc += fbuf[base + (long)r * DIMV] * gv[r];
    y[(long)p * DIMV + col] = acc / den;
}

// net[e, d] += y2[e / NFRAMES, d]
__global__ __launch_bounds__(256)
void addseg_kernel(float* __restrict__ net, const float* __restrict__ y2)
{
    long idx = (long)blockIdx.x * 256 + threadIdx.x;
    long e = idx / DIMV;
    int d = (int)(idx % DIMV);
    net[idx] += y2[(e / NFRAMESV) * DIMV + d];
}

// ---------------------------------------------------------------------------
// RoPE + elu+1 on q and k in place. Processes (d, d+24) pairs per thread to
// avoid the in-place rotate-half race. cos/sin indexed by flat[e] (token id).
// ---------------------------------------------------------------------------
__global__ __launch_bounds__(256)
void rope_kernel(float* __restrict__ q, float* __restrict__ k,
                 const float* __restrict__ pos, const int* __restrict__ flat)
{
    long idx = (long)blockIdx.x * 256 + threadIdx.x;          // E*8*24 threads
    long e = idx / (NHEADV * 24);
    int rem = (int)(idx % (NHEADV * 24));
    int h = rem / 24, d = rem % 24;
    int tok = flat[e];
    const float* cp = pos + (long)tok * HDV;
    const float* sp = pos + (long)ETOK * HDV + (long)tok * HDV;
    float c1 = cp[d], c2 = cp[d + 24], s1 = sp[d], s2 = sp[d + 24];
    long o1 = e * DIMV + h * HDV + d;
    long o2 = o1 + 24;

    float q1 = q[o1], q2 = q[o2];
    float r1 = q1 * c1 - q2 * s1;
    float r2 = q2 * c2 + q1 * s2;
    q[o1] = (r1 > 0.f) ? r1 + 1.f : expf(r1);   // elu(x)+1
    q[o2] = (r2 > 0.f) ? r2 + 1.f : expf(r2);

    float k1 = k[o1], k2 = k[o2];
    float t1 = k1 * c1 - k2 * s1;
    float t2 = k2 * c2 + k1 * s2;
    k[o1] = (t1 > 0.f) ? t1 + 1.f : expf(t1);
    k[o2] = (t2 > 0.f) ? t2 + 1.f : expf(t2);
}

// ---------------------------------------------------------------------------
// Gated linear attention core, one block per (group n, head h).
// Reads Q (post elu+1) from qo, K from kbuf, V from vbuf; writes out into the
// same (n,h) slice of qo (disjoint across blocks -> race-free).
// ---------------------------------------------------------------------------
__global__ __launch_bounds__(256)
void attn_kernel(float* __restrict__ qo, const float* __restrict__ kbuf,
                 const float* __restrict__ vbuf)
{
    const int n = blockIdx.x, h = blockIdx.y;
    __shared__ float Qs[MTOK][HDV];
    __shared__ float Ks[MTOK][HDV];
    __shared__ float Vs[MTOK][HDV];
    __shared__ float KV[HDV][HDV];
    __shared__ float Ksum[HDV];
    __shared__ float Zs[MTOK];
    const int tid = threadIdx.x;

    for (int idx = tid; idx < MTOK * HDV; idx += 256) {
        int l = idx / HDV, d = idx % HDV;
        long off = ((long)n * MTOK + l) * DIMV + h * HDV + d;
        Qs[l][d] = qo[off];
        Ks[l][d] = kbuf[off];
        Vs[l][d] = vbuf[off];
    }
    __syncthreads();

    for (int idx = tid; idx < HDV * HDV; idx += 256) {
        int d = idx / HDV, dv = idx % HDV;
        float a = 0.f;
        #pragma unroll 8
        for (int l = 0; l < MTOK; ++l) a = fmaf(Ks[l][d], Vs[l][dv], a);
        KV[d][dv] = a;
    }
    if (tid < HDV) {
        float s = 0.f;
        #pragma unroll 8
        for (int l = 0; l < MTOK; ++l) s += Ks[l][tid];
        Ksum[tid] = s;
    }
    __syncthreads();

    if (tid < MTOK) {
        float s = 0.f;
        #pragma unroll
        for (int d = 0; d < HDV; ++d) s = fmaf(Qs[tid][d], Ksum[d], s);
        Zs[tid] = 1.f / (s + 1e-6f);
    }
    __syncthreads();

    for (int idx = tid; idx < MTOK * HDV; idx += 256) {
        int l = idx / HDV, dv = idx % HDV;
        float a = 0.f;
        #pragma unroll
        for (int d = 0; d < HDV; ++d) a = fmaf(Qs[l][d], KV[d][dv], a);
        qo[((long)n * MTOK + l) * DIMV + h * HDV + dv] = a * Zs[l];
    }
}

// out_net[flat[e], d] = tok[e, d] + sigmoid(gatepre[e, d]) * msg[e, d]
__global__ __launch_bounds__(256)
void combine_kernel(float* __restrict__ out_net, const float* __restrict__ tok,
                    const float* __restrict__ msg, const float* __restrict__ gatepre,
                    const int* __restrict__ flat)
{
    long idx = (long)blockIdx.x * 256 + threadIdx.x;
    long e = idx / DIMV;
    int d = (int)(idx % DIMV);
    float gate = 1.f / (1.f + expf(-gatepre[idx]));
    out_net[(long)flat[e] * DIMV + d] = tok[idx] + gate * msg[idx];
}

// d/w heads: one wave per row; 4 simultaneous 384-dots, shfl reduce.
__global__ __launch_bounds__(256)
void head_kernel(const float* __restrict__ net,
                 const float* __restrict__ Wd, const float* __restrict__ bd,
                 const float* __restrict__ Ww, const float* __restrict__ bw,
                 float* __restrict__ dout, float* __restrict__ wout)
{
    const int wave = threadIdx.x >> 6;
    const int lane = threadIdx.x & 63;
    const long row = (long)blockIdx.x * 4 + wave;
    const float* p = net + row * DIMV;
    float a0 = 0.f, a1 = 0.f, a2 = 0.f, a3 = 0.f;
    #pragma unroll
    for (int i = 0; i < 6; ++i) {
        int c = lane + i * 64;
        float r = fmaxf(p[c], 0.f);
        a0 = fmaf(r, Wd[c * 2 + 0], a0);
        a1 = fmaf(r, Wd[c * 2 + 1], a1);
        a2 = fmaf(r, Ww[c * 2 + 0], a2);
        a3 = fmaf(r, Ww[c * 2 + 1], a3);
    }
    #pragma unroll
    for (int o = 32; o > 0; o >>= 1) {
        a0 += __shfl_xor(a0, o);
        a1 += __shfl_xor(a1, o);
        a2 += __shfl_xor(a2, o);
        a3 += __shfl_xor(a3, o);
    }
    if (lane == 0) {
        dout[row * 2 + 0] = a0 + bd[0];
        dout[row * 2 + 1] = a1 + bd[1];
        wout[row * 2 + 0] = 1.f / (1.f + expf(-(a2 + bw[0])));
        wout[row * 2 + 1] = 1.f / (1.f + expf(-(a3 + bw[1])));
    }
}

extern "C" void kernel_launch(void* const* d_in, const int* in_sizes, int n_in,
                              void* d_out, int out_size, void* d_ws, size_t ws_size,
                              hipStream_t stream)
{
    const float* net_in = (const float*)d_in[0];
    const float* inp    = (const float*)d_in[1];
    const float* corr   = (const float*)d_in[2];
    const float* posenc = (const float*)d_in[4];
    const int*   ix     = (const int*)d_in[8];
    const int*   jx     = (const int*)d_in[9];
    const int*   flat   = (const int*)d_in[10];   // ij_ind flattened (E,)

    const float* Wc1 = (const float*)d_in[11]; const float* bc1 = (const float*)d_in[12];
    const float* Wc2 = (const float*)d_in[13]; const float* bc2 = (const float*)d_in[14];
    const float* g_lnc = (const float*)d_in[15]; const float* b_lnc = (const float*)d_in[16];
    const float* Wc3 = (const float*)d_in[17]; const float* bc3 = (const float*)d_in[18];
    const float* g_norm = (const float*)d_in[19]; const float* b_norm = (const float*)d_in[20];
    const float* W1a = (const float*)d_in[21]; const float* b1a = (const float*)d_in[22];
    const float* W1b = (const float*)d_in[23]; const float* b1b = (const float*)d_in[24];
    const float* W2a = (const float*)d_in[25]; const float* b2a = (const float*)d_in[26];
    const float* W2b = (const float*)d_in[27]; const float* b2b = (const float*)d_in[28];
    const float* Wf = (const float*)d_in[29]; const float* bf = (const float*)d_in[30];
    const float* Wg = (const float*)d_in[31]; const float* bg = (const float*)d_in[32];
    const float* Wh = (const float*)d_in[33]; const float* bh = (const float*)d_in[34];
    const float* g_norm2 = (const float*)d_in[35]; const float* b_norm2 = (const float*)d_in[36];
    const float* Wq = (const float*)d_in[37]; const float* bq = (const float*)d_in[38];
    const float* Wk = (const float*)d_in[39]; const float* bk = (const float*)d_in[40];
    const float* Wv = (const float*)d_in[41]; const float* bv = (const float*)d_in[42];
    const float* Wm = (const float*)d_in[43]; const float* bm = (const float*)d_in[44];
    const float* Wgt = (const float*)d_in[45]; const float* bgt = (const float*)d_in[46];
    const float* Wd = (const float*)d_in[47]; const float* bd = (const float*)d_in[48];
    const float* Ww = (const float*)d_in[49]; const float* bw = (const float*)d_in[50];

    const size_t EB = (size_t)ETOK * DIMV;
    float* B0 = (float*)d_ws;            // tokens (LN'd)
    float* B1 = B0 + EB;                 // running net / v / gate_pre
    float* B2 = B1 + EB;                 // scratch / q / attn out
    float* B3 = B2 + EB;                 // scratch / k / msg
    float* Y  = B3 + EB;                 // NPATCH x DIM
    float* Y2 = Y + (size_t)NPATCHV * DIMV;

    float* out_net = (float*)d_out;
    float* out_d = out_net + EB;
    float* out_w = out_d + (size_t)ETOK * 2;

    const dim3 g64(DIMV / 64, ETOK / 64);       // (6, 864)
    const dim3 gY(DIMV / 64, NPATCHV / 64);     // (6, 36)
    const int lnBlocks = ETOK / 4;              // 13824
    const int ewBlocks = (int)(EB / 256);       // 82944

    // corr encoder: c = linear(relu(ln(linear(relu(linear(corr))))))
    gemm_f32<1, false, false><<<g64, 256, 0, stream>>>(corr, Wc1, bc1, B2, nullptr, CORR_DIMV, DIMV);
    gemm_f32<0, false, false><<<g64, 256, 0, stream>>>(B2, Wc2, bc2, B3, nullptr, DIMV, DIMV);
    ln_kernel<<<lnBlocks, 256, 0, stream>>>(B3, B3, nullptr, nullptr, nullptr, g_lnc, b_lnc);
    gemm_f32<0, false, true><<<g64, 256, 0, stream>>>(B3, Wc3, bc3, B2, nullptr, DIMV, DIMV);

    // net = LN(net + inp + c)
    ln_kernel<<<lnBlocks, 256, 0, stream>>>(B1, net_in, inp, B2, nullptr, g_norm, b_norm);

    // net += mlp2(mask_ix * net[ix])
    gemm_f32<1, true, false><<<g64, 256, 0, stream>>>(B1, W1a, b1a, B2, ix, DIMV, DIMV);
    gemm_f32<2, false, false><<<g64, 256, 0, stream>>>(B2, W1b, b1b, B1, nullptr, DIMV, DIMV);

    // net += mlp2(mask_jx * net[jx])
    gemm_f32<1, true, false><<<g64, 256, 0, stream>>>(B1, W2a, b2a, B2, jx, DIMV, DIMV);
    gemm_f32<2, false, false><<<g64, 256, 0, stream>>>(B2, W2b, b2b, B1, nullptr, DIMV, DIMV);

    // soft aggregation
    gemm_f32<0, false, false><<<g64, 256, 0, stream>>>(B1, Wg, bg, B2, nullptr, DIMV, DIMV);
    gemm_f32<0, false, false><<<g64, 256, 0, stream>>>(B1, Wf, bf, B3, nullptr, DIMV, DIMV);
    softagg_kernel<<<NPATCHV, 384, 0, stream>>>(B2, B3, Y);
    gemm_f32<0, false, false><<<gY, 256, 0, stream>>>(Y, Wh, bh, Y2, nullptr, DIMV, DIMV);
    addseg_kernel<<<ewBlocks, 256, 0, stream>>>(B1, Y2);

    // tokens = LN(net[flat])
    ln_kernel<<<lnBlocks, 256, 0, stream>>>(B0, B1, nullptr, nullptr, flat, g_norm2, b_norm2);

    // q,k,v  (v reuses B1 — net no longer needed)
    gemm_f32<0, false, false><<<g64, 256, 0, stream>>>(B0, Wq, bq, B2, nullptr, DIMV, DIMV);
    gemm_f32<0, false, false><<<g64, 256, 0, stream>>>(B0, Wk, bk, B3, nullptr, DIMV, DIMV);
    gemm_f32<0, false, false><<<g64, 256, 0, stream>>>(B0, Wv, bv, B1, nullptr, DIMV, DIMV);

    // RoPE + elu+1 on q,k
    {
        long total = (long)ETOK * NHEADV * 24;
        rope_kernel<<<(int)(total / 256), 256, 0, stream>>>(B2, B3, posenc, flat);
    }

    // linear attention (out written into B2)
    attn_kernel<<<dim3(NGRP, NHEADV), 256, 0, stream>>>(B2, B3, B1);

    // msg = out @ Wm + bm   (B3: k dead)
    gemm_f32<0, false, false><<<g64, 256, 0, stream>>>(B2, Wm, bm, B3, nullptr, DIMV, DIMV);

    // gate_pre = tok @ Wgt[:384] + bgt + msg @ Wgt[384:]   (B1: v dead)
    gemm_f32<0, false, false><<<g64, 256, 0, stream>>>(B0, Wgt, bgt, B1, nullptr, DIMV, DIMV);
    gemm_f32<2, false, false><<<g64, 256, 0, stream>>>(B3, Wgt + (size_t)DIMV * DIMV, nullptr, B1, nullptr, DIMV, DIMV);

    // net_out[flat[e]] = tok + sigmoid(gate_pre) * msg
    combine_kernel<<<ewBlocks, 256, 0, stream>>>(out_net, B0, B3, B1, flat);

    // heads
    head_kernel<<<lnBlocks, 256, 0, stream>>>(out_net, Wd, bd, Ww, bw, out_d, out_w);
}

// Round 2
// 2714.066 us; speedup vs baseline: 1.8777x; 1.8777x over previous
//
#include <hip/hip_runtime.h>
#include <math.h>

#define DIMV 384
#define NHEADV 8
#define HDV 48
#define CORR_DIMV 882
#define NFRAMESV 24
#define PPIV 96
#define NPATCHV (NFRAMESV * PPIV)        // 2304
#define ETOK (NPATCHV * NFRAMESV)        // 55296
#define MTOK 96
#define NGRP (ETOK / MTOK)               // 576

using f32x4 = __attribute__((ext_vector_type(4))) float;
using s16x8 = __attribute__((ext_vector_type(8))) short;

__device__ __forceinline__ unsigned int f2bf(float x) {
    union { float f; unsigned int u; } c; c.f = x;
    unsigned int u = c.u;
    u += 0x7fffu + ((u >> 16) & 1u);   // round-to-nearest-even
    return u >> 16;
}

// ---------------------------------------------------------------------------
// bf16 MFMA GEMM: C[M x N] = epi(A[M x K] @ W[K x N] + bias), f32 in/out.
// A, W converted f32->bf16 during LDS staging; f32 accumulation (MFMA).
// Block tile 128x64, 4 waves (2m x 2n), wave tile 64x32 = 4x2 frags 16x16.
// EPI: 0 = store, 1 = relu-store, 2 = accumulate into C
// GATHER: A row r is A[gidx[r]]; gidx[r] < 0 -> zero row. RELU_A: relu on A.
// ---------------------------------------------------------------------------
template<int EPI, bool GATHER, bool RELU_A>
__global__ __launch_bounds__(256)
void gemm_bf16(const float* __restrict__ A, const float* __restrict__ W,
               const float* __restrict__ bias, float* __restrict__ C,
               const int* __restrict__ gidx, int K, int N)
{
    const int row0 = blockIdx.y * 128;
    const int col0 = blockIdx.x * 64;
    __shared__ __align__(16) unsigned short As[128][40];   // [m][k], pad 32->40
    __shared__ __align__(16) unsigned short Ws[64][40];    // [n][k], pad 32->40

    const int tid  = threadIdx.x;
    const int lane = tid & 63;
    const int wid  = tid >> 6;
    const int wm   = wid >> 1;          // 0..1
    const int wn   = wid & 1;           // 0..1

    f32x4 acc[4][2] = {};

    const int ntiles = (K + 31) >> 5;
    for (int t = 0; t < ntiles; ++t) {
        const int k0 = t << 5;

        // ---- stage A tile: 128 x 32, f32 -> bf16 (float2 loads, 8B aligned) ----
        {
            const int f2 = tid & 15;        // float2 slot within 32-wide row
            const int rb = tid >> 4;        // 0..15
            const int kk = k0 + f2 * 2;
            #pragma unroll
            for (int i = 0; i < 8; ++i) {
                const int r = rb + i * 16;
                long srow = row0 + r;
                if (GATHER) srow = gidx[row0 + r];
                float v0 = 0.f, v1 = 0.f;
                if (!GATHER || srow >= 0) {
                    const float* p = A + srow * (long)K + kk;
                    if (kk + 1 < K) { float2 tv = *(const float2*)p; v0 = tv.x; v1 = tv.y; }
                    else if (kk < K) { v0 = p[0]; }
                }
                if (RELU_A) { v0 = fmaxf(v0, 0.f); v1 = fmaxf(v1, 0.f); }
                *(unsigned int*)&As[r][f2 * 2] = f2bf(v0) | (f2bf(v1) << 16);
            }
        }

        // ---- stage W tile: 32 x 64, transposed to [n][k], f32 -> bf16 ----
        {
            const int n  = tid & 63;
            const int kq = tid >> 6;        // 0..3, 8 k each
            union { unsigned short us[8]; int4 v; } wt;
            #pragma unroll
            for (int j = 0; j < 8; ++j) {
                const int kk = k0 + kq * 8 + j;
                float v = (kk < K) ? W[(long)kk * N + col0 + n] : 0.f;
                wt.us[j] = (unsigned short)f2bf(v);
            }
            *(int4*)&Ws[n][kq * 8] = wt.v;
        }
        __syncthreads();

        // ---- fragments + MFMA ----
        {
            const int rsel  = lane & 15;
            const int khalf = (lane >> 4) * 8;
            s16x8 a[4], b[2];
            #pragma unroll
            for (int i = 0; i < 4; ++i)
                a[i] = *(const s16x8*)&As[wm * 64 + i * 16 + rsel][khalf];
            #pragma unroll
            for (int j = 0; j < 2; ++j)
                b[j] = *(const s16x8*)&Ws[wn * 32 + j * 16 + rsel][khalf];
            #pragma unroll
            for (int i = 0; i < 4; ++i)
                #pragma unroll
                for (int j = 0; j < 2; ++j)
                    acc[i][j] = __builtin_amdgcn_mfma_f32_16x16x32_bf16(a[i], b[j], acc[i][j], 0, 0, 0);
        }
        __syncthreads();
    }

    // ---- epilogue: C/D layout col=lane&15, row=(lane>>4)*4+reg ----
    const int ccol = lane & 15;
    const int rgrp = lane >> 4;
    #pragma unroll
    for (int i = 0; i < 4; ++i) {
        #pragma unroll
        for (int j = 0; j < 2; ++j) {
            const int col = col0 + wn * 32 + j * 16 + ccol;
            const long rbase = row0 + wm * 64 + i * 16 + rgrp * 4;
            const float bsv = bias ? bias[col] : 0.f;
            #pragma unroll
            for (int rr = 0; rr < 4; ++rr) {
                const long off = (rbase + rr) * (long)N + col;
                float v = acc[i][j][rr] + bsv;
                if (EPI == 1) v = fmaxf(v, 0.f);
                if (EPI == 2) v += C[off];
                C[off] = v;
            }
        }
    }
}

// ---------------------------------------------------------------------------
// LayerNorm over DIM=384, one wave per row (4 rows/block).
// ---------------------------------------------------------------------------
__global__ __launch_bounds__(256)
void ln_kernel(float* __restrict__ dst, const float* __restrict__ s0,
               const float* __restrict__ s1, const float* __restrict__ s2,
               const int* __restrict__ gather,
               const float* __restrict__ g, const float* __restrict__ b)
{
    const int wave = threadIdx.x >> 6;
    const int lane = threadIdx.x & 63;
    const long row = (long)blockIdx.x * 4 + wave;
    const long srow = gather ? (long)gather[row] : row;

    float x[6];
    float sum = 0.f;
    #pragma unroll
    for (int i = 0; i < 6; ++i) {
        int c = lane + i * 64;
        float v = s0[srow * DIMV + c];
        if (s1) v += s1[srow * DIMV + c];
        if (s2) v += s2[srow * DIMV + c];
        x[i] = v; sum += v;
    }
    #pragma unroll
    for (int o = 32; o > 0; o >>= 1) sum += __shfl_xor(sum, o);
    float mu = sum * (1.f / DIMV);
    float vs = 0.f;
    #pragma unroll
    for (int i = 0; i < 6; ++i) { float d = x[i] - mu; vs += d * d; }
    #pragma unroll
    for (int o = 32; o > 0; o >>= 1) vs += __shfl_xor(vs, o);
    float rstd = rsqrtf(vs * (1.f / DIMV) + 1e-3f);
    #pragma unroll
    for (int i = 0; i < 6; ++i) {
        int c = lane + i * 64;
        dst[row * DIMV + c] = (x[i] - mu) * rstd * g[c] + b[c];
    }
}

// ---------------------------------------------------------------------------
// Segment softmax-aggregation (segments = contiguous 24-row blocks).
// ---------------------------------------------------------------------------
__global__ __launch_bounds__(384)
void softagg_kernel(const float* __restrict__ gbuf, const float* __restrict__ fbuf,
                    float* __restrict__ y)
{
    const int p = blockIdx.x;
    const int col = threadIdx.x;
    const long base = (long)p * NFRAMESV * DIMV + col;
    float gv[NFRAMESV];
    float gmax = -INFINITY;
    #pragma unroll
    for (int r = 0; r < NFRAMESV; ++r) {
        gv[r] = gbuf[base + (long)r * DIMV];
        gmax = fmaxf(gmax, gv[r]);
    }
    float den = 0.f;
    #pragma unroll
    for (int r = 0; r < NFRAMESV; ++r) { gv[r] = expf(gv[r] - gmax); den += gv[r]; }
    float acc = 0.f;
    #pragma unroll
    for (int r = 0; r < NFRAMESV; ++r) acc += fbuf[base + (long)r * DIMV] * gv[r];
    y[(long)p * DIMV + col] = acc / den;
}

// net[e, d] += y2[e / NFRAMES, d]
__global__ __launch_bounds__(256)
void addseg_kernel(float* __restrict__ net, const float* __restrict__ y2)
{
    long idx = (long)blockIdx.x * 256 + threadIdx.x;
    long e = idx / DIMV;
    int d = (int)(idx % DIMV);
    net[idx] += y2[(e / NFRAMESV) * DIMV + d];
}

// ---------------------------------------------------------------------------
// RoPE + elu+1 on q and k in place ((d, d+24) pairs per thread).
// ---------------------------------------------------------------------------
__global__ __launch_bounds__(256)
void rope_kernel(float* __restrict__ q, float* __restrict__ k,
                 const float* __restrict__ pos, const int* __restrict__ flat)
{
    long idx = (long)blockIdx.x * 256 + threadIdx.x;          // E*8*24 threads
    long e = idx / (NHEADV * 24);
    int rem = (int)(idx % (NHEADV * 24));
    int h = rem / 24, d = rem % 24;
    int tok = flat[e];
    const float* cp = pos + (long)tok * HDV;
    const float* sp = pos + (long)ETOK * HDV + (long)tok * HDV;
    float c1 = cp[d], c2 = cp[d + 24], s1 = sp[d], s2 = sp[d + 24];
    long o1 = e * DIMV + h * HDV + d;
    long o2 = o1 + 24;

    float q1 = q[o1], q2 = q[o2];
    float r1 = q1 * c1 - q2 * s1;
    float r2 = q2 * c2 + q1 * s2;
    q[o1] = (r1 > 0.f) ? r1 + 1.f : expf(r1);   // elu(x)+1
    q[o2] = (r2 > 0.f) ? r2 + 1.f : expf(r2);

    float k1 = k[o1], k2 = k[o2];
    float t1 = k1 * c1 - k2 * s1;
    float t2 = k2 * c2 + k1 * s2;
    k[o1] = (t1 > 0.f) ? t1 + 1.f : expf(t1);
    k[o2] = (t2 > 0.f) ? t2 + 1.f : expf(t2);
}

// ---------------------------------------------------------------------------
// Gated linear attention core, one block per (group n, head h).
// ---------------------------------------------------------------------------
__global__ __launch_bounds__(256)
void attn_kernel(float* __restrict__ qo, const float* __restrict__ kbuf,
                 const float* __restrict__ vbuf)
{
    const int n = blockIdx.x, h = blockIdx.y;
    __shared__ float Qs[MTOK][HDV];
    __shared__ float Ks[MTOK][HDV];
    __shared__ float Vs[MTOK][HDV];
    __shared__ float KV[HDV][HDV];
    __shared__ float Ksum[HDV];
    __shared__ float Zs[MTOK];
    const int tid = threadIdx.x;

    for (int idx = tid; idx < MTOK * HDV; idx += 256) {
        int l = idx / HDV, d = idx % HDV;
        long off = ((long)n * MTOK + l) * DIMV + h * HDV + d;
        Qs[l][d] = qo[off];
        Ks[l][d] = kbuf[off];
        Vs[l][d] = vbuf[off];
    }
    __syncthreads();

    for (int idx = tid; idx < HDV * HDV; idx += 256) {
        int d = idx / HDV, dv = idx % HDV;
        float a = 0.f;
        #pragma unroll 8
        for (int l = 0; l < MTOK; ++l) a = fmaf(Ks[l][d], Vs[l][dv], a);
        KV[d][dv] = a;
    }
    if (tid < HDV) {
        float s = 0.f;
        #pragma unroll 8
        for (int l = 0; l < MTOK; ++l) s += Ks[l][tid];
        Ksum[tid] = s;
    }
    __syncthreads();

    if (tid < MTOK) {
        float s = 0.f;
        #pragma unroll
        for (int d = 0; d < HDV; ++d) s = fmaf(Qs[tid][d], Ksum[d], s);
        Zs[tid] = 1.f / (s + 1e-6f);
    }
    __syncthreads();

    for (int idx = tid; idx < MTOK * HDV; idx += 256) {
        int l = idx / HDV, dv = idx % HDV;
        float a = 0.f;
        #pragma unroll
        for (int d = 0; d < HDV; ++d) a = fmaf(Qs[l][d], KV[d][dv], a);
        qo[((long)n * MTOK + l) * DIMV + h * HDV + dv] = a * Zs[l];
    }
}

// out_net[flat[e], d] = tok[e, d] + sigmoid(gatepre[e, d]) * msg[e, d]
__global__ __launch_bounds__(256)
void combine_kernel(float* __restrict__ out_net, const float* __restrict__ tok,
                    const float* __restrict__ msg, const float* __restrict__ gatepre,
                    const int* __restrict__ flat)
{
    long idx = (long)blockIdx.x * 256 + threadIdx.x;
    long e = idx / DIMV;
    int d = (int)(idx % DIMV);
    float gate = 1.f / (1.f + expf(-gatepre[idx]));
    out_net[(long)flat[e] * DIMV + d] = tok[idx] + gate * msg[idx];
}

// d/w heads: one wave per row; 4 simultaneous 384-dots, shfl reduce.
__global__ __launch_bounds__(256)
void head_kernel(const float* __restrict__ net,
                 const float* __restrict__ Wd, const float* __restrict__ bd,
                 const float* __restrict__ Ww, const float* __restrict__ bw,
                 float* __restrict__ dout, float* __restrict__ wout)
{
    const int wave = threadIdx.x >> 6;
    const int lane = threadIdx.x & 63;
    const long row = (long)blockIdx.x * 4 + wave;
    const float* p = net + row * DIMV;
    float a0 = 0.f, a1 = 0.f, a2 = 0.f, a3 = 0.f;
    #pragma unroll
    for (int i = 0; i < 6; ++i) {
        int c = lane + i * 64;
        float r = fmaxf(p[c], 0.f);
        a0 = fmaf(r, Wd[c * 2 + 0], a0);
        a1 = fmaf(r, Wd[c * 2 + 1], a1);
        a2 = fmaf(r, Ww[c * 2 + 0], a2);
        a3 = fmaf(r, Ww[c * 2 + 1], a3);
    }
    #pragma unroll
    for (int o = 32; o > 0; o >>= 1) {
        a0 += __shfl_xor(a0, o);
        a1 += __shfl_xor(a1, o);
        a2 += __shfl_xor(a2, o);
        a3 += __shfl_xor(a3, o);
    }
    if (lane == 0) {
        dout[row * 2 + 0] = a0 + bd[0];
        dout[row * 2 + 1] = a1 + bd[1];
        wout[row * 2 + 0] = 1.f / (1.f + expf(-(a2 + bw[0])));
        wout[row * 2 + 1] = 1.f / (1.f + expf(-(a3 + bw[1])));
    }
}

extern "C" void kernel_launch(void* const* d_in, const int* in_sizes, int n_in,
                              void* d_out, int out_size, void* d_ws, size_t ws_size,
                              hipStream_t stream)
{
    const float* net_in = (const float*)d_in[0];
    const float* inp    = (const float*)d_in[1];
    const float* corr   = (const float*)d_in[2];
    const float* posenc = (const float*)d_in[4];
    const int*   ix     = (const int*)d_in[8];
    const int*   jx     = (const int*)d_in[9];
    const int*   flat   = (const int*)d_in[10];   // ij_ind flattened (E,)

    const float* Wc1 = (const float*)d_in[11]; const float* bc1 = (const float*)d_in[12];
    const float* Wc2 = (const float*)d_in[13]; const float* bc2 = (const float*)d_in[14];
    const float* g_lnc = (const float*)d_in[15]; const float* b_lnc = (const float*)d_in[16];
    const float* Wc3 = (const float*)d_in[17]; const float* bc3 = (const float*)d_in[18];
    const float* g_norm = (const float*)d_in[19]; const float* b_norm = (const float*)d_in[20];
    const float* W1a = (const float*)d_in[21]; const float* b1a = (const float*)d_in[22];
    const float* W1b = (const float*)d_in[23]; const float* b1b = (const float*)d_in[24];
    const float* W2a = (const float*)d_in[25]; const float* b2a = (const float*)d_in[26];
    const float* W2b = (const float*)d_in[27]; const float* b2b = (const float*)d_in[28];
    const float* Wf = (const float*)d_in[29]; const float* bf = (const float*)d_in[30];
    const float* Wg = (const float*)d_in[31]; const float* bg = (const float*)d_in[32];
    const float* Wh = (const float*)d_in[33]; const float* bh = (const float*)d_in[34];
    const float* g_norm2 = (const float*)d_in[35]; const float* b_norm2 = (const float*)d_in[36];
    const float* Wq = (const float*)d_in[37]; const float* bq = (const float*)d_in[38];
    const float* Wk = (const float*)d_in[39]; const float* bk = (const float*)d_in[40];
    const float* Wv = (const float*)d_in[41]; const float* bv = (const float*)d_in[42];
    const float* Wm = (const float*)d_in[43]; const float* bm = (const float*)d_in[44];
    const float* Wgt = (const float*)d_in[45]; const float* bgt = (const float*)d_in[46];
    const float* Wd = (const float*)d_in[47]; const float* bd = (const float*)d_in[48];
    const float* Ww = (const float*)d_in[49]; const float* bw = (const float*)d_in[50];

    const size_t EB = (size_t)ETOK * DIMV;
    float* B0 = (float*)d_ws;            // tokens (LN'd)
    float* B1 = B0 + EB;                 // running net / v / gate_pre
    float* B2 = B1 + EB;                 // scratch / q / attn out
    float* B3 = B2 + EB;                 // scratch / k / msg
    float* Y  = B3 + EB;                 // NPATCH x DIM
    float* Y2 = Y + (size_t)NPATCHV * DIMV;

    float* out_net = (float*)d_out;
    float* out_d = out_net + EB;
    float* out_w = out_d + (size_t)ETOK * 2;

    const dim3 gB(DIMV / 64, ETOK / 128);       // (6, 432)
    const dim3 gY(DIMV / 64, NPATCHV / 128);    // (6, 18)
    const int lnBlocks = ETOK / 4;              // 13824
    const int ewBlocks = (int)(EB / 256);       // 82944

    // corr encoder: c = linear(relu(ln(linear(relu(linear(corr))))))
    gemm_bf16<1, false, false><<<gB, 256, 0, stream>>>(corr, Wc1, bc1, B2, nullptr, CORR_DIMV, DIMV);
    gemm_bf16<0, false, false><<<gB, 256, 0, stream>>>(B2, Wc2, bc2, B3, nullptr, DIMV, DIMV);
    ln_kernel<<<lnBlocks, 256, 0, stream>>>(B3, B3, nullptr, nullptr, nullptr, g_lnc, b_lnc);
    gemm_bf16<0, false, true><<<gB, 256, 0, stream>>>(B3, Wc3, bc3, B2, nullptr, DIMV, DIMV);

    // net = LN(net + inp + c)
    ln_kernel<<<lnBlocks, 256, 0, stream>>>(B1, net_in, inp, B2, nullptr, g_norm, b_norm);

    // net += mlp2(mask_ix * net[ix])
    gemm_bf16<1, true, false><<<gB, 256, 0, stream>>>(B1, W1a, b1a, B2, ix, DIMV, DIMV);
    gemm_bf16<2, false, false><<<gB, 256, 0, stream>>>(B2, W1b, b1b, B1, nullptr, DIMV, DIMV);

    // net += mlp2(mask_jx * net[jx])
    gemm_bf16<1, true, false><<<gB, 256, 0, stream>>>(B1, W2a, b2a, B2, jx, DIMV, DIMV);
    gemm_bf16<2, false, false><<<gB, 256, 0, stream>>>(B2, W2b, b2b, B1, nullptr, DIMV, DIMV);

    // soft aggregation
    gemm_bf16<0, false, false><<<gB, 256, 0, stream>>>(B1, Wg, bg, B2, nullptr, DIMV, DIMV);
    gemm_bf16<0, false, false><<<gB, 256, 0, stream>>>(B1, Wf, bf, B3, nullptr, DIMV, DIMV);
    softagg_kernel<<<NPATCHV, 384, 0, stream>>>(B2, B3, Y);
    gemm_bf16<0, false, false><<<gY, 256, 0, stream>>>(Y, Wh, bh, Y2, nullptr, DIMV, DIMV);
    addseg_kernel<<<ewBlocks, 256, 0, stream>>>(B1, Y2);

    // tokens = LN(net[flat])
    ln_kernel<<<lnBlocks, 256, 0, stream>>>(B0, B1, nullptr, nullptr, flat, g_norm2, b_norm2);

    // q,k,v  (v reuses B1 — net no longer needed)
    gemm_bf16<0, false, false><<<gB, 256, 0, stream>>>(B0, Wq, bq, B2, nullptr, DIMV, DIMV);
    gemm_bf16<0, false, false><<<gB, 256, 0, stream>>>(B0, Wk, bk, B3, nullptr, DIMV, DIMV);
    gemm_bf16<0, false, false><<<gB, 256, 0, stream>>>(B0, Wv, bv, B1, nullptr, DIMV, DIMV);

    // RoPE + elu+1 on q,k
    {
        long total = (long)ETOK * NHEADV * 24;
        rope_kernel<<<(int)(total / 256), 256, 0, stream>>>(B2, B3, posenc, flat);
    }

    // linear attention (out written into B2)
    attn_kernel<<<dim3(NGRP, NHEADV), 256, 0, stream>>>(B2, B3, B1);

    // msg = out @ Wm + bm   (B3: k dead)
    gemm_bf16<0, false, false><<<gB, 256, 0, stream>>>(B2, Wm, bm, B3, nullptr, DIMV, DIMV);

    // gate_pre = tok @ Wgt[:384] + bgt + msg @ Wgt[384:]   (B1: v dead)
    gemm_bf16<0, false, false><<<gB, 256, 0, stream>>>(B0, Wgt, bgt, B1, nullptr, DIMV, DIMV);
    gemm_bf16<2, false, false><<<gB, 256, 0, stream>>>(B3, Wgt + (size_t)DIMV * DIMV, nullptr, B1, nullptr, DIMV, DIMV);

    // net_out[flat[e]] = tok + sigmoid(gate_pre) * msg
    combine_kernel<<<ewBlocks, 256, 0, stream>>>(out_net, B0, B3, B1, flat);

    // heads
    head_kernel<<<lnBlocks, 256, 0, stream>>>(out_net, Wd, bd, Ww, bw, out_d, out_w);
}

// Round 3
// 2026.933 us; speedup vs baseline: 2.5142x; 1.3390x over previous
//
#include <hip/hip_runtime.h>
#include <math.h>

#define DIMV 384
#define NHEADV 8
#define HDV 48
#define CORR_DIMV 882
#define NFRAMESV 24
#define PPIV 96
#define NPATCHV (NFRAMESV * PPIV)        // 2304
#define ETOK (NPATCHV * NFRAMESV)        // 55296
#define MTOK 96
#define NGRP (ETOK / MTOK)               // 576

using f32x4 = __attribute__((ext_vector_type(4))) float;
using s16x8 = __attribute__((ext_vector_type(8))) short;

__device__ __forceinline__ unsigned int f2bf(float x) {
    union { float f; unsigned int u; } c; c.f = x;
    unsigned int u = c.u;
    u += 0x7fffu + ((u >> 16) & 1u);   // round-to-nearest-even
    return u >> 16;
}

// Bijective XCD-chunked block swizzle (m204): consecutive tiles -> same XCD.
__device__ __forceinline__ void xcd_tile(int& colblk, int& rowblk) {
    const int nwg  = gridDim.x * gridDim.y;
    const int flat = blockIdx.y * gridDim.x + blockIdx.x;
    const int xcd  = flat & 7;
    const int base = flat >> 3;
    const int q = nwg >> 3, r = nwg & 7;
    const int nf = (xcd < r ? xcd * (q + 1) : r * (q + 1) + (xcd - r) * q) + base;
    colblk = nf % gridDim.x;
    rowblk = nf / gridDim.x;
}

// ---------------------------------------------------------------------------
// bf16 MFMA GEMM: C[M x N] = epi(A[M x K] @ W[K x N] + bias), f32 in/out.
// 128x64 block tile, 4 waves (2m x 2n), 2-phase register-prefetch K-loop,
// XCD-chunked tile swizzle.
// EPI: 0 = store, 1 = relu-store, 2 = accumulate into C
// GATHER: A row r is A[gidx[r]]; gidx[r] < 0 -> zero row. RELU_A: relu on A.
// ---------------------------------------------------------------------------
template<int EPI, bool GATHER, bool RELU_A>
__global__ __launch_bounds__(256)
void gemm_bf16(const float* __restrict__ A, const float* __restrict__ W,
               const float* __restrict__ bias, float* __restrict__ C,
               const int* __restrict__ gidx, int K, int N)
{
    int colblk, rowblk;
    xcd_tile(colblk, rowblk);
    const int row0 = rowblk * 128;
    const int col0 = colblk * 64;

    __shared__ __align__(16) unsigned short As[128][40];   // [m][k], pad 32->40
    __shared__ __align__(16) unsigned short Ws[64][40];    // [n][k], pad 32->40

    const int tid  = threadIdx.x;
    const int lane = tid & 63;
    const int wid  = tid >> 6;
    const int wm   = wid >> 1;          // 0..1
    const int wn   = wid & 1;           // 0..1

    // --- A staging geometry: 16 float2-slots x 16 row-blocks, 8 rows each ---
    const int af2 = tid & 15;           // float2 slot (k/2)
    const int arb = tid >> 4;           // row base 0..15
    // --- W staging geometry: n = tid>>2 (0..63), kq = tid&3 (8 k each) ---
    const int wn_s = tid >> 2;
    const int wkq  = tid & 3;

    // Gather rows are K-invariant: resolve once.
    long asrc[8];
    #pragma unroll
    for (int i = 0; i < 8; ++i) {
        const int r = arb + i * 16;
        long srow = row0 + r;
        if (GATHER) srow = gidx[row0 + r];
        asrc[i] = srow;
    }

    f32x4 acc[4][2] = {};
    float2 ra[8];
    float  rw[8];

    const int ntiles = (K + 31) >> 5;

    // ---- prologue: load tile 0 into registers ----
    {
        const int kk = af2 * 2;
        #pragma unroll
        for (int i = 0; i < 8; ++i) {
            float2 v = make_float2(0.f, 0.f);
            if ((!GATHER || asrc[i] >= 0) && kk < K)
                v = *(const float2*)(A + asrc[i] * (long)K + kk);
            ra[i] = v;
        }
        #pragma unroll
        for (int j = 0; j < 8; ++j) {
            const int kr = wkq * 8 + j;
            rw[j] = (kr < K) ? W[(long)kr * N + col0 + wn_s] : 0.f;
        }
    }

    for (int t = 0; t < ntiles; ++t) {
        // ---- write staged registers -> LDS (bf16 convert) ----
        #pragma unroll
        for (int i = 0; i < 8; ++i) {
            float v0 = ra[i].x, v1 = ra[i].y;
            if (RELU_A) { v0 = fmaxf(v0, 0.f); v1 = fmaxf(v1, 0.f); }
            *(unsigned int*)&As[arb + i * 16][af2 * 2] = f2bf(v0) | (f2bf(v1) << 16);
        }
        {
            union { unsigned short us[8]; int4 v; } wt;
            #pragma unroll
            for (int j = 0; j < 8; ++j) wt.us[j] = (unsigned short)f2bf(rw[j]);
            *(int4*)&Ws[wn_s][wkq * 8] = wt.v;
        }
        __syncthreads();

        // ---- prefetch tile t+1 into registers (overlaps MFMA below) ----
        if (t + 1 < ntiles) {
            const int k0n = (t + 1) << 5;
            const int kk = k0n + af2 * 2;
            #pragma unroll
            for (int i = 0; i < 8; ++i) {
                float2 v = make_float2(0.f, 0.f);
                if ((!GATHER || asrc[i] >= 0) && kk < K)
                    v = *(const float2*)(A + asrc[i] * (long)K + kk);
                ra[i] = v;
            }
            #pragma unroll
            for (int j = 0; j < 8; ++j) {
                const int kr = k0n + wkq * 8 + j;
                rw[j] = (kr < K) ? W[(long)kr * N + col0 + wn_s] : 0.f;
            }
        }

        // ---- fragments + MFMA ----
        {
            const int rsel  = lane & 15;
            const int khalf = (lane >> 4) * 8;
            s16x8 a[4], b[2];
            #pragma unroll
            for (int i = 0; i < 4; ++i)
                a[i] = *(const s16x8*)&As[wm * 64 + i * 16 + rsel][khalf];
            #pragma unroll
            for (int j = 0; j < 2; ++j)
                b[j] = *(const s16x8*)&Ws[wn * 32 + j * 16 + rsel][khalf];
            #pragma unroll
            for (int i = 0; i < 4; ++i)
                #pragma unroll
                for (int j = 0; j < 2; ++j)
                    acc[i][j] = __builtin_amdgcn_mfma_f32_16x16x32_bf16(a[i], b[j], acc[i][j], 0, 0, 0);
        }
        __syncthreads();
    }

    // ---- epilogue: C/D layout col=lane&15, row=(lane>>4)*4+reg ----
    const int ccol = lane & 15;
    const int rgrp = lane >> 4;
    #pragma unroll
    for (int i = 0; i < 4; ++i) {
        #pragma unroll
        for (int j = 0; j < 2; ++j) {
            const int col = col0 + wn * 32 + j * 16 + ccol;
            const long rbase = row0 + wm * 64 + i * 16 + rgrp * 4;
            const float bsv = bias ? bias[col] : 0.f;
            #pragma unroll
            for (int rr = 0; rr < 4; ++rr) {
                const long off = (rbase + rr) * (long)N + col;
                float v = acc[i][j][rr] + bsv;
                if (EPI == 1) v = fmaxf(v, 0.f);
                if (EPI == 2) v += C[off];
                C[off] = v;
            }
        }
    }
}

// ---------------------------------------------------------------------------
// LayerNorm over DIM=384, one wave per row (4 rows/block).
// dst[row] = LN(s0[srow] (+ s1[srow]) (+ s2[srow]) (+ seg[srow/24])) * g + b
// ---------------------------------------------------------------------------
__global__ __launch_bounds__(256)
void ln_kernel(float* __restrict__ dst, const float* __restrict__ s0,
               const float* __restrict__ s1, const float* __restrict__ s2,
               const float* __restrict__ seg,
               const int* __restrict__ gather,
               const float* __restrict__ g, const float* __restrict__ b)
{
    const int wave = threadIdx.x >> 6;
    const int lane = threadIdx.x & 63;
    const long row = (long)blockIdx.x * 4 + wave;
    const long srow = gather ? (long)gather[row] : row;

    float x[6];
    float sum = 0.f;
    #pragma unroll
    for (int i = 0; i < 6; ++i) {
        int c = lane + i * 64;
        float v = s0[srow * DIMV + c];
        if (s1) v += s1[srow * DIMV + c];
        if (s2) v += s2[srow * DIMV + c];
        if (seg) v += seg[(srow / NFRAMESV) * DIMV + c];
        x[i] = v; sum += v;
    }
    #pragma unroll
    for (int o = 32; o > 0; o >>= 1) sum += __shfl_xor(sum, o);
    float mu = sum * (1.f / DIMV);
    float vs = 0.f;
    #pragma unroll
    for (int i = 0; i < 6; ++i) { float d = x[i] - mu; vs += d * d; }
    #pragma unroll
    for (int o = 32; o > 0; o >>= 1) vs += __shfl_xor(vs, o);
    float rstd = rsqrtf(vs * (1.f / DIMV) + 1e-3f);
    #pragma unroll
    for (int i = 0; i < 6; ++i) {
        int c = lane + i * 64;
        dst[row * DIMV + c] = (x[i] - mu) * rstd * g[c] + b[c];
    }
}

// ---------------------------------------------------------------------------
// Segment softmax-aggregation (segments = contiguous 24-row blocks).
// ---------------------------------------------------------------------------
__global__ __launch_bounds__(384)
void softagg_kernel(const float* __restrict__ gbuf, const float* __restrict__ fbuf,
                    float* __restrict__ y)
{
    const int p = blockIdx.x;
    const int col = threadIdx.x;
    const long base = (long)p * NFRAMESV * DIMV + col;
    float gv[NFRAMESV];
    float gmax = -INFINITY;
    #pragma unroll
    for (int r = 0; r < NFRAMESV; ++r) {
        gv[r] = gbuf[base + (long)r * DIMV];
        gmax = fmaxf(gmax, gv[r]);
    }
    float den = 0.f;
    #pragma unroll
    for (int r = 0; r < NFRAMESV; ++r) { gv[r] = expf(gv[r] - gmax); den += gv[r]; }
    float acc = 0.f;
    #pragma unroll
    for (int r = 0; r < NFRAMESV; ++r) acc += fbuf[base + (long)r * DIMV] * gv[r];
    y[(long)p * DIMV + col] = acc / den;
}

// ---------------------------------------------------------------------------
// RoPE + elu+1 on q and k in place ((d, d+24) pairs per thread).
// ---------------------------------------------------------------------------
__global__ __launch_bounds__(256)
void rope_kernel(float* __restrict__ q, float* __restrict__ k,
                 const float* __restrict__ pos, const int* __restrict__ flat)
{
    long idx = (long)blockIdx.x * 256 + threadIdx.x;          // E*8*24 threads
    long e = idx / (NHEADV * 24);
    int rem = (int)(idx % (NHEADV * 24));
    int h = rem / 24, d = rem % 24;
    int tok = flat[e];
    const float* cp = pos + (long)tok * HDV;
    const float* sp = pos + (long)ETOK * HDV + (long)tok * HDV;
    float c1 = cp[d], c2 = cp[d + 24], s1 = sp[d], s2 = sp[d + 24];
    long o1 = e * DIMV + h * HDV + d;
    long o2 = o1 + 24;

    float q1 = q[o1], q2 = q[o2];
    float r1 = q1 * c1 - q2 * s1;
    float r2 = q2 * c2 + q1 * s2;
    q[o1] = (r1 > 0.f) ? r1 + 1.f : expf(r1);   // elu(x)+1
    q[o2] = (r2 > 0.f) ? r2 + 1.f : expf(r2);

    float k1 = k[o1], k2 = k[o2];
    float t1 = k1 * c1 - k2 * s1;
    float t2 = k2 * c2 + k1 * s2;
    k[o1] = (t1 > 0.f) ? t1 + 1.f : expf(t1);
    k[o2] = (t2 > 0.f) ? t2 + 1.f : expf(t2);
}

// ---------------------------------------------------------------------------
// Gated linear attention core, one block per (group n, head h).
// ---------------------------------------------------------------------------
__global__ __launch_bounds__(256)
void attn_kernel(float* __restrict__ qo, const float* __restrict__ kbuf,
                 const float* __restrict__ vbuf)
{
    const int n = blockIdx.x, h = blockIdx.y;
    __shared__ float Qs[MTOK][HDV];
    __shared__ float Ks[MTOK][HDV];
    __shared__ float Vs[MTOK][HDV];
    __shared__ float KV[HDV][HDV];
    __shared__ float Ksum[HDV];
    __shared__ float Zs[MTOK];
    const int tid = threadIdx.x;

    for (int idx = tid; idx < MTOK * HDV; idx += 256) {
        int l = idx / HDV, d = idx % HDV;
        long off = ((long)n * MTOK + l) * DIMV + h * HDV + d;
        Qs[l][d] = qo[off];
        Ks[l][d] = kbuf[off];
        Vs[l][d] = vbuf[off];
    }
    __syncthreads();

    for (int idx = tid; idx < HDV * HDV; idx += 256) {
        int d = idx / HDV, dv = idx % HDV;
        float a = 0.f;
        #pragma unroll 8
        for (int l = 0; l < MTOK; ++l) a = fmaf(Ks[l][d], Vs[l][dv], a);
        KV[d][dv] = a;
    }
    if (tid < HDV) {
        float s = 0.f;
        #pragma unroll 8
        for (int l = 0; l < MTOK; ++l) s += Ks[l][tid];
        Ksum[tid] = s;
    }
    __syncthreads();

    if (tid < MTOK) {
        float s = 0.f;
        #pragma unroll
        for (int d = 0; d < HDV; ++d) s = fmaf(Qs[tid][d], Ksum[d], s);
        Zs[tid] = 1.f / (s + 1e-6f);
    }
    __syncthreads();

    for (int idx = tid; idx < MTOK * HDV; idx += 256) {
        int l = idx / HDV, dv = idx % HDV;
        float a = 0.f;
        #pragma unroll
        for (int d = 0; d < HDV; ++d) a = fmaf(Qs[l][d], KV[d][dv], a);
        qo[((long)n * MTOK + l) * DIMV + h * HDV + dv] = a * Zs[l];
    }
}

// out_net[flat[e], d] = tok[e, d] + sigmoid(gatepre[e, d]) * msg[e, d]
__global__ __launch_bounds__(256)
void combine_kernel(float* __restrict__ out_net, const float* __restrict__ tok,
                    const float* __restrict__ msg, const float* __restrict__ gatepre,
                    const int* __restrict__ flat)
{
    long idx = (long)blockIdx.x * 256 + threadIdx.x;
    long e = idx / DIMV;
    int d = (int)(idx % DIMV);
    float gate = 1.f / (1.f + expf(-gatepre[idx]));
    out_net[(long)flat[e] * DIMV + d] = tok[idx] + gate * msg[idx];
}

// d/w heads: one wave per row; 4 simultaneous 384-dots, shfl reduce.
__global__ __launch_bounds__(256)
void head_kernel(const float* __restrict__ net,
                 const float* __restrict__ Wd, const float* __restrict__ bd,
                 const float* __restrict__ Ww, const float* __restrict__ bw,
                 float* __restrict__ dout, float* __restrict__ wout)
{
    const int wave = threadIdx.x >> 6;
    const int lane = threadIdx.x & 63;
    const long row = (long)blockIdx.x * 4 + wave;
    const float* p = net + row * DIMV;
    float a0 = 0.f, a1 = 0.f, a2 = 0.f, a3 = 0.f;
    #pragma unroll
    for (int i = 0; i < 6; ++i) {
        int c = lane + i * 64;
        float r = fmaxf(p[c], 0.f);
        a0 = fmaf(r, Wd[c * 2 + 0], a0);
        a1 = fmaf(r, Wd[c * 2 + 1], a1);
        a2 = fmaf(r, Ww[c * 2 + 0], a2);
        a3 = fmaf(r, Ww[c * 2 + 1], a3);
    }
    #pragma unroll
    for (int o = 32; o > 0; o >>= 1) {
        a0 += __shfl_xor(a0, o);
        a1 += __shfl_xor(a1, o);
        a2 += __shfl_xor(a2, o);
        a3 += __shfl_xor(a3, o);
    }
    if (lane == 0) {
        dout[row * 2 + 0] = a0 + bd[0];
        dout[row * 2 + 1] = a1 + bd[1];
        wout[row * 2 + 0] = 1.f / (1.f + expf(-(a2 + bw[0])));
        wout[row * 2 + 1] = 1.f / (1.f + expf(-(a3 + bw[1])));
    }
}

extern "C" void kernel_launch(void* const* d_in, const int* in_sizes, int n_in,
                              void* d_out, int out_size, void* d_ws, size_t ws_size,
                              hipStream_t stream)
{
    const float* net_in = (const float*)d_in[0];
    const float* inp    = (const float*)d_in[1];
    const float* corr   = (const float*)d_in[2];
    const float* posenc = (const float*)d_in[4];
    const int*   ix     = (const int*)d_in[8];
    const int*   jx     = (const int*)d_in[9];
    const int*   flat   = (const int*)d_in[10];   // ij_ind flattened (E,)

    const float* Wc1 = (const float*)d_in[11]; const float* bc1 = (const float*)d_in[12];
    const float* Wc2 = (const float*)d_in[13]; const float* bc2 = (const float*)d_in[14];
    const float* g_lnc = (const float*)d_in[15]; const float* b_lnc = (const float*)d_in[16];
    const float* Wc3 = (const float*)d_in[17]; const float* bc3 = (const float*)d_in[18];
    const float* g_norm = (const float*)d_in[19]; const float* b_norm = (const float*)d_in[20];
    const float* W1a = (const float*)d_in[21]; const float* b1a = (const float*)d_in[22];
    const float* W1b = (const float*)d_in[23]; const float* b1b = (const float*)d_in[24];
    const float* W2a = (const float*)d_in[25]; const float* b2a = (const float*)d_in[26];
    const float* W2b = (const float*)d_in[27]; const float* b2b = (const float*)d_in[28];
    const float* Wf = (const float*)d_in[29]; const float* bf = (const float*)d_in[30];
    const float* Wg = (const float*)d_in[31]; const float* bg = (const float*)d_in[32];
    const float* Wh = (const float*)d_in[33]; const float* bh = (const float*)d_in[34];
    const float* g_norm2 = (const float*)d_in[35]; const float* b_norm2 = (const float*)d_in[36];
    const float* Wq = (const float*)d_in[37]; const float* bq = (const float*)d_in[38];
    const float* Wk = (const float*)d_in[39]; const float* bk = (const float*)d_in[40];
    const float* Wv = (const float*)d_in[41]; const float* bv = (const float*)d_in[42];
    const float* Wm = (const float*)d_in[43]; const float* bm = (const float*)d_in[44];
    const float* Wgt = (const float*)d_in[45]; const float* bgt = (const float*)d_in[46];
    const float* Wd = (const float*)d_in[47]; const float* bd = (const float*)d_in[48];
    const float* Ww = (const float*)d_in[49]; const float* bw = (const float*)d_in[50];

    const size_t EB = (size_t)ETOK * DIMV;
    float* B0 = (float*)d_ws;            // tokens (LN'd)
    float* B1 = B0 + EB;                 // running net / v / gate_pre
    float* B2 = B1 + EB;                 // scratch / q / attn out
    float* B3 = B2 + EB;                 // scratch / k / msg
    float* Y  = B3 + EB;                 // NPATCH x DIM
    float* Y2 = Y + (size_t)NPATCHV * DIMV;

    float* out_net = (float*)d_out;
    float* out_d = out_net + EB;
    float* out_w = out_d + (size_t)ETOK * 2;

    const dim3 gB(DIMV / 64, ETOK / 128);       // (6, 432)
    const dim3 gY(DIMV / 64, NPATCHV / 128);    // (6, 18)
    const int lnBlocks = ETOK / 4;              // 13824
    const int ewBlocks = (int)(EB / 256);       // 82944

    // corr encoder: c = linear(relu(ln(linear(relu(linear(corr))))))
    gemm_bf16<1, false, false><<<gB, 256, 0, stream>>>(corr, Wc1, bc1, B2, nullptr, CORR_DIMV, DIMV);
    gemm_bf16<0, false, false><<<gB, 256, 0, stream>>>(B2, Wc2, bc2, B3, nullptr, DIMV, DIMV);
    ln_kernel<<<lnBlocks, 256, 0, stream>>>(B3, B3, nullptr, nullptr, nullptr, nullptr, g_lnc, b_lnc);
    gemm_bf16<0, false, true><<<gB, 256, 0, stream>>>(B3, Wc3, bc3, B2, nullptr, DIMV, DIMV);

    // net = LN(net + inp + c)
    ln_kernel<<<lnBlocks, 256, 0, stream>>>(B1, net_in, inp, B2, nullptr, nullptr, g_norm, b_norm);

    // net += mlp2(mask_ix * net[ix])
    gemm_bf16<1, true, false><<<gB, 256, 0, stream>>>(B1, W1a, b1a, B2, ix, DIMV, DIMV);
    gemm_bf16<2, false, false><<<gB, 256, 0, stream>>>(B2, W1b, b1b, B1, nullptr, DIMV, DIMV);

    // net += mlp2(mask_jx * net[jx])
    gemm_bf16<1, true, false><<<gB, 256, 0, stream>>>(B1, W2a, b2a, B2, jx, DIMV, DIMV);
    gemm_bf16<2, false, false><<<gB, 256, 0, stream>>>(B2, W2b, b2b, B1, nullptr, DIMV, DIMV);

    // soft aggregation
    gemm_bf16<0, false, false><<<gB, 256, 0, stream>>>(B1, Wg, bg, B2, nullptr, DIMV, DIMV);
    gemm_bf16<0, false, false><<<gB, 256, 0, stream>>>(B1, Wf, bf, B3, nullptr, DIMV, DIMV);
    softagg_kernel<<<NPATCHV, 384, 0, stream>>>(B2, B3, Y);
    gemm_bf16<0, false, false><<<gY, 256, 0, stream>>>(Y, Wh, bh, Y2, nullptr, DIMV, DIMV);

    // tokens = LN(net[flat] + Y2[flat/24])   (addseg fused into gather-LN)
    ln_kernel<<<lnBlocks, 256, 0, stream>>>(B0, B1, nullptr, nullptr, Y2, flat, g_norm2, b_norm2);

    // q,k,v  (v reuses B1 — net no longer needed)
    gemm_bf16<0, false, false><<<gB, 256, 0, stream>>>(B0, Wq, bq, B2, nullptr, DIMV, DIMV);
    gemm_bf16<0, false, false><<<gB, 256, 0, stream>>>(B0, Wk, bk, B3, nullptr, DIMV, DIMV);
    gemm_bf16<0, false, false><<<gB, 256, 0, stream>>>(B0, Wv, bv, B1, nullptr, DIMV, DIMV);

    // RoPE + elu+1 on q,k
    {
        long total = (long)ETOK * NHEADV * 24;
        rope_kernel<<<(int)(total / 256), 256, 0, stream>>>(B2, B3, posenc, flat);
    }

    // linear attention (out written into B2)
    attn_kernel<<<dim3(NGRP, NHEADV), 256, 0, stream>>>(B2, B3, B1);

    // msg = out @ Wm + bm   (B3: k dead)
    gemm_bf16<0, false, false><<<gB, 256, 0, stream>>>(B2, Wm, bm, B3, nullptr, DIMV, DIMV);

    // gate_pre = tok @ Wgt[:384] + bgt + msg @ Wgt[384:]   (B1: v dead)
    gemm_bf16<0, false, false><<<gB, 256, 0, stream>>>(B0, Wgt, bgt, B1, nullptr, DIMV, DIMV);
    gemm_bf16<2, false, false><<<gB, 256, 0, stream>>>(B3, Wgt + (size_t)DIMV * DIMV, nullptr, B1, nullptr, DIMV, DIMV);

    // net_out[flat[e]] = tok + sigmoid(gate_pre) * msg
    combine_kernel<<<ewBlocks, 256, 0, stream>>>(out_net, B0, B3, B1, flat);

    // heads
    head_kernel<<<lnBlocks, 256, 0, stream>>>(out_net, Wd, bd, Ww, bw, out_d, out_w);
}

// Round 4
// 1784.982 us; speedup vs baseline: 2.8550x; 1.1355x over previous
//
#include <hip/hip_runtime.h>
#include <math.h>

#define DIMV 384
#define NHEADV 8
#define HDV 48
#define CORR_DIMV 882
#define NFRAMESV 24
#define PPIV 96
#define NPATCHV (NFRAMESV * PPIV)        // 2304
#define ETOK (NPATCHV * NFRAMESV)        // 55296
#define MTOK 96
#define NGRP (ETOK / MTOK)               // 576

using f32x4 = __attribute__((ext_vector_type(4))) float;
using s16x8 = __attribute__((ext_vector_type(8))) short;

__device__ __forceinline__ unsigned int f2bf(float x) {
    union { float f; unsigned int u; } c; c.f = x;
    unsigned int u = c.u;
    u += 0x7fffu + ((u >> 16) & 1u);   // round-to-nearest-even
    return u >> 16;
}

// Bijective XCD-chunked block swizzle (m204): consecutive tiles -> same XCD.
__device__ __forceinline__ void xcd_tile(int& colblk, int& rowblk) {
    const int nwg  = gridDim.x * gridDim.y;
    const int flat = blockIdx.y * gridDim.x + blockIdx.x;
    const int xcd  = flat & 7;
    const int base = flat >> 3;
    const int q = nwg >> 3, r = nwg & 7;
    const int nf = (xcd < r ? xcd * (q + 1) : r * (q + 1) + (xcd - r) * q) + base;
    colblk = nf % gridDim.x;
    rowblk = nf / gridDim.x;
}

// ---------------------------------------------------------------------------
// bf16 MFMA GEMM: C[M x N] = epi(A[M x K] @ W[K x N] + bias), f32 in/out.
// 128x64 block tile, 4 waves (2m x 2n), 2-phase register-prefetch K-loop,
// XCD-chunked tile swizzle.
// EPI: 0 = store, 1 = relu-store, 2 = accumulate into C
// GATHER: A row r is A[gidx[r]]; gidx[r] < 0 -> zero row. RELU_A: relu on A.
// ---------------------------------------------------------------------------
template<int EPI, bool GATHER, bool RELU_A>
__global__ __launch_bounds__(256)
void gemm_bf16(const float* __restrict__ A, const float* __restrict__ W,
               const float* __restrict__ bias, float* __restrict__ C,
               const int* __restrict__ gidx, int K, int N)
{
    int colblk, rowblk;
    xcd_tile(colblk, rowblk);
    const int row0 = rowblk * 128;
    const int col0 = colblk * 64;

    __shared__ __align__(16) unsigned short As[128][40];   // [m][k], pad 32->40
    __shared__ __align__(16) unsigned short Ws[64][40];    // [n][k], pad 32->40

    const int tid  = threadIdx.x;
    const int lane = tid & 63;
    const int wid  = tid >> 6;
    const int wm   = wid >> 1;          // 0..1
    const int wn   = wid & 1;           // 0..1

    // --- A staging geometry: 16 float2-slots x 16 row-blocks, 8 rows each ---
    const int af2 = tid & 15;           // float2 slot (k/2)
    const int arb = tid >> 4;           // row base 0..15
    // --- W staging geometry: n = tid>>2 (0..63), kq = tid&3 (8 k each) ---
    const int wn_s = tid >> 2;
    const int wkq  = tid & 3;

    // Gather rows are K-invariant: resolve once.
    long asrc[8];
    #pragma unroll
    for (int i = 0; i < 8; ++i) {
        const int r = arb + i * 16;
        long srow = row0 + r;
        if (GATHER) srow = gidx[row0 + r];
        asrc[i] = srow;
    }

    f32x4 acc[4][2] = {};
    float2 ra[8];
    float  rw[8];

    const int ntiles = (K + 31) >> 5;

    // ---- prologue: load tile 0 into registers ----
    {
        const int kk = af2 * 2;
        #pragma unroll
        for (int i = 0; i < 8; ++i) {
            float2 v = make_float2(0.f, 0.f);
            if ((!GATHER || asrc[i] >= 0) && kk < K)
                v = *(const float2*)(A + asrc[i] * (long)K + kk);
            ra[i] = v;
        }
        #pragma unroll
        for (int j = 0; j < 8; ++j) {
            const int kr = wkq * 8 + j;
            rw[j] = (kr < K) ? W[(long)kr * N + col0 + wn_s] : 0.f;
        }
    }

    for (int t = 0; t < ntiles; ++t) {
        // ---- write staged registers -> LDS (bf16 convert) ----
        #pragma unroll
        for (int i = 0; i < 8; ++i) {
            float v0 = ra[i].x, v1 = ra[i].y;
            if (RELU_A) { v0 = fmaxf(v0, 0.f); v1 = fmaxf(v1, 0.f); }
            *(unsigned int*)&As[arb + i * 16][af2 * 2] = f2bf(v0) | (f2bf(v1) << 16);
        }
        {
            union { unsigned short us[8]; int4 v; } wt;
            #pragma unroll
            for (int j = 0; j < 8; ++j) wt.us[j] = (unsigned short)f2bf(rw[j]);
            *(int4*)&Ws[wn_s][wkq * 8] = wt.v;
        }
        __syncthreads();

        // ---- prefetch tile t+1 into registers (overlaps MFMA below) ----
        if (t + 1 < ntiles) {
            const int k0n = (t + 1) << 5;
            const int kk = k0n + af2 * 2;
            #pragma unroll
            for (int i = 0; i < 8; ++i) {
                float2 v = make_float2(0.f, 0.f);
                if ((!GATHER || asrc[i] >= 0) && kk < K)
                    v = *(const float2*)(A + asrc[i] * (long)K + kk);
                ra[i] = v;
            }
            #pragma unroll
            for (int j = 0; j < 8; ++j) {
                const int kr = k0n + wkq * 8 + j;
                rw[j] = (kr < K) ? W[(long)kr * N + col0 + wn_s] : 0.f;
            }
        }

        // ---- fragments + MFMA ----
        {
            const int rsel  = lane & 15;
            const int khalf = (lane >> 4) * 8;
            s16x8 a[4], b[2];
            #pragma unroll
            for (int i = 0; i < 4; ++i)
                a[i] = *(const s16x8*)&As[wm * 64 + i * 16 + rsel][khalf];
            #pragma unroll
            for (int j = 0; j < 2; ++j)
                b[j] = *(const s16x8*)&Ws[wn * 32 + j * 16 + rsel][khalf];
            #pragma unroll
            for (int i = 0; i < 4; ++i)
                #pragma unroll
                for (int j = 0; j < 2; ++j)
                    acc[i][j] = __builtin_amdgcn_mfma_f32_16x16x32_bf16(a[i], b[j], acc[i][j], 0, 0, 0);
        }
        __syncthreads();
    }

    // ---- epilogue: C/D layout col=lane&15, row=(lane>>4)*4+reg ----
    const int ccol = lane & 15;
    const int rgrp = lane >> 4;
    #pragma unroll
    for (int i = 0; i < 4; ++i) {
        #pragma unroll
        for (int j = 0; j < 2; ++j) {
            const int col = col0 + wn * 32 + j * 16 + ccol;
            const long rbase = row0 + wm * 64 + i * 16 + rgrp * 4;
            const float bsv = bias ? bias[col] : 0.f;
            #pragma unroll
            for (int rr = 0; rr < 4; ++rr) {
                const long off = (rbase + rr) * (long)N + col;
                float v = acc[i][j][rr] + bsv;
                if (EPI == 1) v = fmaxf(v, 0.f);
                if (EPI == 2) v += C[off];
                C[off] = v;
            }
        }
    }
}

// ---------------------------------------------------------------------------
// LayerNorm over DIM=384, one wave per row (4 rows/block).
// dst[row] = LN(s0[srow] (+ s1[srow]) (+ s2[srow]) (+ seg[srow/24])) * g + b
// ---------------------------------------------------------------------------
__global__ __launch_bounds__(256)
void ln_kernel(float* __restrict__ dst, const float* __restrict__ s0,
               const float* __restrict__ s1, const float* __restrict__ s2,
               const float* __restrict__ seg,
               const int* __restrict__ gather,
               const float* __restrict__ g, const float* __restrict__ b)
{
    const int wave = threadIdx.x >> 6;
    const int lane = threadIdx.x & 63;
    const long row = (long)blockIdx.x * 4 + wave;
    const long srow = gather ? (long)gather[row] : row;

    float x[6];
    float sum = 0.f;
    #pragma unroll
    for (int i = 0; i < 6; ++i) {
        int c = lane + i * 64;
        float v = s0[srow * DIMV + c];
        if (s1) v += s1[srow * DIMV + c];
        if (s2) v += s2[srow * DIMV + c];
        if (seg) v += seg[(srow / NFRAMESV) * DIMV + c];
        x[i] = v; sum += v;
    }
    #pragma unroll
    for (int o = 32; o > 0; o >>= 1) sum += __shfl_xor(sum, o);
    float mu = sum * (1.f / DIMV);
    float vs = 0.f;
    #pragma unroll
    for (int i = 0; i < 6; ++i) { float d = x[i] - mu; vs += d * d; }
    #pragma unroll
    for (int o = 32; o > 0; o >>= 1) vs += __shfl_xor(vs, o);
    float rstd = rsqrtf(vs * (1.f / DIMV) + 1e-3f);
    #pragma unroll
    for (int i = 0; i < 6; ++i) {
        int c = lane + i * 64;
        dst[row * DIMV + c] = (x[i] - mu) * rstd * g[c] + b[c];
    }
}

// ---------------------------------------------------------------------------
// Segment softmax-aggregation (segments = contiguous 24-row blocks).
// ---------------------------------------------------------------------------
__global__ __launch_bounds__(384)
void softagg_kernel(const float* __restrict__ gbuf, const float* __restrict__ fbuf,
                    float* __restrict__ y)
{
    const int p = blockIdx.x;
    const int col = threadIdx.x;
    const long base = (long)p * NFRAMESV * DIMV + col;
    float gv[NFRAMESV];
    float gmax = -INFINITY;
    #pragma unroll
    for (int r = 0; r < NFRAMESV; ++r) {
        gv[r] = gbuf[base + (long)r * DIMV];
        gmax = fmaxf(gmax, gv[r]);
    }
    float den = 0.f;
    #pragma unroll
    for (int r = 0; r < NFRAMESV; ++r) { gv[r] = expf(gv[r] - gmax); den += gv[r]; }
    float acc = 0.f;
    #pragma unroll
    for (int r = 0; r < NFRAMESV; ++r) acc += fbuf[base + (long)r * DIMV] * gv[r];
    y[(long)p * DIMV + col] = acc / den;
}

// ---------------------------------------------------------------------------
// RoPE + elu+1 on q and k in place ((d, d+24) pairs per thread).
// ---------------------------------------------------------------------------
__global__ __launch_bounds__(256)
void rope_kernel(float* __restrict__ q, float* __restrict__ k,
                 const float* __restrict__ pos, const int* __restrict__ flat)
{
    long idx = (long)blockIdx.x * 256 + threadIdx.x;          // E*8*24 threads
    long e = idx / (NHEADV * 24);
    int rem = (int)(idx % (NHEADV * 24));
    int h = rem / 24, d = rem % 24;
    int tok = flat[e];
    const float* cp = pos + (long)tok * HDV;
    const float* sp = pos + (long)ETOK * HDV + (long)tok * HDV;
    float c1 = cp[d], c2 = cp[d + 24], s1 = sp[d], s2 = sp[d + 24];
    long o1 = e * DIMV + h * HDV + d;
    long o2 = o1 + 24;

    float q1 = q[o1], q2 = q[o2];
    float r1 = q1 * c1 - q2 * s1;
    float r2 = q2 * c2 + q1 * s2;
    q[o1] = (r1 > 0.f) ? r1 + 1.f : expf(r1);   // elu(x)+1
    q[o2] = (r2 > 0.f) ? r2 + 1.f : expf(r2);

    float k1 = k[o1], k2 = k[o2];
    float t1 = k1 * c1 - k2 * s1;
    float t2 = k2 * c2 + k1 * s2;
    k[o1] = (t1 > 0.f) ? t1 + 1.f : expf(t1);
    k[o2] = (t2 > 0.f) ? t2 + 1.f : expf(t2);
}

// ---------------------------------------------------------------------------
// Gated linear attention core — MFMA version, one WAVE per (group n, head h),
// 4 waves/block, per-wave LDS slices, no barriers.
//   KV[d][dv]  = sum_l K[l][d] V[l][dv]      (27 mfma 16x16x32, K=96)
//   Ksum[d]    = sum_l K[l][d]               (free, from A-frag loads + shfl)
//   denom[l]   = sum_d Q[l][d] Ksum[d]       (VALU during Q-frag load)
//   out[l][dv] = (sum_d Q[l][d] KV[d][dv]) / (denom[l]+1e-6)   (36 mfma)
// KV staged in LDS as bf16 [dv][d-pad64] with 16B XOR swizzle (bank-safe).
// ---------------------------------------------------------------------------
__global__ __launch_bounds__(256)
void attn_kernel(float* __restrict__ qo, const float* __restrict__ kbuf,
                 const float* __restrict__ vbuf)
{
    __shared__ unsigned short KVt[4][48][64];   // per-wave bf16 KV^T, swizzled
    __shared__ float KsumS[4][48];
    __shared__ float ZlS[4][96];

    const int tid  = threadIdx.x;
    const int wid  = tid >> 6;
    const int lane = tid & 63;
    const int task = blockIdx.x * 4 + wid;       // 4608 tasks
    const int n = task >> 3, h = task & 7;

    const long base = ((long)n * MTOK) * DIMV + h * HDV;

    const int c16   = lane & 15;
    const int kq    = lane >> 4;    // 0..3
    const int khalf = kq * 8;

    // zero logical d=48..63 pad rows of KVt (physical = logical ^ swizzle)
    if (lane < 48) {
        const int s = (lane & 7) << 3;
        const uint4 z = make_uint4(0u, 0u, 0u, 0u);
        *(uint4*)&KVt[wid][lane][48 ^ s] = z;
        *(uint4*)&KVt[wid][lane][56 ^ s] = z;
    }

    // ---- KV = K^T V via MFMA; Ksum accumulated from the same K loads ----
    f32x4 kv[3][3] = {};
    float ksum_p[3] = {0.f, 0.f, 0.f};

    for (int ks = 0; ks < 3; ++ks) {
        const int l0 = ks * 32 + khalf;
        s16x8 afr[3], bfr[3];
        #pragma unroll
        for (int mf = 0; mf < 3; ++mf) {
            const int d = mf * 16 + c16;
            union { unsigned short us[8]; s16x8 v; } pk;
            float s = 0.f;
            #pragma unroll
            for (int j = 0; j < 8; ++j) {
                const float kval = kbuf[base + (long)(l0 + j) * DIMV + d];
                s += kval;
                pk.us[j] = (unsigned short)f2bf(kval);
            }
            ksum_p[mf] += s;
            afr[mf] = pk.v;
        }
        #pragma unroll
        for (int nf = 0; nf < 3; ++nf) {
            const int dv = nf * 16 + c16;
            union { unsigned short us[8]; s16x8 v; } pk;
            #pragma unroll
            for (int j = 0; j < 8; ++j)
                pk.us[j] = (unsigned short)f2bf(vbuf[base + (long)(l0 + j) * DIMV + dv]);
            bfr[nf] = pk.v;
        }
        #pragma unroll
        for (int mf = 0; mf < 3; ++mf)
            #pragma unroll
            for (int nf = 0; nf < 3; ++nf)
                kv[mf][nf] = __builtin_amdgcn_mfma_f32_16x16x32_bf16(afr[mf], bfr[nf], kv[mf][nf], 0, 0, 0);
    }

    // Ksum: reduce over the 4 lane-quarters (each holds 24 of the 96 l's)
    #pragma unroll
    for (int mf = 0; mf < 3; ++mf) {
        float s = ksum_p[mf];
        s += __shfl_xor(s, 16);
        s += __shfl_xor(s, 32);
        if (kq == 0) KsumS[wid][mf * 16 + c16] = s;
    }

    // KV fragments -> LDS bf16 [dv][d] (C layout: col=dv=lane&15, row=d=kq*4+rr)
    #pragma unroll
    for (int mf = 0; mf < 3; ++mf) {
        #pragma unroll
        for (int nf = 0; nf < 3; ++nf) {
            const int dv = nf * 16 + c16;
            const int d0 = (mf * 16 + kq * 4) ^ ((dv & 7) << 3);
            uint2 w;
            w.x = f2bf(kv[mf][nf][0]) | (f2bf(kv[mf][nf][1]) << 16);
            w.y = f2bf(kv[mf][nf][2]) | (f2bf(kv[mf][nf][3]) << 16);
            *(uint2*)&KVt[wid][dv][d0] = w;
        }
    }

    // ---- Q fragments (float4 loads) + Z denominators ----
    s16x8 qf[6][2];
    const s16x8 zfrag = {0, 0, 0, 0, 0, 0, 0, 0};
    #pragma unroll
    for (int mf = 0; mf < 6; ++mf) {
        const int l = mf * 16 + c16;
        float dsum = 0.f;
        #pragma unroll
        for (int ks = 0; ks < 2; ++ks) {
            if (ks == 0 || kq < 2) {          // d < 48 region only
                const int d = ks * 32 + khalf;
                const float* qp = qo + base + (long)l * DIMV + d;
                const float4 v0 = *(const float4*)qp;
                const float4 v1 = *(const float4*)(qp + 4);
                dsum += v0.x * KsumS[wid][d]     + v0.y * KsumS[wid][d + 1]
                      + v0.z * KsumS[wid][d + 2] + v0.w * KsumS[wid][d + 3]
                      + v1.x * KsumS[wid][d + 4] + v1.y * KsumS[wid][d + 5]
                      + v1.z * KsumS[wid][d + 6] + v1.w * KsumS[wid][d + 7];
                union { unsigned short us[8]; s16x8 v; } pk;
                pk.us[0] = (unsigned short)f2bf(v0.x);
                pk.us[1] = (unsigned short)f2bf(v0.y);
                pk.us[2] = (unsigned short)f2bf(v0.z);
                pk.us[3] = (unsigned short)f2bf(v0.w);
                pk.us[4] = (unsigned short)f2bf(v1.x);
                pk.us[5] = (unsigned short)f2bf(v1.y);
                pk.us[6] = (unsigned short)f2bf(v1.z);
                pk.us[7] = (unsigned short)f2bf(v1.w);
                qf[mf][ks] = pk.v;
            } else {
                qf[mf][ks] = zfrag;
            }
        }
        dsum += __shfl_xor(dsum, 16);
        dsum += __shfl_xor(dsum, 32);
        if (kq == 0) ZlS[wid][l] = 1.f / (dsum + 1e-6f);
    }

    // ---- out = (Q @ KV) * Z ----
    #pragma unroll
    for (int nf = 0; nf < 3; ++nf) {
        const int dv = nf * 16 + c16;
        const int sw = (dv & 7) << 3;
        const s16x8 b0 = *(const s16x8*)&KVt[wid][dv][khalf ^ sw];
        const s16x8 b1 = *(const s16x8*)&KVt[wid][dv][(32 + khalf) ^ sw];
        #pragma unroll
        for (int mf = 0; mf < 6; ++mf) {
            f32x4 a = {};
            a = __builtin_amdgcn_mfma_f32_16x16x32_bf16(qf[mf][0], b0, a, 0, 0, 0);
            a = __builtin_amdgcn_mfma_f32_16x16x32_bf16(qf[mf][1], b1, a, 0, 0, 0);
            const int lb = mf * 16 + kq * 4;
            const long rbase = base + (long)lb * DIMV + dv;
            #pragma unroll
            for (int rr = 0; rr < 4; ++rr) {
                const float z = ZlS[wid][lb + rr];
                qo[rbase + (long)rr * DIMV] = a[rr] * z;
            }
        }
    }
}

// out_net[flat[e], d] = tok[e, d] + sigmoid(gatepre[e, d]) * msg[e, d]
__global__ __launch_bounds__(256)
void combine_kernel(float* __restrict__ out_net, const float* __restrict__ tok,
                    const float* __restrict__ msg, const float* __restrict__ gatepre,
                    const int* __restrict__ flat)
{
    long idx = (long)blockIdx.x * 256 + threadIdx.x;
    long e = idx / DIMV;
    int d = (int)(idx % DIMV);
    float gate = 1.f / (1.f + expf(-gatepre[idx]));
    out_net[(long)flat[e] * DIMV + d] = tok[idx] + gate * msg[idx];
}

// d/w heads: one wave per row; 4 simultaneous 384-dots, shfl reduce.
__global__ __launch_bounds__(256)
void head_kernel(const float* __restrict__ net,
                 const float* __restrict__ Wd, const float* __restrict__ bd,
                 const float* __restrict__ Ww, const float* __restrict__ bw,
                 float* __restrict__ dout, float* __restrict__ wout)
{
    const int wave = threadIdx.x >> 6;
    const int lane = threadIdx.x & 63;
    const long row = (long)blockIdx.x * 4 + wave;
    const float* p = net + row * DIMV;
    float a0 = 0.f, a1 = 0.f, a2 = 0.f, a3 = 0.f;
    #pragma unroll
    for (int i = 0; i < 6; ++i) {
        int c = lane + i * 64;
        float r = fmaxf(p[c], 0.f);
        a0 = fmaf(r, Wd[c * 2 + 0], a0);
        a1 = fmaf(r, Wd[c * 2 + 1], a1);
        a2 = fmaf(r, Ww[c * 2 + 0], a2);
        a3 = fmaf(r, Ww[c * 2 + 1], a3);
    }
    #pragma unroll
    for (int o = 32; o > 0; o >>= 1) {
        a0 += __shfl_xor(a0, o);
        a1 += __shfl_xor(a1, o);
        a2 += __shfl_xor(a2, o);
        a3 += __shfl_xor(a3, o);
    }
    if (lane == 0) {
        dout[row * 2 + 0] = a0 + bd[0];
        dout[row * 2 + 1] = a1 + bd[1];
        wout[row * 2 + 0] = 1.f / (1.f + expf(-(a2 + bw[0])));
        wout[row * 2 + 1] = 1.f / (1.f + expf(-(a3 + bw[1])));
    }
}

extern "C" void kernel_launch(void* const* d_in, const int* in_sizes, int n_in,
                              void* d_out, int out_size, void* d_ws, size_t ws_size,
                              hipStream_t stream)
{
    const float* net_in = (const float*)d_in[0];
    const float* inp    = (const float*)d_in[1];
    const float* corr   = (const float*)d_in[2];
    const float* posenc = (const float*)d_in[4];
    const int*   ix     = (const int*)d_in[8];
    const int*   jx     = (const int*)d_in[9];
    const int*   flat   = (const int*)d_in[10];   // ij_ind flattened (E,)

    const float* Wc1 = (const float*)d_in[11]; const float* bc1 = (const float*)d_in[12];
    const float* Wc2 = (const float*)d_in[13]; const float* bc2 = (const float*)d_in[14];
    const float* g_lnc = (const float*)d_in[15]; const float* b_lnc = (const float*)d_in[16];
    const float* Wc3 = (const float*)d_in[17]; const float* bc3 = (const float*)d_in[18];
    const float* g_norm = (const float*)d_in[19]; const float* b_norm = (const float*)d_in[20];
    const float* W1a = (const float*)d_in[21]; const float* b1a = (const float*)d_in[22];
    const float* W1b = (const float*)d_in[23]; const float* b1b = (const float*)d_in[24];
    const float* W2a = (const float*)d_in[25]; const float* b2a = (const float*)d_in[26];
    const float* W2b = (const float*)d_in[27]; const float* b2b = (const float*)d_in[28];
    const float* Wf = (const float*)d_in[29]; const float* bf = (const float*)d_in[30];
    const float* Wg = (const float*)d_in[31]; const float* bg = (const float*)d_in[32];
    const float* Wh = (const float*)d_in[33]; const float* bh = (const float*)d_in[34];
    const float* g_norm2 = (const float*)d_in[35]; const float* b_norm2 = (const float*)d_in[36];
    const float* Wq = (const float*)d_in[37]; const float* bq = (const float*)d_in[38];
    const float* Wk = (const float*)d_in[39]; const float* bk = (const float*)d_in[40];
    const float* Wv = (const float*)d_in[41]; const float* bv = (const float*)d_in[42];
    const float* Wm = (const float*)d_in[43]; const float* bm = (const float*)d_in[44];
    const float* Wgt = (const float*)d_in[45]; const float* bgt = (const float*)d_in[46];
    const float* Wd = (const float*)d_in[47]; const float* bd = (const float*)d_in[48];
    const float* Ww = (const float*)d_in[49]; const float* bw = (const float*)d_in[50];

    const size_t EB = (size_t)ETOK * DIMV;
    float* B0 = (float*)d_ws;            // tokens (LN'd)
    float* B1 = B0 + EB;                 // running net / v / gate_pre
    float* B2 = B1 + EB;                 // scratch / q / attn out
    float* B3 = B2 + EB;                 // scratch / k / msg
    float* Y  = B3 + EB;                 // NPATCH x DIM
    float* Y2 = Y + (size_t)NPATCHV * DIMV;

    float* out_net = (float*)d_out;
    float* out_d = out_net + EB;
    float* out_w = out_d + (size_t)ETOK * 2;

    const dim3 gB(DIMV / 64, ETOK / 128);       // (6, 432)
    const dim3 gY(DIMV / 64, NPATCHV / 128);    // (6, 18)
    const int lnBlocks = ETOK / 4;              // 13824
    const int ewBlocks = (int)(EB / 256);       // 82944

    // corr encoder: c = linear(relu(ln(linear(relu(linear(corr))))))
    gemm_bf16<1, false, false><<<gB, 256, 0, stream>>>(corr, Wc1, bc1, B2, nullptr, CORR_DIMV, DIMV);
    gemm_bf16<0, false, false><<<gB, 256, 0, stream>>>(B2, Wc2, bc2, B3, nullptr, DIMV, DIMV);
    ln_kernel<<<lnBlocks, 256, 0, stream>>>(B3, B3, nullptr, nullptr, nullptr, nullptr, g_lnc, b_lnc);
    gemm_bf16<0, false, true><<<gB, 256, 0, stream>>>(B3, Wc3, bc3, B2, nullptr, DIMV, DIMV);

    // net = LN(net + inp + c)
    ln_kernel<<<lnBlocks, 256, 0, stream>>>(B1, net_in, inp, B2, nullptr, nullptr, g_norm, b_norm);

    // net += mlp2(mask_ix * net[ix])
    gemm_bf16<1, true, false><<<gB, 256, 0, stream>>>(B1, W1a, b1a, B2, ix, DIMV, DIMV);
    gemm_bf16<2, false, false><<<gB, 256, 0, stream>>>(B2, W1b, b1b, B1, nullptr, DIMV, DIMV);

    // net += mlp2(mask_jx * net[jx])
    gemm_bf16<1, true, false><<<gB, 256, 0, stream>>>(B1, W2a, b2a, B2, jx, DIMV, DIMV);
    gemm_bf16<2, false, false><<<gB, 256, 0, stream>>>(B2, W2b, b2b, B1, nullptr, DIMV, DIMV);

    // soft aggregation
    gemm_bf16<0, false, false><<<gB, 256, 0, stream>>>(B1, Wg, bg, B2, nullptr, DIMV, DIMV);
    gemm_bf16<0, false, false><<<gB, 256, 0, stream>>>(B1, Wf, bf, B3, nullptr, DIMV, DIMV);
    softagg_kernel<<<NPATCHV, 384, 0, stream>>>(B2, B3, Y);
    gemm_bf16<0, false, false><<<gY, 256, 0, stream>>>(Y, Wh, bh, Y2, nullptr, DIMV, DIMV);

    // tokens = LN(net[flat] + Y2[flat/24])   (addseg fused into gather-LN)
    ln_kernel<<<lnBlocks, 256, 0, stream>>>(B0, B1, nullptr, nullptr, Y2, flat, g_norm2, b_norm2);

    // q,k,v  (v reuses B1 — net no longer needed)
    gemm_bf16<0, false, false><<<gB, 256, 0, stream>>>(B0, Wq, bq, B2, nullptr, DIMV, DIMV);
    gemm_bf16<0, false, false><<<gB, 256, 0, stream>>>(B0, Wk, bk, B3, nullptr, DIMV, DIMV);
    gemm_bf16<0, false, false><<<gB, 256, 0, stream>>>(B0, Wv, bv, B1, nullptr, DIMV, DIMV);

    // RoPE + elu+1 on q,k
    {
        long total = (long)ETOK * NHEADV * 24;
        rope_kernel<<<(int)(total / 256), 256, 0, stream>>>(B2, B3, posenc, flat);
    }

    // linear attention (out written into B2), one wave per (n,h)
    attn_kernel<<<NGRP * NHEADV / 4, 256, 0, stream>>>(B2, B3, B1);

    // msg = out @ Wm + bm   (B3: k dead)
    gemm_bf16<0, false, false><<<gB, 256, 0, stream>>>(B2, Wm, bm, B3, nullptr, DIMV, DIMV);

    // gate_pre = tok @ Wgt[:384] + bgt + msg @ Wgt[384:]   (B1: v dead)
    gemm_bf16<0, false, false><<<gB, 256, 0, stream>>>(B0, Wgt, bgt, B1, nullptr, DIMV, DIMV);
    gemm_bf16<2, false, false><<<gB, 256, 0, stream>>>(B3, Wgt + (size_t)DIMV * DIMV, nullptr, B1, nullptr, DIMV, DIMV);

    // net_out[flat[e]] = tok + sigmoid(gate_pre) * msg
    combine_kernel<<<ewBlocks, 256, 0, stream>>>(out_net, B0, B3, B1, flat);

    // heads
    head_kernel<<<lnBlocks, 256, 0, stream>>>(out_net, Wd, bd, Ww, bw, out_d, out_w);
}

// Round 5
// 1237.567 us; speedup vs baseline: 4.1178x; 1.4423x over previous
//
#include <hip/hip_runtime.h>
#include <math.h>

#define DIMV 384
#define NHEADV 8
#define HDV 48
#define CORR_DIMV 882
#define CORR_PAD 896
#define NFRAMESV 24
#define PPIV 96
#define NPATCHV (NFRAMESV * PPIV)        // 2304
#define ETOK (NPATCHV * NFRAMESV)        // 55296
#define MTOK 96
#define NGRP (ETOK / MTOK)               // 576

using f32x4 = __attribute__((ext_vector_type(4))) float;
using s16x8 = __attribute__((ext_vector_type(8))) short;

__device__ __forceinline__ unsigned int f2bf(float x) {
    union { float f; unsigned int u; } c; c.f = x;
    unsigned int u = c.u;
    u += 0x7fffu + ((u >> 16) & 1u);   // round-to-nearest-even
    return u >> 16;
}
__device__ __forceinline__ float bf2f(unsigned short x) {
    union { unsigned int u; float f; } c; c.u = ((unsigned int)x) << 16;
    return c.f;
}

__device__ __forceinline__ void gload_lds16(const void* g, void* l) {
    __builtin_amdgcn_global_load_lds(
        (const __attribute__((address_space(1))) unsigned int*)g,
        (__attribute__((address_space(3))) unsigned int*)l, 16, 0, 0);
}

// Bijective XCD-chunked block swizzle (m204): consecutive tiles -> same XCD.
__device__ __forceinline__ void xcd_tile(int& colblk, int& rowblk) {
    const int nwg  = gridDim.x * gridDim.y;
    const int flat = blockIdx.y * gridDim.x + blockIdx.x;
    const int xcd  = flat & 7;
    const int base = flat >> 3;
    const int q = nwg >> 3, r = nwg & 7;
    const int nf = (xcd < r ? xcd * (q + 1) : r * (q + 1) + (xcd - r) * q) + base;
    colblk = nf % gridDim.x;
    rowblk = nf / gridDim.x;
}

// ---------------------------------------------------------------------------
// All-bf16 MFMA GEMM: C[M x 384] = epi(A[M x K] @ W + bias); A bf16 [M][K],
// W pre-transposed bf16 [384][K]. 128x128 block tile, 4 waves (2m x 2n),
// global_load_lds staging (4 x 16B per thread per K-tile), source-side
// chunk-XOR swizzle (phys chunk = logical ^ ((row>>1)&3)) for bank-free
// ds_read_b128 fragment reads. K must be a multiple of 32.
// EPI: 0 = f32 store, 1 = bf16 relu store, 2 = f32 accumulate,
//      3 = f32 accumulate + bf16 dual write, 4 = f32 + bf16 dual store
// GATHER: A row r is A[gidx[r]]; gidx[r] < 0 -> reads zrow (zeroed region).
// ---------------------------------------------------------------------------
template<int EPI, bool GATHER>
__global__ __launch_bounds__(256)
void gemm_bb(const unsigned short* __restrict__ A,
             const unsigned short* __restrict__ Wt,
             const float* __restrict__ bias,
             float* __restrict__ C, unsigned short* __restrict__ Cb,
             const int* __restrict__ gidx,
             const unsigned short* __restrict__ zrow, int K)
{
    int colblk, rowblk;
    xcd_tile(colblk, rowblk);
    const int row0 = rowblk * 128;
    const int col0 = colblk * 128;

    __shared__ __align__(16) unsigned short As[128 * 32];
    __shared__ __align__(16) unsigned short Bs[128 * 32];

    const int tid  = threadIdx.x;
    const int lane = tid & 63;
    const int wid  = tid >> 6;
    const int wm   = wid >> 1;
    const int wn   = wid & 1;

    // staging map: wave wid, issue s: lane l -> row wid*32+s*16+(l>>2),
    // physical 16B chunk (l&3) holds logical chunk (l&3)^((row>>1)&3)
    const int rl = lane >> 2;
    const int cp = lane & 3;

    const unsigned short* asrc[2];
    const unsigned short* bsrc[2];
    #pragma unroll
    for (int s = 0; s < 2; ++s) {
        const int r = wid * 32 + s * 16 + rl;
        const int c = cp ^ ((r >> 1) & 3);
        long arow = row0 + r;
        if (GATHER) arow = gidx[row0 + r];
        asrc[s] = (GATHER && arow < 0) ? (zrow + c * 8)
                                       : (A + arow * (long)K + c * 8);
        bsrc[s] = Wt + (long)(col0 + r) * K + c * 8;
    }
    unsigned short* adst[2] = { &As[(wid * 32) * 32], &As[(wid * 32 + 16) * 32] };
    unsigned short* bdst[2] = { &Bs[(wid * 32) * 32], &Bs[(wid * 32 + 16) * 32] };

    f32x4 acc[4][4] = {};
    const int ntiles = K >> 5;

    for (int t = 0; t < ntiles; ++t) {
        const int ko = t * 32;
        gload_lds16(asrc[0] + ko, adst[0]);
        gload_lds16(asrc[1] + ko, adst[1]);
        gload_lds16(bsrc[0] + ko, bdst[0]);
        gload_lds16(bsrc[1] + ko, bdst[1]);
        __syncthreads();

        const int rsel = lane & 15;
        const int kq   = lane >> 4;
        s16x8 a[4], b[4];
        #pragma unroll
        for (int i = 0; i < 4; ++i) {
            const int R = wm * 64 + i * 16 + rsel;
            a[i] = *(const s16x8*)&As[R * 32 + ((kq ^ ((R >> 1) & 3)) << 3)];
        }
        #pragma unroll
        for (int j = 0; j < 4; ++j) {
            const int R = wn * 64 + j * 16 + rsel;
            b[j] = *(const s16x8*)&Bs[R * 32 + ((kq ^ ((R >> 1) & 3)) << 3)];
        }
        #pragma unroll
        for (int i = 0; i < 4; ++i)
            #pragma unroll
            for (int j = 0; j < 4; ++j)
                acc[i][j] = __builtin_amdgcn_mfma_f32_16x16x32_bf16(a[i], b[j], acc[i][j], 0, 0, 0);
        __syncthreads();
    }

    // epilogue: C/D layout col=lane&15, row=(lane>>4)*4+reg
    const int ccol = lane & 15;
    const int rgrp = lane >> 4;
    #pragma unroll
    for (int i = 0; i < 4; ++i) {
        #pragma unroll
        for (int j = 0; j < 4; ++j) {
            const int col = col0 + wn * 64 + j * 16 + ccol;
            const long rbase = row0 + wm * 64 + i * 16 + rgrp * 4;
            const float bsv = bias ? bias[col] : 0.f;
            #pragma unroll
            for (int rr = 0; rr < 4; ++rr) {
                const long off = (rbase + rr) * (long)DIMV + col;
                float v = acc[i][j][rr] + bsv;
                if (EPI == 0) C[off] = v;
                if (EPI == 1) Cb[off] = (unsigned short)f2bf(fmaxf(v, 0.f));
                if (EPI == 2) C[off] += v;
                if (EPI == 3) { const float nv = C[off] + v; C[off] = nv; Cb[off] = (unsigned short)f2bf(nv); }
                if (EPI == 4) { C[off] = v; Cb[off] = (unsigned short)f2bf(v); }
            }
        }
    }
}

// ---------------------------------------------------------------------------
// Weight transpose+convert: 15 x [384][384] f32 -> [384][384] bf16 transposed.
// ---------------------------------------------------------------------------
struct WPtrs { const float* p[15]; };

__global__ __launch_bounds__(256)
void wtrans15(WPtrs w, unsigned short* __restrict__ out)
{
    __shared__ float t[32][33];
    const float* W = w.p[blockIdx.z];
    unsigned short* O = out + (size_t)blockIdx.z * DIMV * DIMV;
    const int k0 = blockIdx.x * 32, n0 = blockIdx.y * 32;
    const int tx = threadIdx.x, ty = threadIdx.y;
    #pragma unroll
    for (int i = ty; i < 32; i += 8)
        t[i][tx] = W[(long)(k0 + i) * DIMV + n0 + tx];
    __syncthreads();
    #pragma unroll
    for (int i = ty; i < 32; i += 8)
        O[(long)(n0 + i) * DIMV + k0 + tx] = (unsigned short)f2bf(t[tx][i]);
}

// Wc1 transpose: [882][384] f32 -> [384][896] bf16 (k zero-padded).
__global__ __launch_bounds__(256)
void wtransc1(const float* __restrict__ W, unsigned short* __restrict__ O)
{
    __shared__ float t[32][33];
    const int k0 = blockIdx.x * 32, n0 = blockIdx.y * 32;
    const int tx = threadIdx.x, ty = threadIdx.y;
    #pragma unroll
    for (int i = ty; i < 32; i += 8)
        t[i][tx] = (k0 + i < CORR_DIMV) ? W[(long)(k0 + i) * DIMV + n0 + tx] : 0.f;
    __syncthreads();
    #pragma unroll
    for (int i = ty; i < 32; i += 8)
        O[(long)(n0 + i) * CORR_PAD + k0 + tx] = (unsigned short)f2bf(t[tx][i]);
}

// corr f32 [E][882] -> bf16 [E][896] (padded); also zero-fills zrow (2KB).
__global__ __launch_bounds__(256)
void corrconv(const float* __restrict__ corr, unsigned int* __restrict__ corrb,
              unsigned int* __restrict__ zr)
{
    if (blockIdx.x == 0 && threadIdx.x < 512) zr[threadIdx.x] = 0u;
    const long idx = (long)blockIdx.x * 256 + threadIdx.x;   // over E*448 pairs
    if (idx >= (long)ETOK * (CORR_PAD / 2)) return;
    const long e = idx / (CORR_PAD / 2);
    const int  p = (int)(idx % (CORR_PAD / 2));
    const int  k = p * 2;
    unsigned v = 0u;
    if (k + 1 < CORR_DIMV) {
        const float2 f = *(const float2*)(corr + e * CORR_DIMV + k);
        v = f2bf(f.x) | (f2bf(f.y) << 16);
    }
    corrb[idx] = v;
}

// ---------------------------------------------------------------------------
// LayerNorm over DIM=384, one wave per row. Optional f32 and/or bf16 outputs.
// dst/dstb[row] = LN(s0[srow] (+s1) (+s2) (+seg[srow/24])) * g + b
// ---------------------------------------------------------------------------
template<bool RELUB>
__global__ __launch_bounds__(256)
void ln_kernel(float* __restrict__ dst, unsigned short* __restrict__ dstb,
               const float* __restrict__ s0, const float* __restrict__ s1,
               const float* __restrict__ s2, const float* __restrict__ seg,
               const int* __restrict__ gather,
               const float* __restrict__ g, const float* __restrict__ b)
{
    const int wave = threadIdx.x >> 6;
    const int lane = threadIdx.x & 63;
    const long row = (long)blockIdx.x * 4 + wave;
    const long srow = gather ? (long)gather[row] : row;

    float x[6];
    float sum = 0.f;
    #pragma unroll
    for (int i = 0; i < 6; ++i) {
        int c = lane + i * 64;
        float v = s0[srow * DIMV + c];
        if (s1) v += s1[srow * DIMV + c];
        if (s2) v += s2[srow * DIMV + c];
        if (seg) v += seg[(srow / NFRAMESV) * DIMV + c];
        x[i] = v; sum += v;
    }
    #pragma unroll
    for (int o = 32; o > 0; o >>= 1) sum += __shfl_xor(sum, o);
    float mu = sum * (1.f / DIMV);
    float vs = 0.f;
    #pragma unroll
    for (int i = 0; i < 6; ++i) { float d = x[i] - mu; vs += d * d; }
    #pragma unroll
    for (int o = 32; o > 0; o >>= 1) vs += __shfl_xor(vs, o);
    float rstd = rsqrtf(vs * (1.f / DIMV) + 1e-3f);
    #pragma unroll
    for (int i = 0; i < 6; ++i) {
        int c = lane + i * 64;
        float y = (x[i] - mu) * rstd * g[c] + b[c];
        if (dst)  dst[row * DIMV + c] = y;
        if (dstb) dstb[row * DIMV + c] =
            (unsigned short)f2bf(RELUB ? fmaxf(y, 0.f) : y);
    }
}

// ---------------------------------------------------------------------------
// Segment softmax-aggregation (contiguous 24-row segments); bf16 output.
// ---------------------------------------------------------------------------
__global__ __launch_bounds__(384)
void softagg_kernel(const float* __restrict__ gbuf, const float* __restrict__ fbuf,
                    unsigned short* __restrict__ yb)
{
    const int p = blockIdx.x;
    const int col = threadIdx.x;
    const long base = (long)p * NFRAMESV * DIMV + col;
    float gv[NFRAMESV];
    float gmax = -INFINITY;
    #pragma unroll
    for (int r = 0; r < NFRAMESV; ++r) {
        gv[r] = gbuf[base + (long)r * DIMV];
        gmax = fmaxf(gmax, gv[r]);
    }
    float den = 0.f;
    #pragma unroll
    for (int r = 0; r < NFRAMESV; ++r) { gv[r] = expf(gv[r] - gmax); den += gv[r]; }
    float acc = 0.f;
    #pragma unroll
    for (int r = 0; r < NFRAMESV; ++r) acc += fbuf[base + (long)r * DIMV] * gv[r];
    yb[(long)p * DIMV + col] = (unsigned short)f2bf(acc / den);
}

// ---------------------------------------------------------------------------
// RoPE + elu+1 on q and k in place ((d, d+24) pairs per thread).
// ---------------------------------------------------------------------------
__global__ __launch_bounds__(256)
void rope_kernel(float* __restrict__ q, float* __restrict__ k,
                 const float* __restrict__ pos, const int* __restrict__ flat)
{
    long idx = (long)blockIdx.x * 256 + threadIdx.x;          // E*8*24 threads
    long e = idx / (NHEADV * 24);
    int rem = (int)(idx % (NHEADV * 24));
    int h = rem / 24, d = rem % 24;
    int tok = flat[e];
    const float* cp = pos + (long)tok * HDV;
    const float* sp = pos + (long)ETOK * HDV + (long)tok * HDV;
    float c1 = cp[d], c2 = cp[d + 24], s1 = sp[d], s2 = sp[d + 24];
    long o1 = e * DIMV + h * HDV + d;
    long o2 = o1 + 24;

    float q1 = q[o1], q2 = q[o2];
    float r1 = q1 * c1 - q2 * s1;
    float r2 = q2 * c2 + q1 * s2;
    q[o1] = (r1 > 0.f) ? r1 + 1.f : expf(r1);   // elu(x)+1
    q[o2] = (r2 > 0.f) ? r2 + 1.f : expf(r2);

    float k1 = k[o1], k2 = k[o2];
    float t1 = k1 * c1 - k2 * s1;
    float t2 = k2 * c2 + k1 * s2;
    k[o1] = (t1 > 0.f) ? t1 + 1.f : expf(t1);
    k[o2] = (t2 > 0.f) ? t2 + 1.f : expf(t2);
}

// ---------------------------------------------------------------------------
// Gated linear attention core — MFMA, one WAVE per (group n, head h); bf16 out.
// ---------------------------------------------------------------------------
__global__ __launch_bounds__(256)
void attn_kernel(const float* __restrict__ qbuf, const float* __restrict__ kbuf,
                 const float* __restrict__ vbuf, unsigned short* __restrict__ ob)
{
    __shared__ unsigned short KVt[4][48][64];   // per-wave bf16 KV^T, swizzled
    __shared__ float KsumS[4][48];
    __shared__ float ZlS[4][96];

    const int tid  = threadIdx.x;
    const int wid  = tid >> 6;
    const int lane = tid & 63;
    const int task = blockIdx.x * 4 + wid;       // 4608 tasks
    const int n = task >> 3, h = task & 7;

    const long base = ((long)n * MTOK) * DIMV + h * HDV;

    const int c16   = lane & 15;
    const int kq    = lane >> 4;    // 0..3
    const int khalf = kq * 8;

    // zero logical d=48..63 pad rows of KVt (physical = logical ^ swizzle)
    if (lane < 48) {
        const int s = (lane & 7) << 3;
        const uint4 z = make_uint4(0u, 0u, 0u, 0u);
        *(uint4*)&KVt[wid][lane][48 ^ s] = z;
        *(uint4*)&KVt[wid][lane][56 ^ s] = z;
    }

    // ---- KV = K^T V via MFMA; Ksum accumulated from the same K loads ----
    f32x4 kv[3][3] = {};
    float ksum_p[3] = {0.f, 0.f, 0.f};

    for (int ks = 0; ks < 3; ++ks) {
        const int l0 = ks * 32 + khalf;
        s16x8 afr[3], bfr[3];
        #pragma unroll
        for (int mf = 0; mf < 3; ++mf) {
            const int d = mf * 16 + c16;
            union { unsigned short us[8]; s16x8 v; } pk;
            float s = 0.f;
            #pragma unroll
            for (int j = 0; j < 8; ++j) {
                const float kval = kbuf[base + (long)(l0 + j) * DIMV + d];
                s += kval;
                pk.us[j] = (unsigned short)f2bf(kval);
            }
            ksum_p[mf] += s;
            afr[mf] = pk.v;
        }
        #pragma unroll
        for (int nf = 0; nf < 3; ++nf) {
            const int dv = nf * 16 + c16;
            union { unsigned short us[8]; s16x8 v; } pk;
            #pragma unroll
            for (int j = 0; j < 8; ++j)
                pk.us[j] = (unsigned short)f2bf(vbuf[base + (long)(l0 + j) * DIMV + dv]);
            bfr[nf] = pk.v;
        }
        #pragma unroll
        for (int mf = 0; mf < 3; ++mf)
            #pragma unroll
            for (int nf = 0; nf < 3; ++nf)
                kv[mf][nf] = __builtin_amdgcn_mfma_f32_16x16x32_bf16(afr[mf], bfr[nf], kv[mf][nf], 0, 0, 0);
    }

    // Ksum: reduce over the 4 lane-quarters
    #pragma unroll
    for (int mf = 0; mf < 3; ++mf) {
        float s = ksum_p[mf];
        s += __shfl_xor(s, 16);
        s += __shfl_xor(s, 32);
        if (kq == 0) KsumS[wid][mf * 16 + c16] = s;
    }

    // KV fragments -> LDS bf16 [dv][d] (C layout: col=dv=lane&15, row=d=kq*4+rr)
    #pragma unroll
    for (int mf = 0; mf < 3; ++mf) {
        #pragma unroll
        for (int nf = 0; nf < 3; ++nf) {
            const int dv = nf * 16 + c16;
            const int d0 = (mf * 16 + kq * 4) ^ ((dv & 7) << 3);
            uint2 w;
            w.x = f2bf(kv[mf][nf][0]) | (f2bf(kv[mf][nf][1]) << 16);
            w.y = f2bf(kv[mf][nf][2]) | (f2bf(kv[mf][nf][3]) << 16);
            *(uint2*)&KVt[wid][dv][d0] = w;
        }
    }

    // ---- Q fragments (float4 loads) + Z denominators ----
    s16x8 qf[6][2];
    const s16x8 zfrag = {0, 0, 0, 0, 0, 0, 0, 0};
    #pragma unroll
    for (int mf = 0; mf < 6; ++mf) {
        const int l = mf * 16 + c16;
        float dsum = 0.f;
        #pragma unroll
        for (int ks = 0; ks < 2; ++ks) {
            if (ks == 0 || kq < 2) {          // d < 48 region only
                const int d = ks * 32 + khalf;
                const float* qp = qbuf + base + (long)l * DIMV + d;
                const float4 v0 = *(const float4*)qp;
                const float4 v1 = *(const float4*)(qp + 4);
                dsum += v0.x * KsumS[wid][d]     + v0.y * KsumS[wid][d + 1]
                      + v0.z * KsumS[wid][d + 2] + v0.w * KsumS[wid][d + 3]
                      + v1.x * KsumS[wid][d + 4] + v1.y * KsumS[wid][d + 5]
                      + v1.z * KsumS[wid][d + 6] + v1.w * KsumS[wid][d + 7];
                union { unsigned short us[8]; s16x8 v; } pk;
                pk.us[0] = (unsigned short)f2bf(v0.x);
                pk.us[1] = (unsigned short)f2bf(v0.y);
                pk.us[2] = (unsigned short)f2bf(v0.z);
                pk.us[3] = (unsigned short)f2bf(v0.w);
                pk.us[4] = (unsigned short)f2bf(v1.x);
                pk.us[5] = (unsigned short)f2bf(v1.y);
                pk.us[6] = (unsigned short)f2bf(v1.z);
                pk.us[7] = (unsigned short)f2bf(v1.w);
                qf[mf][ks] = pk.v;
            } else {
                qf[mf][ks] = zfrag;
            }
        }
        dsum += __shfl_xor(dsum, 16);
        dsum += __shfl_xor(dsum, 32);
        if (kq == 0) ZlS[wid][l] = 1.f / (dsum + 1e-6f);
    }

    // ---- out = (Q @ KV) * Z, stored bf16 ----
    #pragma unroll
    for (int nf = 0; nf < 3; ++nf) {
        const int dv = nf * 16 + c16;
        const int sw = (dv & 7) << 3;
        const s16x8 b0 = *(const s16x8*)&KVt[wid][dv][khalf ^ sw];
        const s16x8 b1 = *(const s16x8*)&KVt[wid][dv][(32 + khalf) ^ sw];
        #pragma unroll
        for (int mf = 0; mf < 6; ++mf) {
            f32x4 a = {};
            a = __builtin_amdgcn_mfma_f32_16x16x32_bf16(qf[mf][0], b0, a, 0, 0, 0);
            a = __builtin_amdgcn_mfma_f32_16x16x32_bf16(qf[mf][1], b1, a, 0, 0, 0);
            const int lb = mf * 16 + kq * 4;
            const long rbase = base + (long)lb * DIMV + dv;
            #pragma unroll
            for (int rr = 0; rr < 4; ++rr) {
                const float z = ZlS[wid][lb + rr];
                ob[rbase + (long)rr * DIMV] = (unsigned short)f2bf(a[rr] * z);
            }
        }
    }
}

// out_net[flat[e], d] = tok_b[e, d] + sigmoid(gatepre[e, d]) * msg[e, d]
__global__ __launch_bounds__(256)
void combine_kernel(float* __restrict__ out_net, const unsigned short* __restrict__ tokb,
                    const float* __restrict__ msg, const float* __restrict__ gatepre,
                    const int* __restrict__ flat)
{
    long idx = (long)blockIdx.x * 256 + threadIdx.x;
    long e = idx / DIMV;
    int d = (int)(idx % DIMV);
    float gate = 1.f / (1.f + expf(-gatepre[idx]));
    out_net[(long)flat[e] * DIMV + d] = bf2f(tokb[idx]) + gate * msg[idx];
}

// d/w heads: one wave per row; 4 simultaneous 384-dots, shfl reduce.
__global__ __launch_bounds__(256)
void head_kernel(const float* __restrict__ net,
                 const float* __restrict__ Wd, const float* __restrict__ bd,
                 const float* __restrict__ Ww, const float* __restrict__ bw,
                 float* __restrict__ dout, float* __restrict__ wout)
{
    const int wave = threadIdx.x >> 6;
    const int lane = threadIdx.x & 63;
    const long row = (long)blockIdx.x * 4 + wave;
    const float* p = net + row * DIMV;
    float a0 = 0.f, a1 = 0.f, a2 = 0.f, a3 = 0.f;
    #pragma unroll
    for (int i = 0; i < 6; ++i) {
        int c = lane + i * 64;
        float r = fmaxf(p[c], 0.f);
        a0 = fmaf(r, Wd[c * 2 + 0], a0);
        a1 = fmaf(r, Wd[c * 2 + 1], a1);
        a2 = fmaf(r, Ww[c * 2 + 0], a2);
        a3 = fmaf(r, Ww[c * 2 + 1], a3);
    }
    #pragma unroll
    for (int o = 32; o > 0; o >>= 1) {
        a0 += __shfl_xor(a0, o);
        a1 += __shfl_xor(a1, o);
        a2 += __shfl_xor(a2, o);
        a3 += __shfl_xor(a3, o);
    }
    if (lane == 0) {
        dout[row * 2 + 0] = a0 + bd[0];
        dout[row * 2 + 1] = a1 + bd[1];
        wout[row * 2 + 0] = 1.f / (1.f + expf(-(a2 + bw[0])));
        wout[row * 2 + 1] = 1.f / (1.f + expf(-(a3 + bw[1])));
    }
}

extern "C" void kernel_launch(void* const* d_in, const int* in_sizes, int n_in,
                              void* d_out, int out_size, void* d_ws, size_t ws_size,
                              hipStream_t stream)
{
    const float* net_in = (const float*)d_in[0];
    const float* inp    = (const float*)d_in[1];
    const float* corr   = (const float*)d_in[2];
    const float* posenc = (const float*)d_in[4];
    const int*   ix     = (const int*)d_in[8];
    const int*   jx     = (const int*)d_in[9];
    const int*   flat   = (const int*)d_in[10];   // ij_ind flattened (E,)

    const float* Wc1 = (const float*)d_in[11]; const float* bc1 = (const float*)d_in[12];
    const float* Wc2 = (const float*)d_in[13]; const float* bc2 = (const float*)d_in[14];
    const float* g_lnc = (const float*)d_in[15]; const float* b_lnc = (const float*)d_in[16];
    const float* Wc3 = (const float*)d_in[17]; const float* bc3 = (const float*)d_in[18];
    const float* g_norm = (const float*)d_in[19]; const float* b_norm = (const float*)d_in[20];
    const float* W1a = (const float*)d_in[21]; const float* b1a = (const float*)d_in[22];
    const float* W1b = (const float*)d_in[23]; const float* b1b = (const float*)d_in[24];
    const float* W2a = (const float*)d_in[25]; const float* b2a = (const float*)d_in[26];
    const float* W2b = (const float*)d_in[27]; const float* b2b = (const float*)d_in[28];
    const float* Wf = (const float*)d_in[29]; const float* bf = (const float*)d_in[30];
    const float* Wg = (const float*)d_in[31]; const float* bg = (const float*)d_in[32];
    const float* Wh = (const float*)d_in[33]; const float* bh = (const float*)d_in[34];
    const float* g_norm2 = (const float*)d_in[35]; const float* b_norm2 = (const float*)d_in[36];
    const float* Wq = (const float*)d_in[37]; const float* bq = (const float*)d_in[38];
    const float* Wk = (const float*)d_in[39]; const float* bk = (const float*)d_in[40];
    const float* Wv = (const float*)d_in[41]; const float* bv = (const float*)d_in[42];
    const float* Wm = (const float*)d_in[43]; const float* bm = (const float*)d_in[44];
    const float* Wgt = (const float*)d_in[45]; const float* bgt = (const float*)d_in[46];
    const float* Wd = (const float*)d_in[47]; const float* bd = (const float*)d_in[48];
    const float* Ww = (const float*)d_in[49]; const float* bw = (const float*)d_in[50];

    // ---- workspace layout ----
    const size_t EB  = (size_t)ETOK * DIMV;            // elements per E x 384
    const size_t WSLOT = (size_t)DIMV * DIMV;          // 147456
    char* p = (char*)d_ws;
    float* X0 = (float*)p;            p += EB * 4;
    float* X1 = (float*)p;            p += EB * 4;
    float* X2 = (float*)p;            p += EB * 4;
    unsigned short* WT = (unsigned short*)p;  p += (15 * WSLOT + (size_t)DIMV * CORR_PAD) * 2;
    unsigned short* ZR = (unsigned short*)p;  p += 2048;
    unsigned short* Cb0 = (unsigned short*)p; p += EB * 2;
    unsigned short* Bb  = (unsigned short*)p;                 // bf16 net / msgb
    unsigned short* corrb = Bb;                               // overlays Bb..(+99MB)
    p += EB * 2;
    unsigned short* Tb  = (unsigned short*)p; p += EB * 2;
    float* Y2f = (float*)p;           p += (size_t)NPATCHV * DIMV * 4;
    unsigned short* Yb = (unsigned short*)p; p += (size_t)NPATCHV * DIMV * 2;
    p += 16 * 1024 * 1024;            // corrb overlay slack (extends past Tb)

    unsigned short* Wc2t = WT + 0 * WSLOT;
    unsigned short* Wc3t = WT + 1 * WSLOT;
    unsigned short* W1at = WT + 2 * WSLOT;
    unsigned short* W1bt = WT + 3 * WSLOT;
    unsigned short* W2at = WT + 4 * WSLOT;
    unsigned short* W2bt = WT + 5 * WSLOT;
    unsigned short* Wft  = WT + 6 * WSLOT;
    unsigned short* Wgt_ = WT + 7 * WSLOT;   // soft-agg gate Wg
    unsigned short* Wht  = WT + 8 * WSLOT;
    unsigned short* Wqt  = WT + 9 * WSLOT;
    unsigned short* Wkt  = WT + 10 * WSLOT;
    unsigned short* Wvt  = WT + 11 * WSLOT;
    unsigned short* Wmt  = WT + 12 * WSLOT;
    unsigned short* Wg0t = WT + 13 * WSLOT;  // Wgt[:384]
    unsigned short* Wg1t = WT + 14 * WSLOT;  // Wgt[384:]
    unsigned short* Wc1t = WT + 15 * WSLOT;  // [384][896]

    float* out_net = (float*)d_out;
    float* out_d = out_net + EB;
    float* out_w = out_d + (size_t)ETOK * 2;

    const dim3 gB(DIMV / 128, ETOK / 128);      // (3, 432)
    const dim3 gY(DIMV / 128, NPATCHV / 128);   // (3, 18)
    const int lnBlocks = ETOK / 4;
    const int ewBlocks = (int)(EB / 256);

    // ---- pre-passes: corr -> bf16 (padded), weights -> bf16 transposed ----
    {
        const long tot = (long)ETOK * (CORR_PAD / 2);
        corrconv<<<(int)((tot + 255) / 256), 256, 0, stream>>>(corr, (unsigned int*)corrb, (unsigned int*)ZR);
    }
    {
        WPtrs w;
        w.p[0] = Wc2; w.p[1] = Wc3; w.p[2] = W1a; w.p[3] = W1b; w.p[4] = W2a;
        w.p[5] = W2b; w.p[6] = Wf;  w.p[7] = Wg;  w.p[8] = Wh;  w.p[9] = Wq;
        w.p[10] = Wk; w.p[11] = Wv; w.p[12] = Wm; w.p[13] = Wgt;
        w.p[14] = Wgt + (size_t)DIMV * DIMV;
        wtrans15<<<dim3(12, 12, 15), dim3(32, 8), 0, stream>>>(w, WT);
        wtransc1<<<dim3(28, 12), dim3(32, 8), 0, stream>>>(Wc1, Wc1t);
    }

    // corr encoder
    gemm_bb<1, false><<<gB, 256, 0, stream>>>(corrb, Wc1t, bc1, nullptr, Cb0, nullptr, ZR, CORR_PAD);
    gemm_bb<0, false><<<gB, 256, 0, stream>>>(Cb0, Wc2t, bc2, X1, nullptr, nullptr, ZR, DIMV);
    ln_kernel<true><<<lnBlocks, 256, 0, stream>>>(nullptr, Cb0, X1, nullptr, nullptr, nullptr, nullptr, g_lnc, b_lnc);
    gemm_bb<0, false><<<gB, 256, 0, stream>>>(Cb0, Wc3t, bc3, X1, nullptr, nullptr, ZR, DIMV);

    // net = LN(net + inp + c) -> X0 (f32) + Bb (bf16)
    ln_kernel<false><<<lnBlocks, 256, 0, stream>>>(X0, Bb, net_in, inp, X1, nullptr, nullptr, g_norm, b_norm);

    // net += mlp2(mask_ix * net[ix])
    gemm_bb<1, true><<<gB, 256, 0, stream>>>(Bb, W1at, b1a, nullptr, Cb0, ix, ZR, DIMV);
    gemm_bb<3, false><<<gB, 256, 0, stream>>>(Cb0, W1bt, b1b, X0, Bb, nullptr, ZR, DIMV);

    // net += mlp2(mask_jx * net[jx])
    gemm_bb<1, true><<<gB, 256, 0, stream>>>(Bb, W2at, b2a, nullptr, Cb0, jx, ZR, DIMV);
    gemm_bb<3, false><<<gB, 256, 0, stream>>>(Cb0, W2bt, b2b, X0, Bb, nullptr, ZR, DIMV);

    // soft aggregation
    gemm_bb<0, false><<<gB, 256, 0, stream>>>(Bb, Wgt_, bg, X1, nullptr, nullptr, ZR, DIMV);
    gemm_bb<0, false><<<gB, 256, 0, stream>>>(Bb, Wft, bf, X2, nullptr, nullptr, ZR, DIMV);
    softagg_kernel<<<NPATCHV, 384, 0, stream>>>(X1, X2, Yb);
    gemm_bb<0, false><<<gY, 256, 0, stream>>>(Yb, Wht, bh, Y2f, nullptr, nullptr, ZR, DIMV);

    // tokens = LN(net[flat] + Y2[flat/24]) -> Tb (bf16 only)
    ln_kernel<false><<<lnBlocks, 256, 0, stream>>>(nullptr, Tb, X0, nullptr, nullptr, Y2f, flat, g_norm2, b_norm2);

    // q,k,v
    gemm_bb<0, false><<<gB, 256, 0, stream>>>(Tb, Wqt, bq, X1, nullptr, nullptr, ZR, DIMV);
    gemm_bb<0, false><<<gB, 256, 0, stream>>>(Tb, Wkt, bk, X2, nullptr, nullptr, ZR, DIMV);
    gemm_bb<0, false><<<gB, 256, 0, stream>>>(Tb, Wvt, bv, X0, nullptr, nullptr, ZR, DIMV);

    // RoPE + elu+1 on q,k
    {
        long total = (long)ETOK * NHEADV * 24;
        rope_kernel<<<(int)(total / 256), 256, 0, stream>>>(X1, X2, posenc, flat);
    }

    // linear attention -> Ob (= Cb0, bf16)
    attn_kernel<<<NGRP * NHEADV / 4, 256, 0, stream>>>(X1, X2, X0, Cb0);

    // msg = out @ Wm + bm -> X0 (f32) + Bb (bf16)
    gemm_bb<4, false><<<gB, 256, 0, stream>>>(Cb0, Wmt, bm, X0, Bb, nullptr, ZR, DIMV);

    // gate_pre = tok @ Wgt0 + bgt + msg @ Wgt1 -> X1
    gemm_bb<0, false><<<gB, 256, 0, stream>>>(Tb, Wg0t, bgt, X1, nullptr, nullptr, ZR, DIMV);
    gemm_bb<2, false><<<gB, 256, 0, stream>>>(Bb, Wg1t, nullptr, X1, nullptr, nullptr, ZR, DIMV);

    // net_out[flat[e]] = tok + sigmoid(gate_pre) * msg
    combine_kernel<<<ewBlocks, 256, 0, stream>>>(out_net, Tb, X0, X1, flat);

    // heads
    head_kernel<<<lnBlocks, 256, 0, stream>>>(out_net, Wd, bd, Ww, bw, out_d, out_w);
}

// Round 6
// 1006.510 us; speedup vs baseline: 5.0631x; 1.2296x over previous
//
#include <hip/hip_runtime.h>
#include <math.h>

#define DIMV 384
#define NHEADV 8
#define HDV 48
#define CORR_DIMV 882
#define CORR_PAD 896
#define NFRAMESV 24
#define PPIV 96
#define NPATCHV (NFRAMESV * PPIV)        // 2304
#define ETOK (NPATCHV * NFRAMESV)        // 55296
#define MTOK 96
#define NGRP (ETOK / MTOK)               // 576

using f32x4 = __attribute__((ext_vector_type(4))) float;
using s16x8 = __attribute__((ext_vector_type(8))) short;
using u16x4 = __attribute__((ext_vector_type(4))) unsigned short;

__device__ __forceinline__ unsigned int f2bf(float x) {
    union { float f; unsigned int u; } c; c.f = x;
    unsigned int u = c.u;
    u += 0x7fffu + ((u >> 16) & 1u);   // round-to-nearest-even
    return u >> 16;
}
__device__ __forceinline__ float bf2f(unsigned short x) {
    union { unsigned int u; float f; } c; c.u = ((unsigned int)x) << 16;
    return c.f;
}

__device__ __forceinline__ void gload_lds16(const void* g, void* l) {
    __builtin_amdgcn_global_load_lds(
        (const __attribute__((address_space(1))) unsigned int*)g,
        (__attribute__((address_space(3))) unsigned int*)l, 16, 0, 0);
}

// Bijective XCD-chunked block swizzle (m204): consecutive tiles -> same XCD.
__device__ __forceinline__ void xcd_tile(int& colblk, int& rowblk) {
    const int nwg  = gridDim.x * gridDim.y;
    const int flat = blockIdx.y * gridDim.x + blockIdx.x;
    const int xcd  = flat & 7;
    const int base = flat >> 3;
    const int q = nwg >> 3, r = nwg & 7;
    const int nf = (xcd < r ? xcd * (q + 1) : r * (q + 1) + (xcd - r) * q) + base;
    colblk = nf % gridDim.x;
    rowblk = nf / gridDim.x;
}

// ---------------------------------------------------------------------------
// All-bf16 MFMA GEMM: out[M x 384] = epi(A[M x K] @ W + bias); A bf16 (row
// stride lda), W pre-transposed bf16 [384][K]. 128x128 block tile, 4 waves,
// global_load_lds staging with source-side chunk-XOR swizzle.
// EPI: 0 = f32 store, 1 = bf16 relu store, 3 = f32 accumulate + bf16 dual,
//      5 = bf16 store, 7 = gate-combine (read tok/msg from Cb concat buffer,
//          out_net[gidx[row]*384+col] = tok + sigmoid(acc+bias)*msg)
// GATHER: A row r is A[gidx[r]]; gidx[r] < 0 -> reads zrow (zeroed region).
// ---------------------------------------------------------------------------
template<int EPI, bool GATHER>
__global__ __launch_bounds__(256)
void gemm_bb(const unsigned short* __restrict__ A, int lda,
             const unsigned short* __restrict__ Wt,
             const float* __restrict__ bias,
             float* __restrict__ C,
             unsigned short* __restrict__ Cb, int ldcb, int cbofs,
             const int* __restrict__ gidx,
             const unsigned short* __restrict__ zrow, int K)
{
    int colblk, rowblk;
    xcd_tile(colblk, rowblk);
    const int row0 = rowblk * 128;
    const int col0 = colblk * 128;

    __shared__ __align__(16) unsigned short As[128 * 32];
    __shared__ __align__(16) unsigned short Bs[128 * 32];

    const int tid  = threadIdx.x;
    const int lane = tid & 63;
    const int wid  = tid >> 6;
    const int wm   = wid >> 1;
    const int wn   = wid & 1;

    const int rl = lane >> 2;
    const int cp = lane & 3;

    const unsigned short* asrc[2];
    const unsigned short* bsrc[2];
    #pragma unroll
    for (int s = 0; s < 2; ++s) {
        const int r = wid * 32 + s * 16 + rl;
        const int c = cp ^ ((r >> 1) & 3);
        long arow = row0 + r;
        if (GATHER) arow = gidx[row0 + r];
        asrc[s] = (GATHER && arow < 0) ? (zrow + c * 8)
                                       : (A + arow * (long)lda + c * 8);
        bsrc[s] = Wt + (long)(col0 + r) * K + c * 8;
    }
    unsigned short* adst[2] = { &As[(wid * 32) * 32], &As[(wid * 32 + 16) * 32] };
    unsigned short* bdst[2] = { &Bs[(wid * 32) * 32], &Bs[(wid * 32 + 16) * 32] };

    f32x4 acc[4][4] = {};
    const int ntiles = K >> 5;

    for (int t = 0; t < ntiles; ++t) {
        const int ko = t * 32;
        gload_lds16(asrc[0] + ko, adst[0]);
        gload_lds16(asrc[1] + ko, adst[1]);
        gload_lds16(bsrc[0] + ko, bdst[0]);
        gload_lds16(bsrc[1] + ko, bdst[1]);
        __syncthreads();

        const int rsel = lane & 15;
        const int kq   = lane >> 4;
        s16x8 a[4], b[4];
        #pragma unroll
        for (int i = 0; i < 4; ++i) {
            const int R = wm * 64 + i * 16 + rsel;
            a[i] = *(const s16x8*)&As[R * 32 + ((kq ^ ((R >> 1) & 3)) << 3)];
        }
        #pragma unroll
        for (int j = 0; j < 4; ++j) {
            const int R = wn * 64 + j * 16 + rsel;
            b[j] = *(const s16x8*)&Bs[R * 32 + ((kq ^ ((R >> 1) & 3)) << 3)];
        }
        #pragma unroll
        for (int i = 0; i < 4; ++i)
            #pragma unroll
            for (int j = 0; j < 4; ++j)
                acc[i][j] = __builtin_amdgcn_mfma_f32_16x16x32_bf16(a[i], b[j], acc[i][j], 0, 0, 0);
        __syncthreads();
    }

    // epilogue: C/D layout col=lane&15, row=(lane>>4)*4+reg
    const int ccol = lane & 15;
    const int rgrp = lane >> 4;
    #pragma unroll
    for (int i = 0; i < 4; ++i) {
        const long rbase = row0 + wm * 64 + i * 16 + rgrp * 4;
        #pragma unroll
        for (int j = 0; j < 4; ++j) {
            const int col = col0 + wn * 64 + j * 16 + ccol;
            const float bsv = bias ? bias[col] : 0.f;
            #pragma unroll
            for (int rr = 0; rr < 4; ++rr) {
                const long row = rbase + rr;
                float v = acc[i][j][rr] + bsv;
                if (EPI == 0) C[row * (long)DIMV + col] = v;
                if (EPI == 1) Cb[row * (long)ldcb + cbofs + col] = (unsigned short)f2bf(fmaxf(v, 0.f));
                if (EPI == 3) { const long off = row * (long)DIMV + col;
                                const float nv = C[off] + v;
                                C[off] = nv; Cb[row * (long)ldcb + col] = (unsigned short)f2bf(nv); }
                if (EPI == 5) Cb[row * (long)ldcb + cbofs + col] = (unsigned short)f2bf(v);
                if (EPI == 7) {
                    const float gate = 1.f / (1.f + expf(-v));
                    const float tok  = bf2f(Cb[row * (long)ldcb + col]);
                    const float msg  = bf2f(Cb[row * (long)ldcb + cbofs + col]);
                    C[(long)gidx[row] * DIMV + col] = tok + gate * msg;
                }
            }
        }
    }
}

// ---------------------------------------------------------------------------
// Weight transpose+convert.
// ---------------------------------------------------------------------------
struct WPtrs13 { const float* p[13]; };

__global__ __launch_bounds__(256)
void wtrans13(WPtrs13 w, unsigned short* __restrict__ out)
{
    __shared__ float t[32][33];
    const float* W = w.p[blockIdx.z];
    unsigned short* O = out + (size_t)blockIdx.z * DIMV * DIMV;
    const int k0 = blockIdx.x * 32, n0 = blockIdx.y * 32;
    const int tx = threadIdx.x, ty = threadIdx.y;
    #pragma unroll
    for (int i = ty; i < 32; i += 8)
        t[i][tx] = W[(long)(k0 + i) * DIMV + n0 + tx];
    __syncthreads();
    #pragma unroll
    for (int i = ty; i < 32; i += 8)
        O[(long)(n0 + i) * DIMV + k0 + tx] = (unsigned short)f2bf(t[tx][i]);
}

// generic: W [krows][384] f32 -> O [384][ldo] bf16 (zero-padded k >= krows)
__global__ __launch_bounds__(256)
void wtransb(const float* __restrict__ W, unsigned short* __restrict__ O,
             int krows, int ldo)
{
    __shared__ float t[32][33];
    const int k0 = blockIdx.x * 32, n0 = blockIdx.y * 32;
    const int tx = threadIdx.x, ty = threadIdx.y;
    #pragma unroll
    for (int i = ty; i < 32; i += 8)
        t[i][tx] = (k0 + i < krows) ? W[(long)(k0 + i) * DIMV + n0 + tx] : 0.f;
    __syncthreads();
    #pragma unroll
    for (int i = ty; i < 32; i += 8)
        O[(long)(n0 + i) * ldo + k0 + tx] = (unsigned short)f2bf(t[tx][i]);
}

// corr f32 [E][882] -> bf16 [E][896] (padded); also zero-fills zrow (2KB).
__global__ __launch_bounds__(256)
void corrconv(const float* __restrict__ corr, unsigned int* __restrict__ corrb,
              unsigned int* __restrict__ zr)
{
    if (blockIdx.x == 0 && threadIdx.x < 512) zr[threadIdx.x] = 0u;
    const long idx = (long)blockIdx.x * 256 + threadIdx.x;   // over E*448 pairs
    if (idx >= (long)ETOK * (CORR_PAD / 2)) return;
    const long e = idx / (CORR_PAD / 2);
    const int  p = (int)(idx % (CORR_PAD / 2));
    const int  k = p * 2;
    unsigned v = 0u;
    if (k + 1 < CORR_DIMV) {
        const float2 f = *(const float2*)(corr + e * CORR_DIMV + k);
        v = f2bf(f.x) | (f2bf(f.y) << 16);
    }
    corrb[idx] = v;
}

// ---------------------------------------------------------------------------
// LayerNorm over DIM=384, one wave per row.
// MODE 0: x = bf2f(sb)                       (LN_c)
// MODE 1: x = s0 + s1 + bf2f(sb)             (LN1)
// MODE 2: x = s0[gather] + seg[gather/24]    (LN2)
// ---------------------------------------------------------------------------
template<int MODE, bool RELUB>
__global__ __launch_bounds__(256)
void ln_kernel(float* __restrict__ dst, unsigned short* __restrict__ dstb, int ldb,
               const float* __restrict__ s0, const float* __restrict__ s1,
               const unsigned short* __restrict__ sb,
               const float* __restrict__ seg, const int* __restrict__ gather,
               const float* __restrict__ g, const float* __restrict__ b)
{
    const int wave = threadIdx.x >> 6;
    const int lane = threadIdx.x & 63;
    const long row = (long)blockIdx.x * 4 + wave;
    const long srow = (MODE == 2) ? (long)gather[row] : row;

    float x[6];
    float sum = 0.f;
    #pragma unroll
    for (int i = 0; i < 6; ++i) {
        int c = lane + i * 64;
        float v;
        if (MODE == 0) v = bf2f(sb[srow * DIMV + c]);
        if (MODE == 1) v = s0[srow * DIMV + c] + s1[srow * DIMV + c] + bf2f(sb[srow * DIMV + c]);
        if (MODE == 2) v = s0[srow * DIMV + c] + seg[(srow / NFRAMESV) * DIMV + c];
        x[i] = v; sum += v;
    }
    #pragma unroll
    for (int o = 32; o > 0; o >>= 1) sum += __shfl_xor(sum, o);
    float mu = sum * (1.f / DIMV);
    float vs = 0.f;
    #pragma unroll
    for (int i = 0; i < 6; ++i) { float d = x[i] - mu; vs += d * d; }
    #pragma unroll
    for (int o = 32; o > 0; o >>= 1) vs += __shfl_xor(vs, o);
    float rstd = rsqrtf(vs * (1.f / DIMV) + 1e-3f);
    #pragma unroll
    for (int i = 0; i < 6; ++i) {
        int c = lane + i * 64;
        float y = (x[i] - mu) * rstd * g[c] + b[c];
        if (dst)  dst[row * DIMV + c] = y;
        if (dstb) dstb[row * (long)ldb + c] =
            (unsigned short)f2bf(RELUB ? fmaxf(y, 0.f) : y);
    }
}

// ---------------------------------------------------------------------------
// Segment softmax-aggregation (contiguous 24-row segments); bf16 in/out.
// ---------------------------------------------------------------------------
__global__ __launch_bounds__(384)
void softagg_kernel(const unsigned short* __restrict__ gbuf,
                    const unsigned short* __restrict__ fbuf,
                    unsigned short* __restrict__ yb)
{
    const int p = blockIdx.x;
    const int col = threadIdx.x;
    const long base = (long)p * NFRAMESV * DIMV + col;
    float gv[NFRAMESV];
    float gmax = -INFINITY;
    #pragma unroll
    for (int r = 0; r < NFRAMESV; ++r) {
        gv[r] = bf2f(gbuf[base + (long)r * DIMV]);
        gmax = fmaxf(gmax, gv[r]);
    }
    float den = 0.f;
    #pragma unroll
    for (int r = 0; r < NFRAMESV; ++r) { gv[r] = expf(gv[r] - gmax); den += gv[r]; }
    float acc = 0.f;
    #pragma unroll
    for (int r = 0; r < NFRAMESV; ++r) acc += bf2f(fbuf[base + (long)r * DIMV]) * gv[r];
    yb[(long)p * DIMV + col] = (unsigned short)f2bf(acc / den);
}

// ---------------------------------------------------------------------------
// RoPE + elu+1 on q and k in place, bf16. One thread = 4 (d, d+24) pairs.
// ---------------------------------------------------------------------------
__global__ __launch_bounds__(256)
void rope_kernel(unsigned short* __restrict__ q, unsigned short* __restrict__ k,
                 const float* __restrict__ pos, const int* __restrict__ flat)
{
    const long idx = (long)blockIdx.x * 256 + threadIdx.x;    // ETOK*48 threads
    const long e = idx / 48;
    const int rem = (int)(idx % 48);
    const int h = rem / 6, d4 = (rem % 6) * 4;
    const int tok = flat[e];
    const float* cp = pos + (long)tok * HDV;
    const float* sp = pos + (long)ETOK * HDV + (long)tok * HDV;
    const float4 c1 = *(const float4*)(cp + d4);
    const float4 c2 = *(const float4*)(cp + d4 + 24);
    const float4 s1 = *(const float4*)(sp + d4);
    const float4 s2 = *(const float4*)(sp + d4 + 24);
    const long o1 = e * DIMV + h * HDV + d4;
    const long o2 = o1 + 24;

    float c1a[4] = {c1.x, c1.y, c1.z, c1.w};
    float c2a[4] = {c2.x, c2.y, c2.z, c2.w};
    float s1a[4] = {s1.x, s1.y, s1.z, s1.w};
    float s2a[4] = {s2.x, s2.y, s2.z, s2.w};

    u16x4 q1 = *(const u16x4*)&q[o1];
    u16x4 q2 = *(const u16x4*)&q[o2];
    u16x4 k1 = *(const u16x4*)&k[o1];
    u16x4 k2 = *(const u16x4*)&k[o2];
    u16x4 q1o, q2o, k1o, k2o;
    #pragma unroll
    for (int i = 0; i < 4; ++i) {
        const float qa = bf2f(q1[i]), qb = bf2f(q2[i]);
        float r1 = qa * c1a[i] - qb * s1a[i];
        float r2 = qb * c2a[i] + qa * s2a[i];
        r1 = (r1 > 0.f) ? r1 + 1.f : expf(r1);
        r2 = (r2 > 0.f) ? r2 + 1.f : expf(r2);
        q1o[i] = (unsigned short)f2bf(r1);
        q2o[i] = (unsigned short)f2bf(r2);
        const float ka = bf2f(k1[i]), kb = bf2f(k2[i]);
        float t1 = ka * c1a[i] - kb * s1a[i];
        float t2 = kb * c2a[i] + ka * s2a[i];
        t1 = (t1 > 0.f) ? t1 + 1.f : expf(t1);
        t2 = (t2 > 0.f) ? t2 + 1.f : expf(t2);
        k1o[i] = (unsigned short)f2bf(t1);
        k2o[i] = (unsigned short)f2bf(t2);
    }
    *(u16x4*)&q[o1] = q1o;
    *(u16x4*)&q[o2] = q2o;
    *(u16x4*)&k[o1] = k1o;
    *(u16x4*)&k[o2] = k2o;
}

// ---------------------------------------------------------------------------
// Gated linear attention core — MFMA, one WAVE per (group n, head h), bf16 io.
// ---------------------------------------------------------------------------
__global__ __launch_bounds__(256)
void attn_kernel(const unsigned short* __restrict__ qb,
                 const unsigned short* __restrict__ kb,
                 const unsigned short* __restrict__ vb,
                 unsigned short* __restrict__ ob)
{
    __shared__ unsigned short KVt[4][48][64];   // per-wave bf16 KV^T, swizzled
    __shared__ float KsumS[4][48];
    __shared__ float ZlS[4][96];

    const int tid  = threadIdx.x;
    const int wid  = tid >> 6;
    const int lane = tid & 63;
    const int task = blockIdx.x * 4 + wid;       // 4608 tasks
    const int n = task >> 3, h = task & 7;

    const long base = ((long)n * MTOK) * DIMV + h * HDV;

    const int c16   = lane & 15;
    const int kq    = lane >> 4;    // 0..3
    const int khalf = kq * 8;

    // zero logical d=48..63 pad rows of KVt (physical = logical ^ swizzle)
    if (lane < 48) {
        const int s = (lane & 7) << 3;
        const uint4 z = make_uint4(0u, 0u, 0u, 0u);
        *(uint4*)&KVt[wid][lane][48 ^ s] = z;
        *(uint4*)&KVt[wid][lane][56 ^ s] = z;
    }

    // ---- KV = K^T V via MFMA; Ksum accumulated from the same K loads ----
    f32x4 kv[3][3] = {};
    float ksum_p[3] = {0.f, 0.f, 0.f};

    for (int ks = 0; ks < 3; ++ks) {
        const int l0 = ks * 32 + khalf;
        s16x8 afr[3], bfr[3];
        #pragma unroll
        for (int mf = 0; mf < 3; ++mf) {
            const int d = mf * 16 + c16;
            union { unsigned short us[8]; s16x8 v; } pk;
            float s = 0.f;
            #pragma unroll
            for (int j = 0; j < 8; ++j) {
                const unsigned short kw = kb[base + (long)(l0 + j) * DIMV + d];
                s += bf2f(kw);
                pk.us[j] = kw;
            }
            ksum_p[mf] += s;
            afr[mf] = pk.v;
        }
        #pragma unroll
        for (int nf = 0; nf < 3; ++nf) {
            const int dv = nf * 16 + c16;
            union { unsigned short us[8]; s16x8 v; } pk;
            #pragma unroll
            for (int j = 0; j < 8; ++j)
                pk.us[j] = vb[base + (long)(l0 + j) * DIMV + dv];
            bfr[nf] = pk.v;
        }
        #pragma unroll
        for (int mf = 0; mf < 3; ++mf)
            #pragma unroll
            for (int nf = 0; nf < 3; ++nf)
                kv[mf][nf] = __builtin_amdgcn_mfma_f32_16x16x32_bf16(afr[mf], bfr[nf], kv[mf][nf], 0, 0, 0);
    }

    // Ksum: reduce over the 4 lane-quarters
    #pragma unroll
    for (int mf = 0; mf < 3; ++mf) {
        float s = ksum_p[mf];
        s += __shfl_xor(s, 16);
        s += __shfl_xor(s, 32);
        if (kq == 0) KsumS[wid][mf * 16 + c16] = s;
    }

    // KV fragments -> LDS bf16 [dv][d] (C layout: col=dv=lane&15, row=d=kq*4+rr)
    #pragma unroll
    for (int mf = 0; mf < 3; ++mf) {
        #pragma unroll
        for (int nf = 0; nf < 3; ++nf) {
            const int dv = nf * 16 + c16;
            const int d0 = (mf * 16 + kq * 4) ^ ((dv & 7) << 3);
            uint2 w;
            w.x = f2bf(kv[mf][nf][0]) | (f2bf(kv[mf][nf][1]) << 16);
            w.y = f2bf(kv[mf][nf][2]) | (f2bf(kv[mf][nf][3]) << 16);
            *(uint2*)&KVt[wid][dv][d0] = w;
        }
    }

    // ---- Q fragments (direct bf16 16B loads) + Z denominators ----
    s16x8 qf[6][2];
    const s16x8 zfrag = {0, 0, 0, 0, 0, 0, 0, 0};
    #pragma unroll
    for (int mf = 0; mf < 6; ++mf) {
        const int l = mf * 16 + c16;
        float dsum = 0.f;
        #pragma unroll
        for (int ks = 0; ks < 2; ++ks) {
            if (ks == 0 || kq < 2) {          // d < 48 region only
                const int d = ks * 32 + khalf;
                union { unsigned short us[8]; s16x8 v; } pk;
                pk.v = *(const s16x8*)&qb[base + (long)l * DIMV + d];
                #pragma unroll
                for (int j = 0; j < 8; ++j)
                    dsum += bf2f(pk.us[j]) * KsumS[wid][d + j];
                qf[mf][ks] = pk.v;
            } else {
                qf[mf][ks] = zfrag;
            }
        }
        dsum += __shfl_xor(dsum, 16);
        dsum += __shfl_xor(dsum, 32);
        if (kq == 0) ZlS[wid][l] = 1.f / (dsum + 1e-6f);
    }

    // ---- out = (Q @ KV) * Z, stored bf16 ----
    #pragma unroll
    for (int nf = 0; nf < 3; ++nf) {
        const int dv = nf * 16 + c16;
        const int sw = (dv & 7) << 3;
        const s16x8 b0 = *(const s16x8*)&KVt[wid][dv][khalf ^ sw];
        const s16x8 b1 = *(const s16x8*)&KVt[wid][dv][(32 + khalf) ^ sw];
        #pragma unroll
        for (int mf = 0; mf < 6; ++mf) {
            f32x4 a = {};
            a = __builtin_amdgcn_mfma_f32_16x16x32_bf16(qf[mf][0], b0, a, 0, 0, 0);
            a = __builtin_amdgcn_mfma_f32_16x16x32_bf16(qf[mf][1], b1, a, 0, 0, 0);
            const int lb = mf * 16 + kq * 4;
            const long rbase = base + (long)lb * DIMV + dv;
            #pragma unroll
            for (int rr = 0; rr < 4; ++rr) {
                const float z = ZlS[wid][lb + rr];
                ob[rbase + (long)rr * DIMV] = (unsigned short)f2bf(a[rr] * z);
            }
        }
    }
}

// d/w heads: one wave per row; 4 simultaneous 384-dots, shfl reduce.
__global__ __launch_bounds__(256)
void head_kernel(const float* __restrict__ net,
                 const float* __restrict__ Wd, const float* __restrict__ bd,
                 const float* __restrict__ Ww, const float* __restrict__ bw,
                 float* __restrict__ dout, float* __restrict__ wout)
{
    const int wave = threadIdx.x >> 6;
    const int lane = threadIdx.x & 63;
    const long row = (long)blockIdx.x * 4 + wave;
    const float* p = net + row * DIMV;
    float a0 = 0.f, a1 = 0.f, a2 = 0.f, a3 = 0.f;
    #pragma unroll
    for (int i = 0; i < 6; ++i) {
        int c = lane + i * 64;
        float r = fmaxf(p[c], 0.f);
        a0 = fmaf(r, Wd[c * 2 + 0], a0);
        a1 = fmaf(r, Wd[c * 2 + 1], a1);
        a2 = fmaf(r, Ww[c * 2 + 0], a2);
        a3 = fmaf(r, Ww[c * 2 + 1], a3);
    }
    #pragma unroll
    for (int o = 32; o > 0; o >>= 1) {
        a0 += __shfl_xor(a0, o);
        a1 += __shfl_xor(a1, o);
        a2 += __shfl_xor(a2, o);
        a3 += __shfl_xor(a3, o);
    }
    if (lane == 0) {
        dout[row * 2 + 0] = a0 + bd[0];
        dout[row * 2 + 1] = a1 + bd[1];
        wout[row * 2 + 0] = 1.f / (1.f + expf(-(a2 + bw[0])));
        wout[row * 2 + 1] = 1.f / (1.f + expf(-(a3 + bw[1])));
    }
}

extern "C" void kernel_launch(void* const* d_in, const int* in_sizes, int n_in,
                              void* d_out, int out_size, void* d_ws, size_t ws_size,
                              hipStream_t stream)
{
    const float* net_in = (const float*)d_in[0];
    const float* inp    = (const float*)d_in[1];
    const float* corr   = (const float*)d_in[2];
    const float* posenc = (const float*)d_in[4];
    const int*   ix     = (const int*)d_in[8];
    const int*   jx     = (const int*)d_in[9];
    const int*   flat   = (const int*)d_in[10];   // ij_ind flattened (E,)

    const float* Wc1 = (const float*)d_in[11]; const float* bc1 = (const float*)d_in[12];
    const float* Wc2 = (const float*)d_in[13]; const float* bc2 = (const float*)d_in[14];
    const float* g_lnc = (const float*)d_in[15]; const float* b_lnc = (const float*)d_in[16];
    const float* Wc3 = (const float*)d_in[17]; const float* bc3 = (const float*)d_in[18];
    const float* g_norm = (const float*)d_in[19]; const float* b_norm = (const float*)d_in[20];
    const float* W1a = (const float*)d_in[21]; const float* b1a = (const float*)d_in[22];
    const float* W1b = (const float*)d_in[23]; const float* b1b = (const float*)d_in[24];
    const float* W2a = (const float*)d_in[25]; const float* b2a = (const float*)d_in[26];
    const float* W2b = (const float*)d_in[27]; const float* b2b = (const float*)d_in[28];
    const float* Wf = (const float*)d_in[29]; const float* bff = (const float*)d_in[30];
    const float* Wg = (const float*)d_in[31]; const float* bg = (const float*)d_in[32];
    const float* Wh = (const float*)d_in[33]; const float* bh = (const float*)d_in[34];
    const float* g_norm2 = (const float*)d_in[35]; const float* b_norm2 = (const float*)d_in[36];
    const float* Wq = (const float*)d_in[37]; const float* bq = (const float*)d_in[38];
    const float* Wk = (const float*)d_in[39]; const float* bk = (const float*)d_in[40];
    const float* Wv = (const float*)d_in[41]; const float* bv = (const float*)d_in[42];
    const float* Wm = (const float*)d_in[43]; const float* bm = (const float*)d_in[44];
    const float* Wgt = (const float*)d_in[45]; const float* bgt = (const float*)d_in[46];
    const float* Wd = (const float*)d_in[47]; const float* bd = (const float*)d_in[48];
    const float* Ww = (const float*)d_in[49]; const float* bw = (const float*)d_in[50];

    // ---- workspace layout ----
    const size_t EB  = (size_t)ETOK * DIMV;            // elements per E x 384
    const size_t WSLOT = (size_t)DIMV * DIMV;          // 147456
    char* p = (char*)d_ws;
    float* X0  = (float*)p;           p += EB * 4;                    // net f32
    float* Y2f = (float*)p;           p += (size_t)NPATCHV * DIMV * 4;
    unsigned short* WT = (unsigned short*)p;
    p += (13 * WSLOT + (size_t)DIMV * CORR_PAD + (size_t)DIMV * 768) * 2;
    unsigned short* ZR  = (unsigned short*)p; p += 4096;
    unsigned short* Cb0 = (unsigned short*)p; p += EB * 2;
    unsigned short* Bb  = (unsigned short*)p; p += EB * 2;
    unsigned short* Xb1 = (unsigned short*)p; p += EB * 2;
    unsigned short* Xb2 = (unsigned short*)p; p += EB * 2;
    unsigned short* TM  = (unsigned short*)p; p += (size_t)ETOK * 768 * 2;
    unsigned short* Yb  = (unsigned short*)p; p += (size_t)NPATCHV * DIMV * 2;
    unsigned short* qb  = (unsigned short*)p; p += EB * 2;
    unsigned short* kb  = (unsigned short*)p; p += EB * 2;
    unsigned short* vb  = (unsigned short*)p; p += EB * 2;
    unsigned short* corrb = qb;   // overlay: corrb (99MB) over qb+kb+vb (127MB)

    unsigned short* Wc2t = WT + 0 * WSLOT;
    unsigned short* Wc3t = WT + 1 * WSLOT;
    unsigned short* W1at = WT + 2 * WSLOT;
    unsigned short* W1bt = WT + 3 * WSLOT;
    unsigned short* W2at = WT + 4 * WSLOT;
    unsigned short* W2bt = WT + 5 * WSLOT;
    unsigned short* Wft  = WT + 6 * WSLOT;
    unsigned short* Wgt_ = WT + 7 * WSLOT;   // soft-agg gate Wg
    unsigned short* Wht  = WT + 8 * WSLOT;
    unsigned short* Wqt  = WT + 9 * WSLOT;
    unsigned short* Wkt  = WT + 10 * WSLOT;
    unsigned short* Wvt  = WT + 11 * WSLOT;
    unsigned short* Wmt  = WT + 12 * WSLOT;
    unsigned short* Wc1t = WT + 13 * WSLOT;                          // [384][896]
    unsigned short* Wgtt = Wc1t + (size_t)DIMV * CORR_PAD;           // [384][768]

    float* out_net = (float*)d_out;
    float* out_d = out_net + EB;
    float* out_w = out_d + (size_t)ETOK * 2;

    const dim3 gB(DIMV / 128, ETOK / 128);      // (3, 432)
    const dim3 gY(DIMV / 128, NPATCHV / 128);   // (3, 18)
    const int lnBlocks = ETOK / 4;

    // ---- pre-passes ----
    {
        const long tot = (long)ETOK * (CORR_PAD / 2);
        corrconv<<<(int)((tot + 255) / 256), 256, 0, stream>>>(corr, (unsigned int*)corrb, (unsigned int*)ZR);
    }
    {
        WPtrs13 w;
        w.p[0] = Wc2; w.p[1] = Wc3; w.p[2] = W1a; w.p[3] = W1b; w.p[4] = W2a;
        w.p[5] = W2b; w.p[6] = Wf;  w.p[7] = Wg;  w.p[8] = Wh;  w.p[9] = Wq;
        w.p[10] = Wk; w.p[11] = Wv; w.p[12] = Wm;
        wtrans13<<<dim3(12, 12, 13), dim3(32, 8), 0, stream>>>(w, WT);
        wtransb<<<dim3(28, 12), dim3(32, 8), 0, stream>>>(Wc1, Wc1t, CORR_DIMV, CORR_PAD);
        wtransb<<<dim3(24, 12), dim3(32, 8), 0, stream>>>(Wgt, Wgtt, 768, 768);
    }

    // corr encoder
    gemm_bb<1, false><<<gB, 256, 0, stream>>>(corrb, CORR_PAD, Wc1t, bc1, nullptr, Cb0, DIMV, 0, nullptr, ZR, CORR_PAD);
    gemm_bb<5, false><<<gB, 256, 0, stream>>>(Cb0, DIMV, Wc2t, bc2, nullptr, Xb1, DIMV, 0, nullptr, ZR, DIMV);
    ln_kernel<0, true><<<lnBlocks, 256, 0, stream>>>(nullptr, Cb0, DIMV, nullptr, nullptr, Xb1, nullptr, nullptr, g_lnc, b_lnc);
    gemm_bb<5, false><<<gB, 256, 0, stream>>>(Cb0, DIMV, Wc3t, bc3, nullptr, Xb2, DIMV, 0, nullptr, ZR, DIMV);

    // net = LN(net + inp + c) -> X0 (f32) + Bb (bf16)
    ln_kernel<1, false><<<lnBlocks, 256, 0, stream>>>(X0, Bb, DIMV, net_in, inp, Xb2, nullptr, nullptr, g_norm, b_norm);

    // net += mlp2(mask_ix * net[ix])
    gemm_bb<1, true><<<gB, 256, 0, stream>>>(Bb, DIMV, W1at, b1a, nullptr, Cb0, DIMV, 0, ix, ZR, DIMV);
    gemm_bb<3, false><<<gB, 256, 0, stream>>>(Cb0, DIMV, W1bt, b1b, X0, Bb, DIMV, 0, nullptr, ZR, DIMV);

    // net += mlp2(mask_jx * net[jx])
    gemm_bb<1, true><<<gB, 256, 0, stream>>>(Bb, DIMV, W2at, b2a, nullptr, Cb0, DIMV, 0, jx, ZR, DIMV);
    gemm_bb<3, false><<<gB, 256, 0, stream>>>(Cb0, DIMV, W2bt, b2b, X0, Bb, DIMV, 0, nullptr, ZR, DIMV);

    // soft aggregation
    gemm_bb<5, false><<<gB, 256, 0, stream>>>(Bb, DIMV, Wgt_, bg, nullptr, Xb1, DIMV, 0, nullptr, ZR, DIMV);
    gemm_bb<5, false><<<gB, 256, 0, stream>>>(Bb, DIMV, Wft, bff, nullptr, Xb2, DIMV, 0, nullptr, ZR, DIMV);
    softagg_kernel<<<NPATCHV, 384, 0, stream>>>(Xb1, Xb2, Yb);
    gemm_bb<0, false><<<gY, 256, 0, stream>>>(Yb, DIMV, Wht, bh, Y2f, nullptr, DIMV, 0, nullptr, ZR, DIMV);

    // tokens = LN(net[flat] + Y2[flat/24]) -> TM[:, 0:384] bf16
    ln_kernel<2, false><<<lnBlocks, 256, 0, stream>>>(nullptr, TM, 768, X0, nullptr, nullptr, Y2f, flat, g_norm2, b_norm2);

    // q,k,v (bf16 out)
    gemm_bb<5, false><<<gB, 256, 0, stream>>>(TM, 768, Wqt, bq, nullptr, qb, DIMV, 0, nullptr, ZR, DIMV);
    gemm_bb<5, false><<<gB, 256, 0, stream>>>(TM, 768, Wkt, bk, nullptr, kb, DIMV, 0, nullptr, ZR, DIMV);
    gemm_bb<5, false><<<gB, 256, 0, stream>>>(TM, 768, Wvt, bv, nullptr, vb, DIMV, 0, nullptr, ZR, DIMV);

    // RoPE + elu+1 on q,k (bf16 in place)
    rope_kernel<<<(int)((long)ETOK * 48 / 256), 256, 0, stream>>>(qb, kb, posenc, flat);

    // linear attention -> Cb0 (bf16)
    attn_kernel<<<NGRP * NHEADV / 4, 256, 0, stream>>>(qb, kb, vb, Cb0);

    // msg = out @ Wm + bm -> TM[:, 384:768] bf16
    gemm_bb<5, false><<<gB, 256, 0, stream>>>(Cb0, DIMV, Wmt, bm, nullptr, TM, 768, 384, nullptr, ZR, DIMV);

    // gate+combine: out_net[flat[e]] = tok + sigmoid(TM @ Wgt + bgt) * msg
    gemm_bb<7, false><<<gB, 256, 0, stream>>>(TM, 768, Wgtt, bgt, out_net, TM, 768, 384, flat, ZR, 768);

    // heads
    head_kernel<<<lnBlocks, 256, 0, stream>>>(out_net, Wd, bd, Ww, bw, out_d, out_w);
}

// Round 7
// 883.339 us; speedup vs baseline: 5.7691x; 1.1394x over previous
//
#include <hip/hip_runtime.h>
#include <math.h>

#define DIMV 384
#define NHEADV 8
#define HDV 48
#define CORR_DIMV 882
#define CORR_PAD 896
#define NFRAMESV 24
#define PPIV 96
#define NPATCHV (NFRAMESV * PPIV)        // 2304
#define ETOK (NPATCHV * NFRAMESV)        // 55296
#define MTOK 96
#define NGRP (ETOK / MTOK)               // 576

using f32x4 = __attribute__((ext_vector_type(4))) float;
using s16x8 = __attribute__((ext_vector_type(8))) short;
using u16x4 = __attribute__((ext_vector_type(4))) unsigned short;

__device__ __forceinline__ unsigned int f2bf(float x) {
    union { float f; unsigned int u; } c; c.f = x;
    unsigned int u = c.u;
    u += 0x7fffu + ((u >> 16) & 1u);   // round-to-nearest-even
    return u >> 16;
}
__device__ __forceinline__ float bf2f(unsigned short x) {
    union { unsigned int u; float f; } c; c.u = ((unsigned int)x) << 16;
    return c.f;
}

__device__ __forceinline__ void gload_lds16(const void* g, void* l) {
    __builtin_amdgcn_global_load_lds(
        (const __attribute__((address_space(1))) unsigned int*)g,
        (__attribute__((address_space(3))) unsigned int*)l, 16, 0, 0);
}

// Bijective XCD-chunked block swizzle (m204): consecutive tiles -> same XCD.
__device__ __forceinline__ void xcd_tile(int& colblk, int& rowblk) {
    const int nwg  = gridDim.x * gridDim.y;
    const int flat = blockIdx.y * gridDim.x + blockIdx.x;
    const int xcd  = flat & 7;
    const int base = flat >> 3;
    const int q = nwg >> 3, r = nwg & 7;
    const int nf = (xcd < r ? xcd * (q + 1) : r * (q + 1) + (xcd - r) * q) + base;
    colblk = nf % gridDim.x;
    rowblk = nf / gridDim.x;
}

// ---------------------------------------------------------------------------
// All-bf16 MFMA GEMM with LDS DOUBLE-BUFFER + counted vmcnt prefetch.
// out[M x N] = epi(A[M x K] @ W + bias); A bf16 (row stride lda), W
// pre-transposed bf16 [N][K] (N = 128*gridDim.x). 128x128 tile, 4 waves.
// K-loop: STAGE(t+1, buf^1) -> s_waitcnt vmcnt(4) + raw s_barrier -> MFMA(buf)
// -> raw s_barrier. Prefetched loads stay in flight across the barrier.
// EPI: 0 = f32 store, 1 = bf16 relu store, 5 = bf16 store,
//      6 = bf16 in-place accumulate (Cb += acc),
//      7 = gate-combine: out_net[gidx[row]] = tok + sigmoid(acc+bias)*msg
// GATHER: A row r is A[gidx[r]]; gidx[r] < 0 -> reads zrow (zeroed region).
// ---------------------------------------------------------------------------
template<int EPI, bool GATHER>
__global__ __launch_bounds__(256)
void gemm_bb(const unsigned short* __restrict__ A, int lda,
             const unsigned short* __restrict__ Wt,
             const float* __restrict__ bias,
             float* __restrict__ C,
             unsigned short* __restrict__ Cb, int ldcb, int cbofs,
             const int* __restrict__ gidx,
             const unsigned short* __restrict__ zrow, int K)
{
    int colblk, rowblk;
    xcd_tile(colblk, rowblk);
    const int row0 = rowblk * 128;
    const int col0 = colblk * 128;

    __shared__ __align__(16) unsigned short As[2 * 128 * 32];
    __shared__ __align__(16) unsigned short Bs[2 * 128 * 32];

    const int tid  = threadIdx.x;
    const int lane = tid & 63;
    const int wid  = tid >> 6;
    const int wm   = wid >> 1;
    const int wn   = wid & 1;

    const int rl = lane >> 2;
    const int cp = lane & 3;

    const unsigned short* asrc[2];
    const unsigned short* bsrc[2];
    #pragma unroll
    for (int s = 0; s < 2; ++s) {
        const int r = wid * 32 + s * 16 + rl;
        const int c = cp ^ ((r >> 1) & 3);
        long arow = row0 + r;
        if (GATHER) arow = gidx[row0 + r];
        asrc[s] = (GATHER && arow < 0) ? (zrow + c * 8)
                                       : (A + arow * (long)lda + c * 8);
        bsrc[s] = Wt + (long)(col0 + r) * K + c * 8;
    }

    f32x4 acc[4][4] = {};
    const int ntiles = K >> 5;
    const int rsel = lane & 15;
    const int kq   = lane >> 4;

    auto stage = [&](int b, int ko) {
        unsigned short* a0 = &As[b * 4096 + wid * 1024];
        unsigned short* b0 = &Bs[b * 4096 + wid * 1024];
        gload_lds16(asrc[0] + ko, a0);
        gload_lds16(asrc[1] + ko, a0 + 512);
        gload_lds16(bsrc[0] + ko, b0);
        gload_lds16(bsrc[1] + ko, b0 + 512);
    };
    auto body = [&](int b) {
        const unsigned short* Ab = &As[b * 4096];
        const unsigned short* Bf = &Bs[b * 4096];
        s16x8 a[4], w[4];
        #pragma unroll
        for (int i = 0; i < 4; ++i) {
            const int R = wm * 64 + i * 16 + rsel;
            a[i] = *(const s16x8*)&Ab[R * 32 + ((kq ^ ((R >> 1) & 3)) << 3)];
        }
        #pragma unroll
        for (int j = 0; j < 4; ++j) {
            const int R = wn * 64 + j * 16 + rsel;
            w[j] = *(const s16x8*)&Bf[R * 32 + ((kq ^ ((R >> 1) & 3)) << 3)];
        }
        #pragma unroll
        for (int i = 0; i < 4; ++i)
            #pragma unroll
            for (int j = 0; j < 4; ++j)
                acc[i][j] = __builtin_amdgcn_mfma_f32_16x16x32_bf16(a[i], w[j], acc[i][j], 0, 0, 0);
    };

    // prologue
    stage(0, 0);
    int cur = 0;
    for (int t = 0; t + 1 < ntiles; ++t) {
        stage(cur ^ 1, (t + 1) << 5);
        asm volatile("s_waitcnt vmcnt(4)\n\ts_barrier" ::: "memory");
        body(cur);
        asm volatile("s_barrier" ::: "memory");
        cur ^= 1;
    }
    asm volatile("s_waitcnt vmcnt(0)\n\ts_barrier" ::: "memory");
    body(cur);

    // epilogue: C/D layout col=lane&15, row=(lane>>4)*4+reg
    const int ccol = lane & 15;
    const int rgrp = lane >> 4;
    #pragma unroll
    for (int i = 0; i < 4; ++i) {
        const long rbase = row0 + wm * 64 + i * 16 + rgrp * 4;
        #pragma unroll
        for (int j = 0; j < 4; ++j) {
            const int col = col0 + wn * 64 + j * 16 + ccol;
            const float bsv = bias ? bias[col] : 0.f;
            #pragma unroll
            for (int rr = 0; rr < 4; ++rr) {
                const long row = rbase + rr;
                float v = acc[i][j][rr] + bsv;
                if (EPI == 0) C[row * (long)DIMV + col] = v;
                if (EPI == 1) Cb[row * (long)ldcb + cbofs + col] = (unsigned short)f2bf(fmaxf(v, 0.f));
                if (EPI == 5) Cb[row * (long)ldcb + cbofs + col] = (unsigned short)f2bf(v);
                if (EPI == 6) { const long off = row * (long)ldcb + col;
                                Cb[off] = (unsigned short)f2bf(bf2f(Cb[off]) + v); }
                if (EPI == 7) {
                    const float gate = 1.f / (1.f + expf(-v));
                    const float tok  = bf2f(Cb[row * (long)ldcb + col]);
                    const float msg  = bf2f(Cb[row * (long)ldcb + cbofs + col]);
                    C[(long)gidx[row] * DIMV + col] = tok + gate * msg;
                }
            }
        }
    }
}

// ---------------------------------------------------------------------------
// Weight transpose+convert. Slot order matters: 6=Wg,7=Wf (merged N=768),
// 9=Wq,10=Wk,11=Wv (merged N=1152).
// ---------------------------------------------------------------------------
struct WPtrs13 { const float* p[13]; };

__global__ __launch_bounds__(256)
void wtrans13(WPtrs13 w, unsigned short* __restrict__ out)
{
    __shared__ float t[32][33];
    const float* W = w.p[blockIdx.z];
    unsigned short* O = out + (size_t)blockIdx.z * DIMV * DIMV;
    const int k0 = blockIdx.x * 32, n0 = blockIdx.y * 32;
    const int tx = threadIdx.x, ty = threadIdx.y;
    #pragma unroll
    for (int i = ty; i < 32; i += 8)
        t[i][tx] = W[(long)(k0 + i) * DIMV + n0 + tx];
    __syncthreads();
    #pragma unroll
    for (int i = ty; i < 32; i += 8)
        O[(long)(n0 + i) * DIMV + k0 + tx] = (unsigned short)f2bf(t[tx][i]);
}

// generic: W [krows][384] f32 -> O [384][ldo] bf16 (zero-padded k >= krows)
__global__ __launch_bounds__(256)
void wtransb(const float* __restrict__ W, unsigned short* __restrict__ O,
             int krows, int ldo)
{
    __shared__ float t[32][33];
    const int k0 = blockIdx.x * 32, n0 = blockIdx.y * 32;
    const int tx = threadIdx.x, ty = threadIdx.y;
    #pragma unroll
    for (int i = ty; i < 32; i += 8)
        t[i][tx] = (k0 + i < krows) ? W[(long)(k0 + i) * DIMV + n0 + tx] : 0.f;
    __syncthreads();
    #pragma unroll
    for (int i = ty; i < 32; i += 8)
        O[(long)(n0 + i) * ldo + k0 + tx] = (unsigned short)f2bf(t[tx][i]);
}

// corr f32 [E][882] -> bf16 [E][896] (padded); also zero-fills zrow (2KB).
__global__ __launch_bounds__(256)
void corrconv(const float* __restrict__ corr, unsigned int* __restrict__ corrb,
              unsigned int* __restrict__ zr)
{
    if (blockIdx.x == 0 && threadIdx.x < 512) zr[threadIdx.x] = 0u;
    const long idx = (long)blockIdx.x * 256 + threadIdx.x;   // over E*448 pairs
    if (idx >= (long)ETOK * (CORR_PAD / 2)) return;
    const long e = idx / (CORR_PAD / 2);
    const int  p = (int)(idx % (CORR_PAD / 2));
    const int  k = p * 2;
    unsigned v = 0u;
    if (k + 1 < CORR_DIMV) {
        const float2 f = *(const float2*)(corr + e * CORR_DIMV + k);
        v = f2bf(f.x) | (f2bf(f.y) << 16);
    }
    corrb[idx] = v;
}

// concat biases: bqkv[1152] = bq|bk|bv ; bgf[768] = bg|bf
__global__ __launch_bounds__(256)
void biascat(const float* __restrict__ bq, const float* __restrict__ bk,
             const float* __restrict__ bv, const float* __restrict__ bg,
             const float* __restrict__ bf_, float* __restrict__ bqkv,
             float* __restrict__ bgf)
{
    const int t = blockIdx.x * 256 + threadIdx.x;
    if (t < 384)       { bqkv[t] = bq[t];       bgf[t] = bg[t]; }
    else if (t < 768)  { bqkv[t] = bk[t - 384]; bgf[t] = bf_[t - 384]; }
    else if (t < 1152) { bqkv[t] = bv[t - 768]; }
}

// ---------------------------------------------------------------------------
// LayerNorm over DIM=384, one wave per row, bf16 output (stride ldb).
// MODE 0: x = bf2f(sb[row])
// MODE 1: x = s0[row] + s1[row] + bf2f(sb[row])
// MODE 2: x = bf2f(sb[gather]) + seg[gather/24]
// ---------------------------------------------------------------------------
template<int MODE, bool RELUB>
__global__ __launch_bounds__(256)
void ln_kernel(unsigned short* __restrict__ dstb, int ldb,
               const float* __restrict__ s0, const float* __restrict__ s1,
               const unsigned short* __restrict__ sb,
               const float* __restrict__ seg, const int* __restrict__ gather,
               const float* __restrict__ g, const float* __restrict__ b)
{
    const int wave = threadIdx.x >> 6;
    const int lane = threadIdx.x & 63;
    const long row = (long)blockIdx.x * 4 + wave;
    const long srow = (MODE == 2) ? (long)gather[row] : row;

    float x[6];
    float sum = 0.f;
    #pragma unroll
    for (int i = 0; i < 6; ++i) {
        int c = lane + i * 64;
        float v;
        if (MODE == 0) v = bf2f(sb[srow * DIMV + c]);
        if (MODE == 1) v = s0[srow * DIMV + c] + s1[srow * DIMV + c] + bf2f(sb[srow * DIMV + c]);
        if (MODE == 2) v = bf2f(sb[srow * DIMV + c]) + seg[(srow / NFRAMESV) * DIMV + c];
        x[i] = v; sum += v;
    }
    #pragma unroll
    for (int o = 32; o > 0; o >>= 1) sum += __shfl_xor(sum, o);
    float mu = sum * (1.f / DIMV);
    float vs = 0.f;
    #pragma unroll
    for (int i = 0; i < 6; ++i) { float d = x[i] - mu; vs += d * d; }
    #pragma unroll
    for (int o = 32; o > 0; o >>= 1) vs += __shfl_xor(vs, o);
    float rstd = rsqrtf(vs * (1.f / DIMV) + 1e-3f);
    #pragma unroll
    for (int i = 0; i < 6; ++i) {
        int c = lane + i * 64;
        float y = (x[i] - mu) * rstd * g[c] + b[c];
        dstb[row * (long)ldb + c] = (unsigned short)f2bf(RELUB ? fmaxf(y, 0.f) : y);
    }
}

// ---------------------------------------------------------------------------
// Segment softmax-aggregation; g/f interleaved in one [E][768] bf16 buffer.
// ---------------------------------------------------------------------------
__global__ __launch_bounds__(384)
void softagg_kernel(const unsigned short* __restrict__ gf,
                    unsigned short* __restrict__ yb)
{
    const int p = blockIdx.x;
    const int col = threadIdx.x;
    const long base = (long)p * NFRAMESV * 768 + col;
    float gv[NFRAMESV];
    float gmax = -INFINITY;
    #pragma unroll
    for (int r = 0; r < NFRAMESV; ++r) {
        gv[r] = bf2f(gf[base + (long)r * 768]);
        gmax = fmaxf(gmax, gv[r]);
    }
    float den = 0.f;
    #pragma unroll
    for (int r = 0; r < NFRAMESV; ++r) { gv[r] = expf(gv[r] - gmax); den += gv[r]; }
    float acc = 0.f;
    #pragma unroll
    for (int r = 0; r < NFRAMESV; ++r) acc += bf2f(gf[base + 384 + (long)r * 768]) * gv[r];
    yb[(long)p * DIMV + col] = (unsigned short)f2bf(acc / den);
}

// ---------------------------------------------------------------------------
// RoPE + elu+1 on q and k in place, bf16, row stride ld.
// ---------------------------------------------------------------------------
__global__ __launch_bounds__(256)
void rope_kernel(unsigned short* __restrict__ q, unsigned short* __restrict__ k,
                 int ld, const float* __restrict__ pos, const int* __restrict__ flat)
{
    const long idx = (long)blockIdx.x * 256 + threadIdx.x;    // ETOK*48 threads
    const long e = idx / 48;
    const int rem = (int)(idx % 48);
    const int h = rem / 6, d4 = (rem % 6) * 4;
    const int tok = flat[e];
    const float* cp = pos + (long)tok * HDV;
    const float* sp = pos + (long)ETOK * HDV + (long)tok * HDV;
    const float4 c1 = *(const float4*)(cp + d4);
    const float4 c2 = *(const float4*)(cp + d4 + 24);
    const float4 s1 = *(const float4*)(sp + d4);
    const float4 s2 = *(const float4*)(sp + d4 + 24);
    const long o1 = e * ld + h * HDV + d4;
    const long o2 = o1 + 24;

    float c1a[4] = {c1.x, c1.y, c1.z, c1.w};
    float c2a[4] = {c2.x, c2.y, c2.z, c2.w};
    float s1a[4] = {s1.x, s1.y, s1.z, s1.w};
    float s2a[4] = {s2.x, s2.y, s2.z, s2.w};

    u16x4 q1 = *(const u16x4*)&q[o1];
    u16x4 q2 = *(const u16x4*)&q[o2];
    u16x4 k1 = *(const u16x4*)&k[o1];
    u16x4 k2 = *(const u16x4*)&k[o2];
    u16x4 q1o, q2o, k1o, k2o;
    #pragma unroll
    for (int i = 0; i < 4; ++i) {
        const float qa = bf2f(q1[i]), qb = bf2f(q2[i]);
        float r1 = qa * c1a[i] - qb * s1a[i];
        float r2 = qb * c2a[i] + qa * s2a[i];
        r1 = (r1 > 0.f) ? r1 + 1.f : expf(r1);
        r2 = (r2 > 0.f) ? r2 + 1.f : expf(r2);
        q1o[i] = (unsigned short)f2bf(r1);
        q2o[i] = (unsigned short)f2bf(r2);
        const float ka = bf2f(k1[i]), kb = bf2f(k2[i]);
        float t1 = ka * c1a[i] - kb * s1a[i];
        float t2 = kb * c2a[i] + ka * s2a[i];
        t1 = (t1 > 0.f) ? t1 + 1.f : expf(t1);
        t2 = (t2 > 0.f) ? t2 + 1.f : expf(t2);
        k1o[i] = (unsigned short)f2bf(t1);
        k2o[i] = (unsigned short)f2bf(t2);
    }
    *(u16x4*)&q[o1] = q1o;
    *(u16x4*)&q[o2] = q2o;
    *(u16x4*)&k[o1] = k1o;
    *(u16x4*)&k[o2] = k2o;
}

// ---------------------------------------------------------------------------
// Gated linear attention core — MFMA, one WAVE per (group n, head h), bf16 io.
// q/k/v row stride ld (merged QKV buffer); output row stride ldo.
// ---------------------------------------------------------------------------
__global__ __launch_bounds__(256)
void attn_kernel(const unsigned short* __restrict__ qb,
                 const unsigned short* __restrict__ kb,
                 const unsigned short* __restrict__ vb, int ld,
                 unsigned short* __restrict__ ob, int ldo)
{
    __shared__ unsigned short KVt[4][48][64];   // per-wave bf16 KV^T, swizzled
    __shared__ float KsumS[4][48];
    __shared__ float ZlS[4][96];

    const int tid  = threadIdx.x;
    const int wid  = tid >> 6;
    const int lane = tid & 63;
    const int task = blockIdx.x * 4 + wid;       // 4608 tasks
    const int n = task >> 3, h = task & 7;

    const long base  = ((long)n * MTOK) * ld + h * HDV;
    const long baseo = ((long)n * MTOK) * ldo + h * HDV;

    const int c16   = lane & 15;
    const int kq    = lane >> 4;    // 0..3
    const int khalf = kq * 8;

    // zero logical d=48..63 pad rows of KVt (physical = logical ^ swizzle)
    if (lane < 48) {
        const int s = (lane & 7) << 3;
        const uint4 z = make_uint4(0u, 0u, 0u, 0u);
        *(uint4*)&KVt[wid][lane][48 ^ s] = z;
        *(uint4*)&KVt[wid][lane][56 ^ s] = z;
    }

    // ---- KV = K^T V via MFMA; Ksum accumulated from the same K loads ----
    f32x4 kv[3][3] = {};
    float ksum_p[3] = {0.f, 0.f, 0.f};

    for (int ks = 0; ks < 3; ++ks) {
        const int l0 = ks * 32 + khalf;
        s16x8 afr[3], bfr[3];
        #pragma unroll
        for (int mf = 0; mf < 3; ++mf) {
            const int d = mf * 16 + c16;
            union { unsigned short us[8]; s16x8 v; } pk;
            float s = 0.f;
            #pragma unroll
            for (int j = 0; j < 8; ++j) {
                const unsigned short kw = kb[base + (long)(l0 + j) * ld + d];
                s += bf2f(kw);
                pk.us[j] = kw;
            }
            ksum_p[mf] += s;
            afr[mf] = pk.v;
        }
        #pragma unroll
        for (int nf = 0; nf < 3; ++nf) {
            const int dv = nf * 16 + c16;
            union { unsigned short us[8]; s16x8 v; } pk;
            #pragma unroll
            for (int j = 0; j < 8; ++j)
                pk.us[j] = vb[base + (long)(l0 + j) * ld + dv];
            bfr[nf] = pk.v;
        }
        #pragma unroll
        for (int mf = 0; mf < 3; ++mf)
            #pragma unroll
            for (int nf = 0; nf < 3; ++nf)
                kv[mf][nf] = __builtin_amdgcn_mfma_f32_16x16x32_bf16(afr[mf], bfr[nf], kv[mf][nf], 0, 0, 0);
    }

    // Ksum: reduce over the 4 lane-quarters
    #pragma unroll
    for (int mf = 0; mf < 3; ++mf) {
        float s = ksum_p[mf];
        s += __shfl_xor(s, 16);
        s += __shfl_xor(s, 32);
        if (kq == 0) KsumS[wid][mf * 16 + c16] = s;
    }

    // KV fragments -> LDS bf16 [dv][d] (C layout: col=dv=lane&15, row=d=kq*4+rr)
    #pragma unroll
    for (int mf = 0; mf < 3; ++mf) {
        #pragma unroll
        for (int nf = 0; nf < 3; ++nf) {
            const int dv = nf * 16 + c16;
            const int d0 = (mf * 16 + kq * 4) ^ ((dv & 7) << 3);
            uint2 w;
            w.x = f2bf(kv[mf][nf][0]) | (f2bf(kv[mf][nf][1]) << 16);
            w.y = f2bf(kv[mf][nf][2]) | (f2bf(kv[mf][nf][3]) << 16);
            *(uint2*)&KVt[wid][dv][d0] = w;
        }
    }

    // ---- Q fragments (direct bf16 16B loads) + Z denominators ----
    s16x8 qf[6][2];
    const s16x8 zfrag = {0, 0, 0, 0, 0, 0, 0, 0};
    #pragma unroll
    for (int mf = 0; mf < 6; ++mf) {
        const int l = mf * 16 + c16;
        float dsum = 0.f;
        #pragma unroll
        for (int ks = 0; ks < 2; ++ks) {
            if (ks == 0 || kq < 2) {          // d < 48 region only
                const int d = ks * 32 + khalf;
                union { unsigned short us[8]; s16x8 v; } pk;
                pk.v = *(const s16x8*)&qb[base + (long)l * ld + d];
                #pragma unroll
                for (int j = 0; j < 8; ++j)
                    dsum += bf2f(pk.us[j]) * KsumS[wid][d + j];
                qf[mf][ks] = pk.v;
            } else {
                qf[mf][ks] = zfrag;
            }
        }
        dsum += __shfl_xor(dsum, 16);
        dsum += __shfl_xor(dsum, 32);
        if (kq == 0) ZlS[wid][l] = 1.f / (dsum + 1e-6f);
    }

    // ---- out = (Q @ KV) * Z, stored bf16 ----
    #pragma unroll
    for (int nf = 0; nf < 3; ++nf) {
        const int dv = nf * 16 + c16;
        const int sw = (dv & 7) << 3;
        const s16x8 b0 = *(const s16x8*)&KVt[wid][dv][khalf ^ sw];
        const s16x8 b1 = *(const s16x8*)&KVt[wid][dv][(32 + khalf) ^ sw];
        #pragma unroll
        for (int mf = 0; mf < 6; ++mf) {
            f32x4 a = {};
            a = __builtin_amdgcn_mfma_f32_16x16x32_bf16(qf[mf][0], b0, a, 0, 0, 0);
            a = __builtin_amdgcn_mfma_f32_16x16x32_bf16(qf[mf][1], b1, a, 0, 0, 0);
            const int lb = mf * 16 + kq * 4;
            const long rbase = baseo + (long)lb * ldo + dv;
            #pragma unroll
            for (int rr = 0; rr < 4; ++rr) {
                const float z = ZlS[wid][lb + rr];
                ob[rbase + (long)rr * ldo] = (unsigned short)f2bf(a[rr] * z);
            }
        }
    }
}

// d/w heads: one wave per row; 4 simultaneous 384-dots, shfl reduce.
__global__ __launch_bounds__(256)
void head_kernel(const float* __restrict__ net,
                 const float* __restrict__ Wd, const float* __restrict__ bd,
                 const float* __restrict__ Ww, const float* __restrict__ bw,
                 float* __restrict__ dout, float* __restrict__ wout)
{
    const int wave = threadIdx.x >> 6;
    const int lane = threadIdx.x & 63;
    const long row = (long)blockIdx.x * 4 + wave;
    const float* p = net + row * DIMV;
    float a0 = 0.f, a1 = 0.f, a2 = 0.f, a3 = 0.f;
    #pragma unroll
    for (int i = 0; i < 6; ++i) {
        int c = lane + i * 64;
        float r = fmaxf(p[c], 0.f);
        a0 = fmaf(r, Wd[c * 2 + 0], a0);
        a1 = fmaf(r, Wd[c * 2 + 1], a1);
        a2 = fmaf(r, Ww[c * 2 + 0], a2);
        a3 = fmaf(r, Ww[c * 2 + 1], a3);
    }
    #pragma unroll
    for (int o = 32; o > 0; o >>= 1) {
        a0 += __shfl_xor(a0, o);
        a1 += __shfl_xor(a1, o);
        a2 += __shfl_xor(a2, o);
        a3 += __shfl_xor(a3, o);
    }
    if (lane == 0) {
        dout[row * 2 + 0] = a0 + bd[0];
        dout[row * 2 + 1] = a1 + bd[1];
        wout[row * 2 + 0] = 1.f / (1.f + expf(-(a2 + bw[0])));
        wout[row * 2 + 1] = 1.f / (1.f + expf(-(a3 + bw[1])));
    }
}

extern "C" void kernel_launch(void* const* d_in, const int* in_sizes, int n_in,
                              void* d_out, int out_size, void* d_ws, size_t ws_size,
                              hipStream_t stream)
{
    const float* net_in = (const float*)d_in[0];
    const float* inp    = (const float*)d_in[1];
    const float* corr   = (const float*)d_in[2];
    const float* posenc = (const float*)d_in[4];
    const int*   ix     = (const int*)d_in[8];
    const int*   jx     = (const int*)d_in[9];
    const int*   flat   = (const int*)d_in[10];   // ij_ind flattened (E,)

    const float* Wc1 = (const float*)d_in[11]; const float* bc1 = (const float*)d_in[12];
    const float* Wc2 = (const float*)d_in[13]; const float* bc2 = (const float*)d_in[14];
    const float* g_lnc = (const float*)d_in[15]; const float* b_lnc = (const float*)d_in[16];
    const float* Wc3 = (const float*)d_in[17]; const float* bc3 = (const float*)d_in[18];
    const float* g_norm = (const float*)d_in[19]; const float* b_norm = (const float*)d_in[20];
    const float* W1a = (const float*)d_in[21]; const float* b1a = (const float*)d_in[22];
    const float* W1b = (const float*)d_in[23]; const float* b1b = (const float*)d_in[24];
    const float* W2a = (const float*)d_in[25]; const float* b2a = (const float*)d_in[26];
    const float* W2b = (const float*)d_in[27]; const float* b2b = (const float*)d_in[28];
    const float* Wf = (const float*)d_in[29]; const float* bff = (const float*)d_in[30];
    const float* Wg = (const float*)d_in[31]; const float* bg = (const float*)d_in[32];
    const float* Wh = (const float*)d_in[33]; const float* bh = (const float*)d_in[34];
    const float* g_norm2 = (const float*)d_in[35]; const float* b_norm2 = (const float*)d_in[36];
    const float* Wq = (const float*)d_in[37]; const float* bq = (const float*)d_in[38];
    const float* Wk = (const float*)d_in[39]; const float* bk = (const float*)d_in[40];
    const float* Wv = (const float*)d_in[41]; const float* bv = (const float*)d_in[42];
    const float* Wm = (const float*)d_in[43]; const float* bm = (const float*)d_in[44];
    const float* Wgt = (const float*)d_in[45]; const float* bgt = (const float*)d_in[46];
    const float* Wd = (const float*)d_in[47]; const float* bd = (const float*)d_in[48];
    const float* Ww = (const float*)d_in[49]; const float* bw = (const float*)d_in[50];

    // ---- workspace layout ----
    const size_t EB  = (size_t)ETOK * DIMV;
    const size_t WSLOT = (size_t)DIMV * DIMV;
    char* p = (char*)d_ws;
    float* Y2f = (float*)p;           p += (size_t)NPATCHV * DIMV * 4;
    unsigned short* WT = (unsigned short*)p;
    p += (13 * WSLOT + (size_t)DIMV * CORR_PAD + (size_t)DIMV * 768) * 2;
    unsigned short* ZR  = (unsigned short*)p; p += 4096;
    float* bqkv = (float*)p;          p += 1152 * 4;
    float* bgf  = (float*)p;          p += 768 * 4;
    unsigned short* Cb0 = (unsigned short*)p; p += EB * 2;
    unsigned short* Bb  = (unsigned short*)p; p += EB * 2;
    unsigned short* Xb1 = (unsigned short*)p; p += EB * 2;
    unsigned short* Xb2 = (unsigned short*)p; p += EB * 2;
    unsigned short* Xgf = (unsigned short*)p; p += (size_t)ETOK * 768 * 2;
    unsigned short* TM  = (unsigned short*)p; p += (size_t)ETOK * 768 * 2;
    unsigned short* Yb  = (unsigned short*)p; p += (size_t)NPATCHV * DIMV * 2;
    unsigned short* QKV = (unsigned short*)p; p += (size_t)ETOK * 1152 * 2;
    unsigned short* corrb = QKV;   // overlay: corrb (99MB) over QKV (127MB)

    unsigned short* Wc2t = WT + 0 * WSLOT;
    unsigned short* Wc3t = WT + 1 * WSLOT;
    unsigned short* W1at = WT + 2 * WSLOT;
    unsigned short* W1bt = WT + 3 * WSLOT;
    unsigned short* W2at = WT + 4 * WSLOT;
    unsigned short* W2bt = WT + 5 * WSLOT;
    unsigned short* WgfT = WT + 6 * WSLOT;   // [768][384]: Wg | Wf
    unsigned short* Wht  = WT + 8 * WSLOT;
    unsigned short* Wqkv = WT + 9 * WSLOT;   // [1152][384]: Wq | Wk | Wv
    unsigned short* Wmt  = WT + 12 * WSLOT;
    unsigned short* Wc1t = WT + 13 * WSLOT;                 // [384][896]
    unsigned short* Wgtt = Wc1t + (size_t)DIMV * CORR_PAD;  // [384][768]

    float* out_net = (float*)d_out;
    float* out_d = out_net + EB;
    float* out_w = out_d + (size_t)ETOK * 2;

    const dim3 gB(DIMV / 128, ETOK / 128);      // (3, 432)
    const dim3 gGF(768 / 128, ETOK / 128);      // (6, 432)
    const dim3 gQKV(1152 / 128, ETOK / 128);    // (9, 432)
    const dim3 gY(DIMV / 128, NPATCHV / 128);   // (3, 18)
    const int lnBlocks = ETOK / 4;

    // ---- pre-passes ----
    {
        const long tot = (long)ETOK * (CORR_PAD / 2);
        corrconv<<<(int)((tot + 255) / 256), 256, 0, stream>>>(corr, (unsigned int*)corrb, (unsigned int*)ZR);
    }
    {
        WPtrs13 w;
        w.p[0] = Wc2; w.p[1] = Wc3; w.p[2] = W1a; w.p[3] = W1b; w.p[4] = W2a;
        w.p[5] = W2b; w.p[6] = Wg;  w.p[7] = Wf;  w.p[8] = Wh;  w.p[9] = Wq;
        w.p[10] = Wk; w.p[11] = Wv; w.p[12] = Wm;
        wtrans13<<<dim3(12, 12, 13), dim3(32, 8), 0, stream>>>(w, WT);
        wtransb<<<dim3(28, 12), dim3(32, 8), 0, stream>>>(Wc1, Wc1t, CORR_DIMV, CORR_PAD);
        wtransb<<<dim3(24, 12), dim3(32, 8), 0, stream>>>(Wgt, Wgtt, 768, 768);
        biascat<<<5, 256, 0, stream>>>(bq, bk, bv, bg, bff, bqkv, bgf);
    }

    // corr encoder
    gemm_bb<1, false><<<gB, 256, 0, stream>>>(corrb, CORR_PAD, Wc1t, bc1, nullptr, Cb0, DIMV, 0, nullptr, ZR, CORR_PAD);
    gemm_bb<5, false><<<gB, 256, 0, stream>>>(Cb0, DIMV, Wc2t, bc2, nullptr, Xb1, DIMV, 0, nullptr, ZR, DIMV);
    ln_kernel<0, true><<<lnBlocks, 256, 0, stream>>>(Cb0, DIMV, nullptr, nullptr, Xb1, nullptr, nullptr, g_lnc, b_lnc);
    gemm_bb<5, false><<<gB, 256, 0, stream>>>(Cb0, DIMV, Wc3t, bc3, nullptr, Xb2, DIMV, 0, nullptr, ZR, DIMV);

    // net = LN(net + inp + c) -> Bb (bf16)
    ln_kernel<1, false><<<lnBlocks, 256, 0, stream>>>(Bb, DIMV, net_in, inp, Xb2, nullptr, nullptr, g_norm, b_norm);

    // net += mlp2(mask_ix * net[ix])
    gemm_bb<1, true><<<gB, 256, 0, stream>>>(Bb, DIMV, W1at, b1a, nullptr, Cb0, DIMV, 0, ix, ZR, DIMV);
    gemm_bb<6, false><<<gB, 256, 0, stream>>>(Cb0, DIMV, W1bt, b1b, nullptr, Bb, DIMV, 0, nullptr, ZR, DIMV);

    // net += mlp2(mask_jx * net[jx])
    gemm_bb<1, true><<<gB, 256, 0, stream>>>(Bb, DIMV, W2at, b2a, nullptr, Cb0, DIMV, 0, jx, ZR, DIMV);
    gemm_bb<6, false><<<gB, 256, 0, stream>>>(Cb0, DIMV, W2bt, b2b, nullptr, Bb, DIMV, 0, nullptr, ZR, DIMV);

    // soft aggregation: g|f in one N=768 GEMM
    gemm_bb<5, false><<<gGF, 256, 0, stream>>>(Bb, DIMV, WgfT, bgf, nullptr, Xgf, 768, 0, nullptr, ZR, DIMV);
    softagg_kernel<<<NPATCHV, 384, 0, stream>>>(Xgf, Yb);
    gemm_bb<0, false><<<gY, 256, 0, stream>>>(Yb, DIMV, Wht, bh, Y2f, nullptr, DIMV, 0, nullptr, ZR, DIMV);

    // tokens = LN(net[flat] + Y2[flat/24]) -> TM[:, 0:384] bf16
    ln_kernel<2, false><<<lnBlocks, 256, 0, stream>>>(TM, 768, nullptr, nullptr, Bb, Y2f, flat, g_norm2, b_norm2);

    // q|k|v in one N=1152 GEMM -> QKV [E][1152]
    gemm_bb<5, false><<<gQKV, 256, 0, stream>>>(TM, 768, Wqkv, bqkv, nullptr, QKV, 1152, 0, nullptr, ZR, DIMV);

    // RoPE + elu+1 on q,k (bf16 in place)
    rope_kernel<<<(int)((long)ETOK * 48 / 256), 256, 0, stream>>>(QKV, QKV + 384, 1152, posenc, flat);

    // linear attention -> Cb0 (bf16)
    attn_kernel<<<NGRP * NHEADV / 4, 256, 0, stream>>>(QKV, QKV + 384, QKV + 768, 1152, Cb0, DIMV);

    // msg = out @ Wm + bm -> TM[:, 384:768] bf16
    gemm_bb<5, false><<<gB, 256, 0, stream>>>(Cb0, DIMV, Wmt, bm, nullptr, TM, 768, 384, nullptr, ZR, DIMV);

    // gate+combine: out_net[flat[e]] = tok + sigmoid(TM @ Wgt + bgt) * msg
    gemm_bb<7, false><<<gB, 256, 0, stream>>>(TM, 768, Wgtt, bgt, out_net, TM, 768, 384, flat, ZR, 768);

    // heads
    head_kernel<<<lnBlocks, 256, 0, stream>>>(out_net, Wd, bd, Ww, bw, out_d, out_w);
}